// Round 1
// baseline (1863.129 us; speedup 1.0000x reference)
//
#include <hip/hip_runtime.h>
#include <math.h>

// Mamba block fwd: B=2, L=2048, d_model=1024, d_inner=2048, d_state=16,
// d_conv=4, dt_rank=64.  All fp32 (reference dtype).
#define MB_B      2
#define MB_L      2048
#define MB_DMODEL 1024
#define MB_DINNER 2048
#define MB_DSTATE 16
#define MB_DTRANK 64
#define MB_ROWS   (MB_B * MB_L)      // 4096
#define MB_E2     (2 * MB_DINNER)    // 4096

__device__ __forceinline__ float softplus_f(float x) {
    return (x > 20.f) ? x : log1pf(expf(x));
}
__device__ __forceinline__ float silu_f(float x) {
    return x / (1.f + expf(-x));
}

// ---------------------------------------------------------------------------
// Generic fp32 GEMM:  C[m][n] = sum_k A[m*lda + k] * B[n*ldb + k]  (C = A·B^T)
// 256 threads; BM x BN block tile; TM x TN per-thread micro-tile.
// EPI==0: plain store. EPI==1: v = softplus(v + bias[n]).
// Assumes M,N,K are exact multiples of BM,BN,BK (true for all our shapes).
// ---------------------------------------------------------------------------
template <int BM, int BN, int BK, int TM, int TN, int EPI>
__global__ __launch_bounds__(256) void gemm_tn(
    const float* __restrict__ A, int lda,
    const float* __restrict__ Bm, int ldb,
    float* __restrict__ C, int ldc,
    int K, const float* __restrict__ bias)
{
    constexpr int TX = BN / TN;  // threads along N
    constexpr int TY = BM / TM;  // threads along M
    static_assert(TX * TY == 256, "bad tile config");

    // +4 pad: keeps rows 16B-aligned for float4 LDS reads and kills
    // power-of-2 bank conflicts on the transposed stores.
    __shared__ float As[BK][BM + 4];
    __shared__ float Bs[BK][BN + 4];

    const int tid = threadIdx.x;
    const int tx  = tid % TX;
    const int ty  = tid / TX;
    const int bm  = blockIdx.y * BM;
    const int bn  = blockIdx.x * BN;

    float acc[TM][TN];
#pragma unroll
    for (int i = 0; i < TM; i++)
#pragma unroll
        for (int j = 0; j < TN; j++) acc[i][j] = 0.f;

    for (int k0 = 0; k0 < K; k0 += BK) {
        // Stage A tile (BM x BK) transposed into As[k][m], float4 along K.
        for (int i = tid; i < BM * (BK / 4); i += 256) {
            const int row = i / (BK / 4), kq = i % (BK / 4);
            const float4 v = *reinterpret_cast<const float4*>(
                A + (size_t)(bm + row) * lda + (k0 + kq * 4));
            As[kq * 4 + 0][row] = v.x;
            As[kq * 4 + 1][row] = v.y;
            As[kq * 4 + 2][row] = v.z;
            As[kq * 4 + 3][row] = v.w;
        }
        for (int i = tid; i < BN * (BK / 4); i += 256) {
            const int row = i / (BK / 4), kq = i % (BK / 4);
            const float4 v = *reinterpret_cast<const float4*>(
                Bm + (size_t)(bn + row) * ldb + (k0 + kq * 4));
            Bs[kq * 4 + 0][row] = v.x;
            Bs[kq * 4 + 1][row] = v.y;
            Bs[kq * 4 + 2][row] = v.z;
            Bs[kq * 4 + 3][row] = v.w;
        }
        __syncthreads();

#pragma unroll
        for (int k = 0; k < BK; k++) {
            float av[TM], bv[TN];
            {
                const float4 a0 =
                    *reinterpret_cast<const float4*>(&As[k][ty * TM]);
                av[0] = a0.x; av[1] = a0.y; av[2] = a0.z; av[3] = a0.w;
                if constexpr (TM == 8) {
                    const float4 a1 =
                        *reinterpret_cast<const float4*>(&As[k][ty * TM + 4]);
                    av[4] = a1.x; av[5] = a1.y; av[6] = a1.z; av[7] = a1.w;
                }
            }
            if constexpr (TN == 8) {
                // Split the 8 columns into two float4 chunks tx*4 and
                // BN/2 + tx*4: lane->bank map stays 2-way max (free) instead
                // of the 4-way conflict a contiguous tx*8 read would hit.
                const float4 b0 =
                    *reinterpret_cast<const float4*>(&Bs[k][tx * 4]);
                const float4 b1 =
                    *reinterpret_cast<const float4*>(&Bs[k][BN / 2 + tx * 4]);
                bv[0] = b0.x; bv[1] = b0.y; bv[2] = b0.z; bv[3] = b0.w;
                bv[4] = b1.x; bv[5] = b1.y; bv[6] = b1.z; bv[7] = b1.w;
            } else {
#pragma unroll
                for (int j = 0; j < TN; j++) bv[j] = Bs[k][tx * TN + j];
            }
#pragma unroll
            for (int i = 0; i < TM; i++)
#pragma unroll
                for (int j = 0; j < TN; j++)
                    acc[i][j] = fmaf(av[i], bv[j], acc[i][j]);
        }
        __syncthreads();
    }

#pragma unroll
    for (int i = 0; i < TM; i++) {
        const int row = bm + ty * TM + i;
#pragma unroll
        for (int j = 0; j < TN; j++) {
            int col;
            if constexpr (TN == 8)
                col = (j < 4) ? (tx * 4 + j) : (BN / 2 + tx * 4 + (j - 4));
            else
                col = tx * TN + j;
            float v = acc[i][j];
            if constexpr (EPI == 1) v = softplus_f(v + bias[bn + col]);
            C[(size_t)row * ldc + bn + col] = v;
        }
    }
}

// ---------------------------------------------------------------------------
// Causal depthwise conv1d (width 4) + bias + SiLU.
// xz: [4096][4096] rows (b*L+l); xb = cols [0,2048). u: [4096][2048].
// One thread per (row, 4 channels).
// ---------------------------------------------------------------------------
__global__ __launch_bounds__(256) void conv_silu_kernel(
    const float* __restrict__ xz, const float* __restrict__ cw,
    const float* __restrict__ cb, float* __restrict__ u)
{
    const int idx = blockIdx.x * 256 + threadIdx.x;  // 0 .. 4096*512-1
    const int dv  = (idx & 511) * 4;
    const int row = idx >> 9;       // b*L + l
    const int l   = row & (MB_L - 1);

    float4 acc = *reinterpret_cast<const float4*>(cb + dv);
#pragma unroll
    for (int k = 0; k < 4; k++) {
        const int ls = l - 3 + k;
        if (ls >= 0) {
            const float4 xv = *reinterpret_cast<const float4*>(
                xz + (size_t)(row - 3 + k) * MB_E2 + dv);
            acc.x = fmaf(xv.x, cw[(dv + 0) * 4 + k], acc.x);
            acc.y = fmaf(xv.y, cw[(dv + 1) * 4 + k], acc.y);
            acc.z = fmaf(xv.z, cw[(dv + 2) * 4 + k], acc.z);
            acc.w = fmaf(xv.w, cw[(dv + 3) * 4 + k], acc.w);
        }
    }
    float4 r;
    r.x = silu_f(acc.x);
    r.y = silu_f(acc.y);
    r.z = silu_f(acc.z);
    r.w = silu_f(acc.w);
    *reinterpret_cast<float4*>(u + (size_t)row * MB_DINNER + dv) = r;
}

// ---------------------------------------------------------------------------
// Selective scan, fused with skip + gating.
// Lane = (channel c in block, state n): tid = c*16 + n. 16 channels/block,
// 256 blocks -> 4096 (b,d) channels. 32-step chunks of delta/u/B/C/z staged
// through LDS so the serial loop never waits on a global load.
// Writes gated y into the (dead) xb half of xz: yg[row][d] = xz[row*4096+d].
// ---------------------------------------------------------------------------
__global__ __launch_bounds__(256) void scan_kernel(
    const float* __restrict__ delta,   // [4096][2048]
    const float* __restrict__ u,       // [4096][2048]
    const float* __restrict__ xdbl,    // [4096][96]  (dt|B|C)
    const float* __restrict__ A_log,   // [2048][16]
    const float* __restrict__ Dskip,   // [2048]
    float* __restrict__ xz)            // read z (cols 2048+), write yg (cols 0..2047)
{
    constexpr int CL = 32;
    __shared__ float sD[CL][16];
    __shared__ float sU[CL][16];
    __shared__ float sB[CL][16];
    __shared__ float sC[CL][16];
    __shared__ float sZ[CL][16];

    const int tid = threadIdx.x;
    const int n   = tid & 15;
    const int c   = tid >> 4;                       // channel within block
    const int gchan = blockIdx.x * 16 + c;          // 0..4095
    const int b     = gchan >> 11;
    const int d     = gchan & (MB_DINNER - 1);
    const int dbase = (blockIdx.x & 127) * 16;

    const size_t base2048 = (size_t)b * MB_L * MB_DINNER;
    const size_t base4096 = (size_t)b * MB_L * MB_E2;
    const size_t base96   = (size_t)b * MB_L * 96;

    const float Av  = -expf(A_log[d * MB_DSTATE + n]);
    const float Dsk = Dskip[d];
    float h = 0.f;

    for (int l0 = 0; l0 < MB_L; l0 += CL) {
        __syncthreads();  // previous chunk's LDS fully consumed
        for (int r = 0; r < 2; r++) {
            const int e    = tid + r * 256;          // 0..511
            const int lloc = e >> 4, cc = e & 15;
            const size_t row = (size_t)(l0 + lloc);
            sD[lloc][cc] = delta[base2048 + row * MB_DINNER + dbase + cc];
            sU[lloc][cc] = u[base2048 + row * MB_DINNER + dbase + cc];
            sB[lloc][cc] = xdbl[base96 + row * 96 + MB_DTRANK + cc];
            sC[lloc][cc] = xdbl[base96 + row * 96 + MB_DTRANK + MB_DSTATE + cc];
            sZ[lloc][cc] = xz[base4096 + row * MB_E2 + MB_DINNER + dbase + cc];
        }
        __syncthreads();

        for (int ll = 0; ll < CL; ll++) {
            const float dt = sD[ll][c];
            const float ut = sU[ll][c];
            const float dA = expf(dt * Av);
            h = fmaf(dA, h, dt * ut * sB[ll][n]);
            float p = h * sC[ll][n];
            p += __shfl_xor(p, 1, 16);
            p += __shfl_xor(p, 2, 16);
            p += __shfl_xor(p, 4, 16);
            p += __shfl_xor(p, 8, 16);
            if (n == 0) {
                const float z = sZ[ll][c];
                xz[base4096 + (size_t)(l0 + ll) * MB_E2 + d] =
                    (p + ut * Dsk) * silu_f(z);
            }
        }
    }
}

// ---------------------------------------------------------------------------
extern "C" void kernel_launch(void* const* d_in, const int* in_sizes, int n_in,
                              void* d_out, int out_size, void* d_ws,
                              size_t ws_size, hipStream_t stream)
{
    const float* x      = (const float*)d_in[0];  // (2,2048,1024)
    const float* W_in   = (const float*)d_in[1];  // (4096,1024)
    const float* conv_w = (const float*)d_in[2];  // (2048,1,4)
    const float* conv_b = (const float*)d_in[3];  // (2048)
    const float* W_xproj= (const float*)d_in[4];  // (96,2048)
    const float* W_dt   = (const float*)d_in[5];  // (2048,64)
    const float* b_dt   = (const float*)d_in[6];  // (2048)
    const float* A_log  = (const float*)d_in[7];  // (2048,16)
    const float* Dskip  = (const float*)d_in[8];  // (2048)
    const float* W_out  = (const float*)d_in[9];  // (1024,2048)
    float* out = (float*)d_out;                   // (2,2048,1024)

    // Workspace layout (floats): 135.8 MB total.
    float* ws    = (float*)d_ws;
    float* xz    = ws;                                   // [4096][4096]
    float* u     = xz + (size_t)MB_ROWS * MB_E2;         // [4096][2048]
    float* delta = u + (size_t)MB_ROWS * MB_DINNER;      // [4096][2048]
    float* xdbl  = delta + (size_t)MB_ROWS * MB_DINNER;  // [4096][96]

    const dim3 blk(256);

    // 1) xz = x @ W_in^T          (M=4096, N=4096, K=1024)
    gemm_tn<128, 128, 16, 8, 8, 0><<<dim3(32, 32), blk, 0, stream>>>(
        x, MB_DMODEL, W_in, MB_DMODEL, xz, MB_E2, MB_DMODEL, nullptr);

    // 2) u = silu(causal_dwconv(xb) + conv_b)
    conv_silu_kernel<<<(MB_ROWS * (MB_DINNER / 4)) / 256, blk, 0, stream>>>(
        xz, conv_w, conv_b, u);

    // 3) x_dbl = u @ W_xproj^T    (M=4096, N=96, K=2048)
    gemm_tn<128, 32, 16, 8, 2, 0><<<dim3(3, 32), blk, 0, stream>>>(
        u, MB_DINNER, W_xproj, MB_DINNER, xdbl, 96, MB_DINNER, nullptr);

    // 4) delta = softplus(dt_low @ W_dt^T + b_dt)  (M=4096, N=2048, K=64)
    gemm_tn<128, 128, 16, 8, 8, 1><<<dim3(16, 32), blk, 0, stream>>>(
        xdbl, 96, W_dt, MB_DTRANK, delta, MB_DINNER, MB_DTRANK, b_dt);

    // 5) selective scan + skip + gate -> yg (overwrites xb half of xz)
    scan_kernel<<<256, blk, 0, stream>>>(delta, u, xdbl, A_log, Dskip, xz);

    // 6) out = yg @ W_out^T       (M=4096, N=1024, K=2048)
    gemm_tn<128, 128, 16, 8, 8, 0><<<dim3(8, 32), blk, 0, stream>>>(
        xz, MB_E2, W_out, MB_DINNER, out, MB_DMODEL, MB_DINNER, nullptr);
}

// Round 2
// 1391.126 us; speedup vs baseline: 1.3393x; 1.3393x over previous
//
#include <hip/hip_runtime.h>
#include <math.h>

// Mamba block fwd: B=2, L=2048, d_model=1024, d_inner=2048, d_state=16,
// d_conv=4, dt_rank=64.  All fp32 (reference dtype).
#define MB_B      2
#define MB_L      2048
#define MB_DMODEL 1024
#define MB_DINNER 2048
#define MB_DSTATE 16
#define MB_DTRANK 64
#define MB_ROWS   (MB_B * MB_L)      // 4096
#define MB_E2     (2 * MB_DINNER)    // 4096

__device__ __forceinline__ float softplus_f(float x) {
    return (x > 20.f) ? x : log1pf(expf(x));
}
__device__ __forceinline__ float silu_f(float x) {
    return x / (1.f + expf(-x));
}

// VALU cross-lane add via DPP (stays off the LDS pipe: ~2-4 cy vs ~100 cy
// for ds_swizzle-backed __shfl_xor at 1 wave/SIMD).
// CTRL: 0x128=row_ror:8, 0x124=row_ror:4, 0x4E=quad_perm(2,3,0,1)=xor2,
//       0xB1=quad_perm(1,0,3,2)=xor1. Rotation butterfly is valid for a
//       commutative reduction over each 16-lane DPP row.
template <int CTRL>
__device__ __forceinline__ float dpp_add(float x) {
    int xi = __builtin_bit_cast(int, x);
    int yi = __builtin_amdgcn_update_dpp(0, xi, CTRL, 0xF, 0xF, true);
    return x + __builtin_bit_cast(float, yi);
}

// ---------------------------------------------------------------------------
// Generic fp32 GEMM:  C[m][n] = sum_k A[m*lda + k] * B[n*ldb + k]  (C = A·B^T)
// 256 threads; BM x BN block tile; TM x TN per-thread micro-tile.
// EPI==0: plain store. EPI==1: v = softplus(v + bias[n]).
// ---------------------------------------------------------------------------
template <int BM, int BN, int BK, int TM, int TN, int EPI>
__global__ __launch_bounds__(256) void gemm_tn(
    const float* __restrict__ A, int lda,
    const float* __restrict__ Bm, int ldb,
    float* __restrict__ C, int ldc,
    int K, const float* __restrict__ bias)
{
    constexpr int TX = BN / TN;  // threads along N
    constexpr int TY = BM / TM;  // threads along M
    static_assert(TX * TY == 256, "bad tile config");

    __shared__ float As[BK][BM + 4];
    __shared__ float Bs[BK][BN + 4];

    const int tid = threadIdx.x;
    const int tx  = tid % TX;
    const int ty  = tid / TX;
    const int bm  = blockIdx.y * BM;
    const int bn  = blockIdx.x * BN;

    float acc[TM][TN];
#pragma unroll
    for (int i = 0; i < TM; i++)
#pragma unroll
        for (int j = 0; j < TN; j++) acc[i][j] = 0.f;

    for (int k0 = 0; k0 < K; k0 += BK) {
        for (int i = tid; i < BM * (BK / 4); i += 256) {
            const int row = i / (BK / 4), kq = i % (BK / 4);
            const float4 v = *reinterpret_cast<const float4*>(
                A + (size_t)(bm + row) * lda + (k0 + kq * 4));
            As[kq * 4 + 0][row] = v.x;
            As[kq * 4 + 1][row] = v.y;
            As[kq * 4 + 2][row] = v.z;
            As[kq * 4 + 3][row] = v.w;
        }
        for (int i = tid; i < BN * (BK / 4); i += 256) {
            const int row = i / (BK / 4), kq = i % (BK / 4);
            const float4 v = *reinterpret_cast<const float4*>(
                Bm + (size_t)(bn + row) * ldb + (k0 + kq * 4));
            Bs[kq * 4 + 0][row] = v.x;
            Bs[kq * 4 + 1][row] = v.y;
            Bs[kq * 4 + 2][row] = v.z;
            Bs[kq * 4 + 3][row] = v.w;
        }
        __syncthreads();

#pragma unroll
        for (int k = 0; k < BK; k++) {
            float av[TM], bv[TN];
            {
                const float4 a0 =
                    *reinterpret_cast<const float4*>(&As[k][ty * TM]);
                av[0] = a0.x; av[1] = a0.y; av[2] = a0.z; av[3] = a0.w;
                if constexpr (TM == 8) {
                    const float4 a1 =
                        *reinterpret_cast<const float4*>(&As[k][ty * TM + 4]);
                    av[4] = a1.x; av[5] = a1.y; av[6] = a1.z; av[7] = a1.w;
                }
            }
            if constexpr (TN == 8) {
                const float4 b0 =
                    *reinterpret_cast<const float4*>(&Bs[k][tx * 4]);
                const float4 b1 =
                    *reinterpret_cast<const float4*>(&Bs[k][BN / 2 + tx * 4]);
                bv[0] = b0.x; bv[1] = b0.y; bv[2] = b0.z; bv[3] = b0.w;
                bv[4] = b1.x; bv[5] = b1.y; bv[6] = b1.z; bv[7] = b1.w;
            } else {
#pragma unroll
                for (int j = 0; j < TN; j++) bv[j] = Bs[k][tx * TN + j];
            }
#pragma unroll
            for (int i = 0; i < TM; i++)
#pragma unroll
                for (int j = 0; j < TN; j++)
                    acc[i][j] = fmaf(av[i], bv[j], acc[i][j]);
        }
        __syncthreads();
    }

#pragma unroll
    for (int i = 0; i < TM; i++) {
        const int row = bm + ty * TM + i;
#pragma unroll
        for (int j = 0; j < TN; j++) {
            int col;
            if constexpr (TN == 8)
                col = (j < 4) ? (tx * 4 + j) : (BN / 2 + tx * 4 + (j - 4));
            else
                col = tx * TN + j;
            float v = acc[i][j];
            if constexpr (EPI == 1) v = softplus_f(v + bias[bn + col]);
            C[(size_t)row * ldc + bn + col] = v;
        }
    }
}

// ---------------------------------------------------------------------------
// Causal depthwise conv1d (width 4) + bias + SiLU.
// ---------------------------------------------------------------------------
__global__ __launch_bounds__(256) void conv_silu_kernel(
    const float* __restrict__ xz, const float* __restrict__ cw,
    const float* __restrict__ cb, float* __restrict__ u)
{
    const int idx = blockIdx.x * 256 + threadIdx.x;  // 0 .. 4096*512-1
    const int dv  = (idx & 511) * 4;
    const int row = idx >> 9;       // b*L + l
    const int l   = row & (MB_L - 1);

    float4 acc = *reinterpret_cast<const float4*>(cb + dv);
#pragma unroll
    for (int k = 0; k < 4; k++) {
        const int ls = l - 3 + k;
        if (ls >= 0) {
            const float4 xv = *reinterpret_cast<const float4*>(
                xz + (size_t)(row - 3 + k) * MB_E2 + dv);
            acc.x = fmaf(xv.x, cw[(dv + 0) * 4 + k], acc.x);
            acc.y = fmaf(xv.y, cw[(dv + 1) * 4 + k], acc.y);
            acc.z = fmaf(xv.z, cw[(dv + 2) * 4 + k], acc.z);
            acc.w = fmaf(xv.w, cw[(dv + 3) * 4 + k], acc.w);
        }
    }
    float4 r;
    r.x = silu_f(acc.x);
    r.y = silu_f(acc.y);
    r.z = silu_f(acc.z);
    r.w = silu_f(acc.w);
    *reinterpret_cast<float4*>(u + (size_t)row * MB_DINNER + dv) = r;
}

// ---------------------------------------------------------------------------
// Selective scan, fused with skip + gating.  Lane (c,n): tid = c*16+n.
// 16 channels/block, 256 blocks = 4096 (b,d) channels = 1 wave/SIMD, so
// every latency is exposed -> design for minimum per-step issue cost:
//   - (delta,u) and (B,C) packed float2 in LDS: 2x ds_read_b64 per step
//   - 16-lane y-reduction via 4 VALU DPP adds (no LDS pipe on the chain)
//   - y staged in LDS, skip+gate applied at a coalesced per-chunk store
//   - next chunk's global loads issued into registers BEFORE the serial
//     loop, committed to LDS after: HBM/L3 latency hides under compute
// ---------------------------------------------------------------------------
__global__ __launch_bounds__(256) void scan_kernel(
    const float* __restrict__ delta,   // [4096][2048]
    const float* __restrict__ u,       // [4096][2048]
    const float* __restrict__ xdbl,    // [4096][96]  (dt|B|C)
    const float* __restrict__ A_log,   // [2048][16]
    const float* __restrict__ Dskip,   // [2048]
    float* __restrict__ xz)            // read z (cols 2048+), write yg (cols 0..2047)
{
    constexpr int CL = 32;
    __shared__ float2 sDU[CL][16];
    __shared__ float2 sBC[CL][16];
    __shared__ float  sZ[CL][16];
    __shared__ float  sY[CL][16];

    const int tid = threadIdx.x;
    const int n   = tid & 15;
    const int c   = tid >> 4;                       // channel within block
    const int gchan = blockIdx.x * 16 + c;          // 0..4095
    const int b     = gchan >> 11;
    const int d     = gchan & (MB_DINNER - 1);
    const int dbase = (blockIdx.x & 127) * 16;

    const size_t base2048 = (size_t)b * MB_L * MB_DINNER;
    const size_t base4096 = (size_t)b * MB_L * MB_E2;
    const size_t base96   = (size_t)b * MB_L * 96;

    const float Av = -expf(A_log[d * MB_DSTATE + n]);
    float h = 0.f;

    // store-role constants: element e=tid+r*256 -> channel (e&15)==(tid&15)
    const float Dsk_s = Dskip[dbase + (tid & 15)];

    float pd[2], pu[2], pb[2], pc[2], pz[2];

    auto stage_load = [&](int l0) {
#pragma unroll
        for (int r = 0; r < 2; r++) {
            const int e = tid + r * 256;
            const int lloc = e >> 4, cc = e & 15;
            const size_t row = (size_t)(l0 + lloc);
            pd[r] = delta[base2048 + row * MB_DINNER + dbase + cc];
            pu[r] = u[base2048 + row * MB_DINNER + dbase + cc];
            pb[r] = xdbl[base96 + row * 96 + MB_DTRANK + cc];
            pc[r] = xdbl[base96 + row * 96 + MB_DTRANK + MB_DSTATE + cc];
            pz[r] = xz[base4096 + row * MB_E2 + MB_DINNER + dbase + cc];
        }
    };
    auto stage_write = [&]() {
#pragma unroll
        for (int r = 0; r < 2; r++) {
            const int e = tid + r * 256;
            const int lloc = e >> 4, cc = e & 15;
            sDU[lloc][cc] = make_float2(pd[r], pu[r]);
            sBC[lloc][cc] = make_float2(pb[r], pc[r]);
            sZ[lloc][cc]  = pz[r];
        }
    };

    stage_load(0);
    stage_write();
    __syncthreads();

    for (int l0 = 0; l0 < MB_L; l0 += CL) {
        const bool has_next = (l0 + CL) < MB_L;
        if (has_next) stage_load(l0 + CL);   // fire-and-forget until commit

#pragma unroll 8
        for (int ll = 0; ll < CL; ll++) {
            const float2 du = sDU[ll][c];    // broadcast within 16-lane group
            const float2 bc = sBC[ll][n];
            const float dA = __expf(du.x * Av);
            h = fmaf(dA, h, du.x * du.y * bc.x);
            float p = h * bc.y;
            p = dpp_add<0x128>(p);   // + ror8
            p = dpp_add<0x124>(p);   // + ror4
            p = dpp_add<0x4E>(p);    // + xor2 (quad_perm)
            p = dpp_add<0xB1>(p);    // + xor1 (quad_perm)
            if (n == 0) sY[ll][c] = p;
        }
        __syncthreads();

        // coalesced gated store of this chunk's y (reads own elements of
        // sY/sDU/sZ, then commits next chunk over them: per-element owner
        // is the same thread in both phases, so program order suffices)
#pragma unroll
        for (int r = 0; r < 2; r++) {
            const int e = tid + r * 256;
            const int lloc = e >> 4, cc = e & 15;
            const float uv = sDU[lloc][cc].y;
            const float yv =
                (sY[lloc][cc] + uv * Dsk_s) * silu_f(sZ[lloc][cc]);
            xz[base4096 + (size_t)(l0 + lloc) * MB_E2 + dbase + cc] = yv;
        }
        if (has_next) stage_write();
        __syncthreads();
    }
}

// ---------------------------------------------------------------------------
extern "C" void kernel_launch(void* const* d_in, const int* in_sizes, int n_in,
                              void* d_out, int out_size, void* d_ws,
                              size_t ws_size, hipStream_t stream)
{
    const float* x      = (const float*)d_in[0];  // (2,2048,1024)
    const float* W_in   = (const float*)d_in[1];  // (4096,1024)
    const float* conv_w = (const float*)d_in[2];  // (2048,1,4)
    const float* conv_b = (const float*)d_in[3];  // (2048)
    const float* W_xproj= (const float*)d_in[4];  // (96,2048)
    const float* W_dt   = (const float*)d_in[5];  // (2048,64)
    const float* b_dt   = (const float*)d_in[6];  // (2048)
    const float* A_log  = (const float*)d_in[7];  // (2048,16)
    const float* Dskip  = (const float*)d_in[8];  // (2048)
    const float* W_out  = (const float*)d_in[9];  // (1024,2048)
    float* out = (float*)d_out;                   // (2,2048,1024)

    // Workspace layout (floats): 135.8 MB total.
    float* ws    = (float*)d_ws;
    float* xz    = ws;                                   // [4096][4096]
    float* u     = xz + (size_t)MB_ROWS * MB_E2;         // [4096][2048]
    float* delta = u + (size_t)MB_ROWS * MB_DINNER;      // [4096][2048]
    float* xdbl  = delta + (size_t)MB_ROWS * MB_DINNER;  // [4096][96]

    const dim3 blk(256);

    // 1) xz = x @ W_in^T          (M=4096, N=4096, K=1024)
    gemm_tn<128, 128, 16, 8, 8, 0><<<dim3(32, 32), blk, 0, stream>>>(
        x, MB_DMODEL, W_in, MB_DMODEL, xz, MB_E2, MB_DMODEL, nullptr);

    // 2) u = silu(causal_dwconv(xb) + conv_b)
    conv_silu_kernel<<<(MB_ROWS * (MB_DINNER / 4)) / 256, blk, 0, stream>>>(
        xz, conv_w, conv_b, u);

    // 3) x_dbl = u @ W_xproj^T    (M=4096, N=96, K=2048)
    gemm_tn<128, 32, 16, 8, 2, 0><<<dim3(3, 32), blk, 0, stream>>>(
        u, MB_DINNER, W_xproj, MB_DINNER, xdbl, 96, MB_DINNER, nullptr);

    // 4) delta = softplus(dt_low @ W_dt^T + b_dt)  (M=4096, N=2048, K=64)
    gemm_tn<128, 128, 16, 8, 8, 1><<<dim3(16, 32), blk, 0, stream>>>(
        xdbl, 96, W_dt, MB_DTRANK, delta, MB_DINNER, MB_DTRANK, b_dt);

    // 5) selective scan + skip + gate -> yg (overwrites xb half of xz)
    scan_kernel<<<256, blk, 0, stream>>>(delta, u, xdbl, A_log, Dskip, xz);

    // 6) out = yg @ W_out^T       (M=4096, N=1024, K=2048)
    gemm_tn<128, 128, 16, 8, 8, 0><<<dim3(8, 32), blk, 0, stream>>>(
        xz, MB_E2, W_out, MB_DINNER, out, MB_DMODEL, MB_DINNER, nullptr);
}

// Round 3
// 643.739 us; speedup vs baseline: 2.8942x; 2.1610x over previous
//
#include <hip/hip_runtime.h>
#include <math.h>

// Mamba block fwd: B=2, L=2048, d_model=1024, d_inner=2048, d_state=16,
// d_conv=4, dt_rank=64.  GEMMs in f16 MFMA (m97 structure), scan fp32.
#define MB_B      2
#define MB_L      2048
#define MB_DMODEL 1024
#define MB_DINNER 2048
#define MB_DSTATE 16
#define MB_DTRANK 64
#define MB_ROWS   (MB_B * MB_L)      // 4096
#define MB_E2     (2 * MB_DINNER)    // 4096

typedef _Float16 f16;
typedef __attribute__((ext_vector_type(8))) _Float16 half8;
typedef __attribute__((ext_vector_type(4))) float floatx4;

__device__ __forceinline__ float softplus_f(float x) {
    return (x > 20.f) ? x : log1pf(expf(x));
}
__device__ __forceinline__ float silu_f(float x) {
    return x / (1.f + expf(-x));
}

// async global->LDS, 16B/lane. LDS dst is WAVE-UNIFORM base; HW adds lane*16.
typedef const __attribute__((address_space(1))) unsigned char gbyte;
typedef __attribute__((address_space(3))) unsigned char lbyte;
__device__ __forceinline__ void gl_lds16(const void* g, void* l) {
    __builtin_amdgcn_global_load_lds((gbyte*)g, (lbyte*)l, 16, 0, 0);
}

// VALU cross-lane add via DPP (off the LDS pipe; ~2-4 cy each).
template <int CTRL>
__device__ __forceinline__ float dpp_add(float x) {
    int xi = __builtin_bit_cast(int, x);
    int yi = __builtin_amdgcn_update_dpp(0, xi, CTRL, 0xF, 0xF, true);
    return x + __builtin_bit_cast(float, yi);
}

// ---------------------------------------------------------------------------
// fp32 -> f16 convert (8 elems/thread). i >= n_src writes zeros (pad rows).
// ---------------------------------------------------------------------------
__global__ __launch_bounds__(256) void convert_f16_kernel(
    const float* __restrict__ src, f16* __restrict__ dst,
    int n_src, int n_dst)
{
    const int i = (blockIdx.x * 256 + threadIdx.x) * 8;
    if (i >= n_dst) return;
    half8 o;
    if (i < n_src) {
        const float4 a = *reinterpret_cast<const float4*>(src + i);
        const float4 b = *reinterpret_cast<const float4*>(src + i + 4);
        o[0] = (f16)a.x; o[1] = (f16)a.y; o[2] = (f16)a.z; o[3] = (f16)a.w;
        o[4] = (f16)b.x; o[5] = (f16)b.y; o[6] = (f16)b.z; o[7] = (f16)b.w;
    } else {
#pragma unroll
        for (int j = 0; j < 8; j++) o[j] = (f16)0.f;
    }
    *reinterpret_cast<half8*>(dst + i) = o;
}

// ---------------------------------------------------------------------------
// f16 MFMA GEMM:  C[m][n] = sum_k A[m][k]*B[n][k]   (C = A·B^T, f32 accum)
// 128x128 tile, BK=32, 256 threads = 4 waves in 2x2, each wave 64x64 =
// 4x4 grid of 16x16x32 MFMAs. Staging via global_load_lds width=16
// (m97 ladder: this structure hits ~874 TF at 4096^3 bf16).
// EPI==1: v = softplus(v + bias[n]).  DUAL: also store f16 to C2.
// NGUARD: store C only when n < Nmax (for N padded to 128).
// ---------------------------------------------------------------------------
template <typename OutT, int EPI, bool NGUARD, bool DUAL>
__global__ __launch_bounds__(256) void gemm_mfma(
    const f16* __restrict__ A, int lda,
    const f16* __restrict__ B, int ldb,
    OutT* __restrict__ C, int ldc, int K, int Nmax,
    const float* __restrict__ bias,
    f16* __restrict__ C2, int ldc2)
{
    __shared__ f16 As[128 * 32];   // [row][k], row stride 32 halves (64 B)
    __shared__ f16 Bs[128 * 32];

    const int tid  = threadIdx.x;
    const int lane = tid & 63;
    const int wave = tid >> 6;
    const int wr   = wave >> 1, wc = wave & 1;
    const int bm   = blockIdx.y * 128, bn = blockIdx.x * 128;

    floatx4 zero4 = {0.f, 0.f, 0.f, 0.f};
    floatx4 acc[4][4];
#pragma unroll
    for (int i = 0; i < 4; i++)
#pragma unroll
        for (int j = 0; j < 4; j++) acc[i][j] = zero4;

    // Staging: A-tile = 128 rows x 64 B = 8 chunks of (16 rows = 1024 B);
    // chunk = wave*2+i. Lane l covers row l/4, k-bytes (l%4)*16 -> LDS
    // base + l*16 matches [row][k] exactly (global_load_lds constraint).
    const int srow = lane >> 2;
    const int scol = (lane & 3) * 8;
    const f16* gA0 = A + (size_t)(bm + wave * 32 + srow) * lda + scol;
    const f16* gA1 = A + (size_t)(bm + wave * 32 + 16 + srow) * lda + scol;
    const f16* gB0 = B + (size_t)(bn + wave * 32 + srow) * ldb + scol;
    const f16* gB1 = B + (size_t)(bn + wave * 32 + 16 + srow) * ldb + scol;
    f16* lA0 = As + wave * 1024;
    f16* lA1 = As + wave * 1024 + 512;
    f16* lB0 = Bs + wave * 1024;
    f16* lB1 = Bs + wave * 1024 + 512;

    const int mr = lane & 15;
    const int kq = (lane >> 4) * 8;

    for (int k0 = 0; k0 < K; k0 += 32) {
        gl_lds16(gA0 + k0, lA0);
        gl_lds16(gA1 + k0, lA1);
        gl_lds16(gB0 + k0, lB0);
        gl_lds16(gB1 + k0, lB1);
        __syncthreads();   // drains vmcnt; LDS tiles visible

        half8 af[4], bf[4];
#pragma unroll
        for (int mt = 0; mt < 4; mt++)
            af[mt] = *reinterpret_cast<const half8*>(
                As + (wr * 64 + mt * 16 + mr) * 32 + kq);
#pragma unroll
        for (int nt = 0; nt < 4; nt++)
            bf[nt] = *reinterpret_cast<const half8*>(
                Bs + (wc * 64 + nt * 16 + mr) * 32 + kq);
#pragma unroll
        for (int mt = 0; mt < 4; mt++)
#pragma unroll
            for (int nt = 0; nt < 4; nt++)
                acc[mt][nt] = __builtin_amdgcn_mfma_f32_16x16x32_f16(
                    af[mt], bf[nt], acc[mt][nt], 0, 0, 0);
        __syncthreads();   // all reads done before next stage overwrites
    }

    // Epilogue. C/D layout (verified m89): col = lane&15, row = quad*4+reg.
    const int rbase = (lane >> 4) * 4;
#pragma unroll
    for (int mt = 0; mt < 4; mt++) {
        const int row0 = bm + wr * 64 + mt * 16 + rbase;
#pragma unroll
        for (int nt = 0; nt < 4; nt++) {
            const int col = bn + wc * 64 + nt * 16 + mr;
#pragma unroll
            for (int r = 0; r < 4; r++) {
                float v = acc[mt][nt][r];
                if constexpr (EPI == 1) v = softplus_f(v + bias[col]);
                if constexpr (DUAL)
                    C2[(size_t)(row0 + r) * ldc2 + col] = (f16)v;
                if (!NGUARD || col < Nmax)
                    C[(size_t)(row0 + r) * ldc + col] = (OutT)v;
            }
        }
    }
}

// ---------------------------------------------------------------------------
// Causal depthwise conv1d (width 4) + bias + SiLU.  f16 in (xb half of xz),
// f16 out.  8 channels/thread.
// ---------------------------------------------------------------------------
__global__ __launch_bounds__(256) void conv_silu_kernel(
    const f16* __restrict__ xz, const float* __restrict__ cw,
    const float* __restrict__ cb, f16* __restrict__ u)
{
    const int idx = blockIdx.x * 256 + threadIdx.x;  // 4096 rows * 256
    const int dv  = (idx & 255) * 8;
    const int row = idx >> 8;
    const int l   = row & (MB_L - 1);

    float acc[8];
#pragma unroll
    for (int j = 0; j < 8; j++) acc[j] = cb[dv + j];
#pragma unroll
    for (int k = 0; k < 4; k++) {
        if (l - 3 + k >= 0) {
            const half8 xv = *reinterpret_cast<const half8*>(
                xz + (size_t)(row - 3 + k) * MB_E2 + dv);
#pragma unroll
            for (int j = 0; j < 8; j++)
                acc[j] = fmaf((float)xv[j], cw[(dv + j) * 4 + k], acc[j]);
        }
    }
    half8 r;
#pragma unroll
    for (int j = 0; j < 8; j++) r[j] = (f16)silu_f(acc[j]);
    *reinterpret_cast<half8*>(u + (size_t)row * MB_DINNER + dv) = r;
}

// ---------------------------------------------------------------------------
// Selective scan + skip + gate.  Lane (c,n): tid = c*16+n; 16 chans/block,
// 256 blocks = 1 wave/SIMD.  f16 inputs (delta,u,z), f32 B,C; writes gated
// y as f16 for the MFMA out_proj.  DPP reduction, register double-buffered
// chunk staging, coalesced chunk store (round-2 structure).
// ---------------------------------------------------------------------------
__global__ __launch_bounds__(256) void scan_kernel(
    const f16*  __restrict__ delta,   // [4096][2048]
    const f16*  __restrict__ u,       // [4096][2048]
    const float* __restrict__ xdbl,   // [4096][96]  (dt|B|C)
    const float* __restrict__ A_log,  // [2048][16]
    const float* __restrict__ Dskip,  // [2048]
    const f16*  __restrict__ xz,      // z = cols [2048,4096)
    f16* __restrict__ yg)             // [4096][2048]
{
    constexpr int CL = 32;
    __shared__ float2 sDU[CL][16];
    __shared__ float2 sBC[CL][16];
    __shared__ float  sZ[CL][16];
    __shared__ float  sY[CL][16];

    const int tid = threadIdx.x;
    const int n   = tid & 15;
    const int c   = tid >> 4;
    const int gchan = blockIdx.x * 16 + c;
    const int b     = gchan >> 11;
    const int d     = gchan & (MB_DINNER - 1);
    const int dbase = (blockIdx.x & 127) * 16;

    const size_t base2048 = (size_t)b * MB_L * MB_DINNER;
    const size_t base4096 = (size_t)b * MB_L * MB_E2;
    const size_t base96   = (size_t)b * MB_L * 96;

    const float Av = -expf(A_log[d * MB_DSTATE + n]);
    float h = 0.f;
    const float Dsk_s = Dskip[dbase + (tid & 15)];

    float pd[2], pu[2], pb[2], pc[2], pz[2];

    auto stage_load = [&](int l0) {
#pragma unroll
        for (int r = 0; r < 2; r++) {
            const int e = tid + r * 256;
            const int lloc = e >> 4, cc = e & 15;
            const size_t row = (size_t)(l0 + lloc);
            pd[r] = (float)delta[base2048 + row * MB_DINNER + dbase + cc];
            pu[r] = (float)u[base2048 + row * MB_DINNER + dbase + cc];
            pb[r] = xdbl[base96 + row * 96 + MB_DTRANK + cc];
            pc[r] = xdbl[base96 + row * 96 + MB_DTRANK + MB_DSTATE + cc];
            pz[r] = (float)xz[base4096 + row * MB_E2 + MB_DINNER + dbase + cc];
        }
    };
    auto stage_write = [&]() {
#pragma unroll
        for (int r = 0; r < 2; r++) {
            const int e = tid + r * 256;
            const int lloc = e >> 4, cc = e & 15;
            sDU[lloc][cc] = make_float2(pd[r], pu[r]);
            sBC[lloc][cc] = make_float2(pb[r], pc[r]);
            sZ[lloc][cc]  = pz[r];
        }
    };

    stage_load(0);
    stage_write();
    __syncthreads();

    for (int l0 = 0; l0 < MB_L; l0 += CL) {
        const bool has_next = (l0 + CL) < MB_L;
        if (has_next) stage_load(l0 + CL);

#pragma unroll 8
        for (int ll = 0; ll < CL; ll++) {
            const float2 du = sDU[ll][c];
            const float2 bc = sBC[ll][n];
            const float dA = __expf(du.x * Av);
            h = fmaf(dA, h, du.x * du.y * bc.x);
            float p = h * bc.y;
            p = dpp_add<0x128>(p);   // row_ror:8
            p = dpp_add<0x124>(p);   // row_ror:4
            p = dpp_add<0x4E>(p);    // quad_perm xor2
            p = dpp_add<0xB1>(p);    // quad_perm xor1
            if (n == 0) sY[ll][c] = p;
        }
        __syncthreads();

#pragma unroll
        for (int r = 0; r < 2; r++) {
            const int e = tid + r * 256;
            const int lloc = e >> 4, cc = e & 15;
            const float uv = sDU[lloc][cc].y;
            const float yv =
                (sY[lloc][cc] + uv * Dsk_s) * silu_f(sZ[lloc][cc]);
            yg[base2048 + (size_t)(l0 + lloc) * MB_DINNER + dbase + cc] =
                (f16)yv;
        }
        if (has_next) stage_write();
        __syncthreads();
    }
}

// ---------------------------------------------------------------------------
extern "C" void kernel_launch(void* const* d_in, const int* in_sizes, int n_in,
                              void* d_out, int out_size, void* d_ws,
                              size_t ws_size, hipStream_t stream)
{
    const float* x      = (const float*)d_in[0];  // (2,2048,1024)
    const float* W_in   = (const float*)d_in[1];  // (4096,1024)
    const float* conv_w = (const float*)d_in[2];  // (2048,1,4)
    const float* conv_b = (const float*)d_in[3];  // (2048)
    const float* W_xproj= (const float*)d_in[4];  // (96,2048)
    const float* W_dt   = (const float*)d_in[5];  // (2048,64)
    const float* b_dt   = (const float*)d_in[6];  // (2048)
    const float* A_log  = (const float*)d_in[7];  // (2048,16)
    const float* Dskip  = (const float*)d_in[8];  // (2048)
    const float* W_out  = (const float*)d_in[9];  // (1024,2048)
    float* out = (float*)d_out;                   // (2,2048,1024)

    // Workspace (~108 MB), all 16B-aligned chunks.
    char* p = (char*)d_ws;
    f16* xz_h    = (f16*)p;  p += (size_t)MB_ROWS * MB_E2 * 2;      // 33.6 MB
    f16* u_h     = (f16*)p;  p += (size_t)MB_ROWS * MB_DINNER * 2;  // 16.8 MB
    f16* delta_h = (f16*)p;  p += (size_t)MB_ROWS * MB_DINNER * 2;  // 16.8 MB
    f16* yg_h    = (f16*)p;  p += (size_t)MB_ROWS * MB_DINNER * 2;  // 16.8 MB
    float* xdbl  = (float*)p; p += (size_t)MB_ROWS * 96 * 4;        // 1.6 MB
    f16* xdbl_h  = (f16*)p;  p += (size_t)MB_ROWS * 128 * 2;        // 1.0 MB
    f16* x_h     = (f16*)p;  p += (size_t)MB_ROWS * MB_DMODEL * 2;  // 8.4 MB
    f16* W_inh   = (f16*)p;  p += (size_t)MB_E2 * MB_DMODEL * 2;    // 8.4 MB
    f16* W_xprojh= (f16*)p;  p += (size_t)128 * MB_DINNER * 2;      // 0.5 MB
    f16* W_dth   = (f16*)p;  p += (size_t)MB_DINNER * MB_DTRANK * 2;// 0.26 MB
    f16* W_outh  = (f16*)p;                                          // 4.2 MB

    const dim3 blk(256);

    // 0) fp32 -> f16 conversions (W_xproj padded 96->128 rows with zeros)
    convert_f16_kernel<<<2048, blk, 0, stream>>>(x,      x_h,     4194304, 4194304);
    convert_f16_kernel<<<2048, blk, 0, stream>>>(W_in,   W_inh,   4194304, 4194304);
    convert_f16_kernel<<< 128, blk, 0, stream>>>(W_xproj,W_xprojh, 196608,  262144);
    convert_f16_kernel<<<  64, blk, 0, stream>>>(W_dt,   W_dth,    131072,  131072);
    convert_f16_kernel<<<1024, blk, 0, stream>>>(W_out,  W_outh,  2097152, 2097152);

    // 1) xz = x @ W_in^T     (M=4096, N=4096, K=1024) -> f16
    gemm_mfma<f16, 0, false, false><<<dim3(32, 32), blk, 0, stream>>>(
        x_h, MB_DMODEL, W_inh, MB_DMODEL, xz_h, MB_E2, MB_DMODEL, 0,
        nullptr, nullptr, 0);

    // 2) u = silu(causal_dwconv(xb) + conv_b)
    conv_silu_kernel<<<4096, blk, 0, stream>>>(xz_h, conv_w, conv_b, u_h);

    // 3) x_dbl = u @ W_xproj^T  (M=4096, N=96->128, K=2048)
    //    dual output: f32 [4096][96] for scan B,C; f16 [4096][128] for GEMM4
    gemm_mfma<float, 0, true, true><<<dim3(1, 32), blk, 0, stream>>>(
        u_h, MB_DINNER, W_xprojh, MB_DINNER, xdbl, 96, MB_DINNER, 96,
        nullptr, xdbl_h, 128);

    // 4) delta = softplus(dt_low @ W_dt^T + b_dt)  (M=4096, N=2048, K=64)
    gemm_mfma<f16, 1, false, false><<<dim3(16, 32), blk, 0, stream>>>(
        xdbl_h, 128, W_dth, MB_DTRANK, delta_h, MB_DINNER, MB_DTRANK, 0,
        b_dt, nullptr, 0);

    // 5) selective scan + skip + gate -> yg (f16)
    scan_kernel<<<256, blk, 0, stream>>>(
        delta_h, u_h, xdbl, A_log, Dskip, xz_h, yg_h);

    // 6) out = yg @ W_out^T   (M=4096, N=1024, K=2048) -> f32
    gemm_mfma<float, 0, false, false><<<dim3(8, 32), blk, 0, stream>>>(
        yg_h, MB_DINNER, W_outh, MB_DINNER, out, MB_DMODEL, MB_DINNER, 0,
        nullptr, nullptr, 0);
}

// Round 4
// 476.777 us; speedup vs baseline: 3.9078x; 1.3502x over previous
//
#include <hip/hip_runtime.h>
#include <math.h>

// Mamba block fwd: B=2, L=2048, d_model=1024, d_inner=2048, d_state=16,
// d_conv=4, dt_rank=64.  GEMMs in f16 MFMA (m97 structure), scan fp32.
#define MB_B      2
#define MB_L      2048
#define MB_DMODEL 1024
#define MB_DINNER 2048
#define MB_DSTATE 16
#define MB_DTRANK 64
#define MB_ROWS   (MB_B * MB_L)      // 4096
#define MB_E2     (2 * MB_DINNER)    // 4096

typedef _Float16 f16;
typedef __attribute__((ext_vector_type(8))) _Float16 half8;
typedef __attribute__((ext_vector_type(4))) float floatx4;

__device__ __forceinline__ float softplus_f(float x) {
    return (x > 20.f) ? x : log1pf(expf(x));
}
__device__ __forceinline__ float silu_f(float x) {
    return x / (1.f + expf(-x));
}

// async global->LDS, 16B/lane. LDS dst is WAVE-UNIFORM base; HW adds lane*16.
typedef const __attribute__((address_space(1))) unsigned char gbyte;
typedef __attribute__((address_space(3))) unsigned char lbyte;
__device__ __forceinline__ void gl_lds16(const void* g, void* l) {
    __builtin_amdgcn_global_load_lds((gbyte*)g, (lbyte*)l, 16, 0, 0);
}

// VALU cross-lane add via DPP (off the LDS pipe; ~2-4 cy each).
// After ror8+ror4+xor2+xor1 every lane of the 16-lane row holds the row sum.
template <int CTRL>
__device__ __forceinline__ float dpp_add(float x) {
    int xi = __builtin_bit_cast(int, x);
    int yi = __builtin_amdgcn_update_dpp(0, xi, CTRL, 0xF, 0xF, true);
    return x + __builtin_bit_cast(float, yi);
}

// ---------------------------------------------------------------------------
// fp32 -> f16 convert (8 elems/thread). i >= n_src writes zeros (pad rows).
// ---------------------------------------------------------------------------
__global__ __launch_bounds__(256) void convert_f16_kernel(
    const float* __restrict__ src, f16* __restrict__ dst,
    int n_src, int n_dst)
{
    const int i = (blockIdx.x * 256 + threadIdx.x) * 8;
    if (i >= n_dst) return;
    half8 o;
    if (i < n_src) {
        const float4 a = *reinterpret_cast<const float4*>(src + i);
        const float4 b = *reinterpret_cast<const float4*>(src + i + 4);
        o[0] = (f16)a.x; o[1] = (f16)a.y; o[2] = (f16)a.z; o[3] = (f16)a.w;
        o[4] = (f16)b.x; o[5] = (f16)b.y; o[6] = (f16)b.z; o[7] = (f16)b.w;
    } else {
#pragma unroll
        for (int j = 0; j < 8; j++) o[j] = (f16)0.f;
    }
    *reinterpret_cast<half8*>(dst + i) = o;
}

// ---------------------------------------------------------------------------
// f16 MFMA GEMM:  C[m][n] = sum_k A[m][k]*B[n][k]   (C = A·B^T, f32 accum)
// 128x128 tile, BK=32, 256 threads = 4 waves in 2x2, each wave 64x64 =
// 4x4 grid of 16x16x32 MFMAs. Staging via global_load_lds width=16.
// EPI==1: v = softplus(v + bias[n]).  DUAL: also store f16 to C2.
// NGUARD: store C only when n < Nmax (for N padded to 128).
// ---------------------------------------------------------------------------
template <typename OutT, int EPI, bool NGUARD, bool DUAL>
__global__ __launch_bounds__(256) void gemm_mfma(
    const f16* __restrict__ A, int lda,
    const f16* __restrict__ B, int ldb,
    OutT* __restrict__ C, int ldc, int K, int Nmax,
    const float* __restrict__ bias,
    f16* __restrict__ C2, int ldc2)
{
    __shared__ f16 As[128 * 32];   // [row][k], row stride 32 halves (64 B)
    __shared__ f16 Bs[128 * 32];

    const int tid  = threadIdx.x;
    const int lane = tid & 63;
    const int wave = tid >> 6;
    const int wr   = wave >> 1, wc = wave & 1;
    const int bm   = blockIdx.y * 128, bn = blockIdx.x * 128;

    floatx4 zero4 = {0.f, 0.f, 0.f, 0.f};
    floatx4 acc[4][4];
#pragma unroll
    for (int i = 0; i < 4; i++)
#pragma unroll
        for (int j = 0; j < 4; j++) acc[i][j] = zero4;

    const int srow = lane >> 2;
    const int scol = (lane & 3) * 8;
    const f16* gA0 = A + (size_t)(bm + wave * 32 + srow) * lda + scol;
    const f16* gA1 = A + (size_t)(bm + wave * 32 + 16 + srow) * lda + scol;
    const f16* gB0 = B + (size_t)(bn + wave * 32 + srow) * ldb + scol;
    const f16* gB1 = B + (size_t)(bn + wave * 32 + 16 + srow) * ldb + scol;
    f16* lA0 = As + wave * 1024;
    f16* lA1 = As + wave * 1024 + 512;
    f16* lB0 = Bs + wave * 1024;
    f16* lB1 = Bs + wave * 1024 + 512;

    const int mr = lane & 15;
    const int kq = (lane >> 4) * 8;

    for (int k0 = 0; k0 < K; k0 += 32) {
        gl_lds16(gA0 + k0, lA0);
        gl_lds16(gA1 + k0, lA1);
        gl_lds16(gB0 + k0, lB0);
        gl_lds16(gB1 + k0, lB1);
        __syncthreads();   // drains vmcnt; LDS tiles visible

        half8 af[4], bf[4];
#pragma unroll
        for (int mt = 0; mt < 4; mt++)
            af[mt] = *reinterpret_cast<const half8*>(
                As + (wr * 64 + mt * 16 + mr) * 32 + kq);
#pragma unroll
        for (int nt = 0; nt < 4; nt++)
            bf[nt] = *reinterpret_cast<const half8*>(
                Bs + (wc * 64 + nt * 16 + mr) * 32 + kq);
#pragma unroll
        for (int mt = 0; mt < 4; mt++)
#pragma unroll
            for (int nt = 0; nt < 4; nt++)
                acc[mt][nt] = __builtin_amdgcn_mfma_f32_16x16x32_f16(
                    af[mt], bf[nt], acc[mt][nt], 0, 0, 0);
        __syncthreads();   // all reads done before next stage overwrites
    }

    // Epilogue. C/D layout (verified m89): col = lane&15, row = quad*4+reg.
    const int rbase = (lane >> 4) * 4;
#pragma unroll
    for (int mt = 0; mt < 4; mt++) {
        const int row0 = bm + wr * 64 + mt * 16 + rbase;
#pragma unroll
        for (int nt = 0; nt < 4; nt++) {
            const int col = bn + wc * 64 + nt * 16 + mr;
#pragma unroll
            for (int r = 0; r < 4; r++) {
                float v = acc[mt][nt][r];
                if constexpr (EPI == 1) v = softplus_f(v + bias[col]);
                if constexpr (DUAL)
                    C2[(size_t)(row0 + r) * ldc2 + col] = (f16)v;
                if (!NGUARD || col < Nmax)
                    C[(size_t)(row0 + r) * ldc + col] = (OutT)v;
            }
        }
    }
}

// ---------------------------------------------------------------------------
// Causal depthwise conv1d (width 4) + bias + SiLU.  f16 in/out.
// ---------------------------------------------------------------------------
__global__ __launch_bounds__(256) void conv_silu_kernel(
    const f16* __restrict__ xz, const float* __restrict__ cw,
    const float* __restrict__ cb, f16* __restrict__ u)
{
    const int idx = blockIdx.x * 256 + threadIdx.x;  // 4096 rows * 256
    const int dv  = (idx & 255) * 8;
    const int row = idx >> 8;
    const int l   = row & (MB_L - 1);

    float acc[8];
#pragma unroll
    for (int j = 0; j < 8; j++) acc[j] = cb[dv + j];
#pragma unroll
    for (int k = 0; k < 4; k++) {
        if (l - 3 + k >= 0) {
            const half8 xv = *reinterpret_cast<const half8*>(
                xz + (size_t)(row - 3 + k) * MB_E2 + dv);
#pragma unroll
            for (int j = 0; j < 8; j++)
                acc[j] = fmaf((float)xv[j], cw[(dv + j) * 4 + k], acc[j]);
        }
    }
    half8 r;
#pragma unroll
    for (int j = 0; j < 8; j++) r[j] = (f16)silu_f(acc[j]);
    *reinterpret_cast<half8*>(u + (size_t)row * MB_DINNER + dv) = r;
}

// ---------------------------------------------------------------------------
// Selective scan + skip + gate, register-resident serial loop.
// Lane (cg,n): tid = cg*16+n; 16 channels/block, 256 blocks = 1 wave/SIMD.
// Per 32-step chunk:
//   1. bulk LDS->reg: du[32] (chan row), bc[32] (state row), gs[32] (chan row)
//      via ds_read_b128 from [chan/state][step] transposed layout
//   2. global prefetch of next chunk into regs (in flight during loop)
//   3. serial loop on REGISTERS ONLY: exp, fma-chain on h, 4 DPP adds,
//      y = fma(p, g, s) selected into y0/y1 by cndmask (no LDS in loop)
//   4. 2 scattered f16 y-stores; commit prefetch regs -> LDS; barrier
// g = silu(z), s = u*Dskip*g precomputed at staging time (parallel).
// ---------------------------------------------------------------------------
__global__ __launch_bounds__(256) void scan_kernel(
    const f16*  __restrict__ delta,   // [4096][2048]
    const f16*  __restrict__ u,       // [4096][2048]
    const float* __restrict__ xdbl,   // [4096][96]  (dt|B|C)
    const float* __restrict__ A_log,  // [2048][16]
    const float* __restrict__ Dskip,  // [2048]
    const f16*  __restrict__ xz,      // z = cols [2048,4096)
    f16* __restrict__ yg)             // [4096][2048]
{
    constexpr int CL = 32;
    // [channel/state][step], +2 pad -> 272 B rows: 16B-aligned, <=2-way banks
    __shared__ float2 sDU[16][CL + 2];
    __shared__ float2 sBC[16][CL + 2];
    __shared__ float2 sGS[16][CL + 2];

    const int tid = threadIdx.x;
    const int n   = tid & 15;
    const int cg  = tid >> 4;                      // channel within block
    const int gchan = blockIdx.x * 16 + cg;
    const int b     = gchan >> 11;
    const int dbase = (blockIdx.x & 127) * 16;

    const size_t base2048 = (size_t)b * MB_L * MB_DINNER;
    const size_t base4096 = (size_t)b * MB_L * MB_E2;
    const size_t base96   = (size_t)b * MB_L * 96;

    const int d = gchan & (MB_DINNER - 1);
    const float Av = -expf(A_log[d * MB_DSTATE + n]);
    float h = 0.f;
    const float Dsk_s = Dskip[dbase + (tid & 15)];

    float pd[2], pu[2], pb[2], pc[2], pz[2];

    auto stage_load = [&](int l0) {
#pragma unroll
        for (int r = 0; r < 2; r++) {
            const int e = tid + r * 256;
            const int lloc = e >> 4, cc = e & 15;
            const size_t row = (size_t)(l0 + lloc);
            pd[r] = (float)delta[base2048 + row * MB_DINNER + dbase + cc];
            pu[r] = (float)u[base2048 + row * MB_DINNER + dbase + cc];
            pb[r] = xdbl[base96 + row * 96 + MB_DTRANK + cc];
            pc[r] = xdbl[base96 + row * 96 + MB_DTRANK + MB_DSTATE + cc];
            pz[r] = (float)xz[base4096 + row * MB_E2 + MB_DINNER + dbase + cc];
        }
    };
    auto stage_write = [&]() {
#pragma unroll
        for (int r = 0; r < 2; r++) {
            const int e = tid + r * 256;
            const int lloc = e >> 4, cc = e & 15;
            sDU[cc][lloc] = make_float2(pd[r], pu[r]);
            sBC[cc][lloc] = make_float2(pb[r], pc[r]);
            const float g = silu_f(pz[r]);
            sGS[cc][lloc] = make_float2(g, pu[r] * Dsk_s * g);
        }
    };

    stage_load(0);
    stage_write();
    __syncthreads();

    for (int l0 = 0; l0 < MB_L; l0 += CL) {
        // 1) bulk LDS -> registers (latency amortized over 48 wide reads;
        //    du/gs broadcast within 16-lane group, bc broadcast across groups)
        float2 du[CL], bc[CL], gs[CL];
#pragma unroll
        for (int kk = 0; kk < CL / 2; kk++) {
            *reinterpret_cast<float4*>(&du[kk * 2]) =
                *reinterpret_cast<const float4*>(&sDU[cg][kk * 2]);
            *reinterpret_cast<float4*>(&bc[kk * 2]) =
                *reinterpret_cast<const float4*>(&sBC[n][kk * 2]);
            *reinterpret_cast<float4*>(&gs[kk * 2]) =
                *reinterpret_cast<const float4*>(&sGS[cg][kk * 2]);
        }
        __syncthreads();   // all waves done reading LDS

        const bool has_next = (l0 + CL) < MB_L;
        if (has_next) stage_load(l0 + CL);   // in flight during serial loop

        // 3) serial recurrence, registers only
        float y0 = 0.f, y1 = 0.f;
#pragma unroll
        for (int ll = 0; ll < CL; ll++) {
            const float dA = __expf(du[ll].x * Av);
            h = fmaf(dA, h, du[ll].x * du[ll].y * bc[ll].x);
            float p = h * bc[ll].y;
            p = dpp_add<0x128>(p);   // row_ror:8
            p = dpp_add<0x124>(p);   // row_ror:4
            p = dpp_add<0x4E>(p);    // quad_perm xor2
            p = dpp_add<0xB1>(p);    // quad_perm xor1  (all 16 lanes = sum)
            const float yv = fmaf(p, gs[ll].x, gs[ll].y);
            if (ll < 16) y0 = (n == ll) ? yv : y0;
            else         y1 = (n == ll - 16) ? yv : y1;
        }

        // 4) scattered f16 stores: lane n owns rows l0+n, l0+n+16 of col gchan
        yg[base2048 + (size_t)(l0 + n) * MB_DINNER + dbase + cg] = (f16)y0;
        yg[base2048 + (size_t)(l0 + n + 16) * MB_DINNER + dbase + cg] = (f16)y1;

        if (has_next) stage_write();
        __syncthreads();
    }
}

// ---------------------------------------------------------------------------
extern "C" void kernel_launch(void* const* d_in, const int* in_sizes, int n_in,
                              void* d_out, int out_size, void* d_ws,
                              size_t ws_size, hipStream_t stream)
{
    const float* x      = (const float*)d_in[0];  // (2,2048,1024)
    const float* W_in   = (const float*)d_in[1];  // (4096,1024)
    const float* conv_w = (const float*)d_in[2];  // (2048,1,4)
    const float* conv_b = (const float*)d_in[3];  // (2048)
    const float* W_xproj= (const float*)d_in[4];  // (96,2048)
    const float* W_dt   = (const float*)d_in[5];  // (2048,64)
    const float* b_dt   = (const float*)d_in[6];  // (2048)
    const float* A_log  = (const float*)d_in[7];  // (2048,16)
    const float* Dskip  = (const float*)d_in[8];  // (2048)
    const float* W_out  = (const float*)d_in[9];  // (1024,2048)
    float* out = (float*)d_out;                   // (2,2048,1024)

    // Workspace (~108 MB), all 16B-aligned chunks.
    char* p = (char*)d_ws;
    f16* xz_h    = (f16*)p;  p += (size_t)MB_ROWS * MB_E2 * 2;      // 33.6 MB
    f16* u_h     = (f16*)p;  p += (size_t)MB_ROWS * MB_DINNER * 2;  // 16.8 MB
    f16* delta_h = (f16*)p;  p += (size_t)MB_ROWS * MB_DINNER * 2;  // 16.8 MB
    f16* yg_h    = (f16*)p;  p += (size_t)MB_ROWS * MB_DINNER * 2;  // 16.8 MB
    float* xdbl  = (float*)p; p += (size_t)MB_ROWS * 96 * 4;        // 1.6 MB
    f16* xdbl_h  = (f16*)p;  p += (size_t)MB_ROWS * 128 * 2;        // 1.0 MB
    f16* x_h     = (f16*)p;  p += (size_t)MB_ROWS * MB_DMODEL * 2;  // 8.4 MB
    f16* W_inh   = (f16*)p;  p += (size_t)MB_E2 * MB_DMODEL * 2;    // 8.4 MB
    f16* W_xprojh= (f16*)p;  p += (size_t)128 * MB_DINNER * 2;      // 0.5 MB
    f16* W_dth   = (f16*)p;  p += (size_t)MB_DINNER * MB_DTRANK * 2;// 0.26 MB
    f16* W_outh  = (f16*)p;                                          // 4.2 MB

    const dim3 blk(256);

    // 0) fp32 -> f16 conversions (W_xproj padded 96->128 rows with zeros)
    convert_f16_kernel<<<2048, blk, 0, stream>>>(x,      x_h,     4194304, 4194304);
    convert_f16_kernel<<<2048, blk, 0, stream>>>(W_in,   W_inh,   4194304, 4194304);
    convert_f16_kernel<<< 128, blk, 0, stream>>>(W_xproj,W_xprojh, 196608,  262144);
    convert_f16_kernel<<<  64, blk, 0, stream>>>(W_dt,   W_dth,    131072,  131072);
    convert_f16_kernel<<<1024, blk, 0, stream>>>(W_out,  W_outh,  2097152, 2097152);

    // 1) xz = x @ W_in^T     (M=4096, N=4096, K=1024) -> f16
    gemm_mfma<f16, 0, false, false><<<dim3(32, 32), blk, 0, stream>>>(
        x_h, MB_DMODEL, W_inh, MB_DMODEL, xz_h, MB_E2, MB_DMODEL, 0,
        nullptr, nullptr, 0);

    // 2) u = silu(causal_dwconv(xb) + conv_b)
    conv_silu_kernel<<<4096, blk, 0, stream>>>(xz_h, conv_w, conv_b, u_h);

    // 3) x_dbl = u @ W_xproj^T  (M=4096, N=96->128, K=2048)
    gemm_mfma<float, 0, true, true><<<dim3(1, 32), blk, 0, stream>>>(
        u_h, MB_DINNER, W_xprojh, MB_DINNER, xdbl, 96, MB_DINNER, 96,
        nullptr, xdbl_h, 128);

    // 4) delta = softplus(dt_low @ W_dt^T + b_dt)  (M=4096, N=2048, K=64)
    gemm_mfma<f16, 1, false, false><<<dim3(16, 32), blk, 0, stream>>>(
        xdbl_h, 128, W_dth, MB_DTRANK, delta_h, MB_DINNER, MB_DTRANK, 0,
        b_dt, nullptr, 0);

    // 5) selective scan + skip + gate -> yg (f16)
    scan_kernel<<<256, blk, 0, stream>>>(
        delta_h, u_h, xdbl, A_log, Dskip, xz_h, yg_h);

    // 6) out = yg @ W_out^T   (M=4096, N=1024, K=2048) -> f32
    gemm_mfma<float, 0, false, false><<<dim3(8, 32), blk, 0, stream>>>(
        yg_h, MB_DINNER, W_outh, MB_DINNER, out, MB_DMODEL, MB_DINNER, 0,
        nullptr, nullptr, 0);
}

// Round 5
// 449.317 us; speedup vs baseline: 4.1466x; 1.0611x over previous
//
#include <hip/hip_runtime.h>
#include <math.h>

// Mamba block fwd: B=2, L=2048, d_model=1024, d_inner=2048, d_state=16,
// d_conv=4, dt_rank=64.  GEMMs in f16 MFMA, scan fp32 chunked 2-pass.
#define MB_B      2
#define MB_L      2048
#define MB_DMODEL 1024
#define MB_DINNER 2048
#define MB_DSTATE 16
#define MB_DTRANK 64
#define MB_ROWS   (MB_B * MB_L)      // 4096
#define MB_E2     (2 * MB_DINNER)    // 4096
#define SC_NC     8                  // scan chunks
#define SC_CHUNK  (MB_L / SC_NC)     // 256 steps per chunk

typedef _Float16 f16;
typedef __attribute__((ext_vector_type(8))) _Float16 half8;
typedef __attribute__((ext_vector_type(4))) float floatx4;

__device__ __forceinline__ float softplus_f(float x) {
    return (x > 20.f) ? x : log1pf(expf(x));
}
__device__ __forceinline__ float silu_f(float x) {
    return x / (1.f + expf(-x));
}

// async global->LDS, 16B/lane. LDS dst is WAVE-UNIFORM base; HW adds lane*16.
typedef const __attribute__((address_space(1))) unsigned char gbyte;
typedef __attribute__((address_space(3))) unsigned char lbyte;
__device__ __forceinline__ void gl_lds16(const void* g, void* l) {
    __builtin_amdgcn_global_load_lds((gbyte*)g, (lbyte*)l, 16, 0, 0);
}

// VALU cross-lane add via DPP. After ror8+ror4+xor2+xor1 every lane of a
// 16-lane row holds the row sum.
template <int CTRL>
__device__ __forceinline__ float dpp_add(float x) {
    int xi = __builtin_bit_cast(int, x);
    int yi = __builtin_amdgcn_update_dpp(0, xi, CTRL, 0xF, 0xF, true);
    return x + __builtin_bit_cast(float, yi);
}

// ---------------------------------------------------------------------------
// Single fused fp32 -> f16 convert over all weight/activation segments.
// Destinations are laid out CONTIGUOUSLY in ws (x_h|W_inh|W_xprojh|W_dth|
// W_outh), so one flat index covers everything; W_xproj pads 196608->262144
// with zeros.  All boundaries are multiples of 8.
// ---------------------------------------------------------------------------
__global__ __launch_bounds__(256) void convert_all_kernel(
    const float* __restrict__ x, const float* __restrict__ W_in,
    const float* __restrict__ W_xproj, const float* __restrict__ W_dt,
    const float* __restrict__ W_out, f16* __restrict__ dst)
{
    const int i = (blockIdx.x * 256 + threadIdx.x) * 8;  // < 10878976
    const float* src;
    int local, nsrc;
    if (i < 4194304)      { src = x;       local = i;           nsrc = 4194304; }
    else if (i < 8388608) { src = W_in;    local = i - 4194304; nsrc = 4194304; }
    else if (i < 8650752) { src = W_xproj; local = i - 8388608; nsrc = 196608; }
    else if (i < 8781824) { src = W_dt;    local = i - 8650752; nsrc = 131072; }
    else                  { src = W_out;   local = i - 8781824; nsrc = 2097152; }
    half8 o;
    if (local < nsrc) {
        const float4 a = *reinterpret_cast<const float4*>(src + local);
        const float4 b = *reinterpret_cast<const float4*>(src + local + 4);
        o[0] = (f16)a.x; o[1] = (f16)a.y; o[2] = (f16)a.z; o[3] = (f16)a.w;
        o[4] = (f16)b.x; o[5] = (f16)b.y; o[6] = (f16)b.z; o[7] = (f16)b.w;
    } else {
#pragma unroll
        for (int j = 0; j < 8; j++) o[j] = (f16)0.f;
    }
    *reinterpret_cast<half8*>(dst + i) = o;
}

// ---------------------------------------------------------------------------
// f16 MFMA GEMM:  C[m][n] = sum_k A[m][k]*B[n][k]   (C = A·B^T, f32 accum)
// 128x128 tile, BK=32, 4 waves in 2x2, global_load_lds width=16 staging.
// EPI==1: v = softplus(v + bias[n]).  DUAL: also store f16 to C2.
// NGUARD: store C only when n < Nmax (for N padded to 128).
// ---------------------------------------------------------------------------
template <typename OutT, int EPI, bool NGUARD, bool DUAL>
__global__ __launch_bounds__(256) void gemm_mfma(
    const f16* __restrict__ A, int lda,
    const f16* __restrict__ B, int ldb,
    OutT* __restrict__ C, int ldc, int K, int Nmax,
    const float* __restrict__ bias,
    f16* __restrict__ C2, int ldc2)
{
    __shared__ f16 As[128 * 32];   // [row][k], row stride 32 halves (64 B)
    __shared__ f16 Bs[128 * 32];

    const int tid  = threadIdx.x;
    const int lane = tid & 63;
    const int wave = tid >> 6;
    const int wr   = wave >> 1, wc = wave & 1;
    const int bm   = blockIdx.y * 128, bn = blockIdx.x * 128;

    floatx4 zero4 = {0.f, 0.f, 0.f, 0.f};
    floatx4 acc[4][4];
#pragma unroll
    for (int i = 0; i < 4; i++)
#pragma unroll
        for (int j = 0; j < 4; j++) acc[i][j] = zero4;

    const int srow = lane >> 2;
    const int scol = (lane & 3) * 8;
    const f16* gA0 = A + (size_t)(bm + wave * 32 + srow) * lda + scol;
    const f16* gA1 = A + (size_t)(bm + wave * 32 + 16 + srow) * lda + scol;
    const f16* gB0 = B + (size_t)(bn + wave * 32 + srow) * ldb + scol;
    const f16* gB1 = B + (size_t)(bn + wave * 32 + 16 + srow) * ldb + scol;
    f16* lA0 = As + wave * 1024;
    f16* lA1 = As + wave * 1024 + 512;
    f16* lB0 = Bs + wave * 1024;
    f16* lB1 = Bs + wave * 1024 + 512;

    const int mr = lane & 15;
    const int kq = (lane >> 4) * 8;

    for (int k0 = 0; k0 < K; k0 += 32) {
        gl_lds16(gA0 + k0, lA0);
        gl_lds16(gA1 + k0, lA1);
        gl_lds16(gB0 + k0, lB0);
        gl_lds16(gB1 + k0, lB1);
        __syncthreads();   // drains vmcnt; LDS tiles visible

        half8 af[4], bf[4];
#pragma unroll
        for (int mt = 0; mt < 4; mt++)
            af[mt] = *reinterpret_cast<const half8*>(
                As + (wr * 64 + mt * 16 + mr) * 32 + kq);
#pragma unroll
        for (int nt = 0; nt < 4; nt++)
            bf[nt] = *reinterpret_cast<const half8*>(
                Bs + (wc * 64 + nt * 16 + mr) * 32 + kq);
#pragma unroll
        for (int mt = 0; mt < 4; mt++)
#pragma unroll
            for (int nt = 0; nt < 4; nt++)
                acc[mt][nt] = __builtin_amdgcn_mfma_f32_16x16x32_f16(
                    af[mt], bf[nt], acc[mt][nt], 0, 0, 0);
        __syncthreads();   // all reads done before next stage overwrites
    }

    // Epilogue. C/D layout (verified m89): col = lane&15, row = quad*4+reg.
    const int rbase = (lane >> 4) * 4;
#pragma unroll
    for (int mt = 0; mt < 4; mt++) {
        const int row0 = bm + wr * 64 + mt * 16 + rbase;
#pragma unroll
        for (int nt = 0; nt < 4; nt++) {
            const int col = bn + wc * 64 + nt * 16 + mr;
#pragma unroll
            for (int r = 0; r < 4; r++) {
                float v = acc[mt][nt][r];
                if constexpr (EPI == 1) v = softplus_f(v + bias[col]);
                if constexpr (DUAL)
                    C2[(size_t)(row0 + r) * ldc2 + col] = (f16)v;
                if (!NGUARD || col < Nmax)
                    C[(size_t)(row0 + r) * ldc + col] = (OutT)v;
            }
        }
    }
}

// ---------------------------------------------------------------------------
// Causal depthwise conv1d (width 4) + bias + SiLU.  f16 in/out.
// ---------------------------------------------------------------------------
__global__ __launch_bounds__(256) void conv_silu_kernel(
    const f16* __restrict__ xz, const float* __restrict__ cw,
    const float* __restrict__ cb, f16* __restrict__ u)
{
    const int idx = blockIdx.x * 256 + threadIdx.x;  // 4096 rows * 256
    const int dv  = (idx & 255) * 8;
    const int row = idx >> 8;
    const int l   = row & (MB_L - 1);

    float acc[8];
#pragma unroll
    for (int j = 0; j < 8; j++) acc[j] = cb[dv + j];
#pragma unroll
    for (int k = 0; k < 4; k++) {
        if (l - 3 + k >= 0) {
            const half8 xv = *reinterpret_cast<const half8*>(
                xz + (size_t)(row - 3 + k) * MB_E2 + dv);
#pragma unroll
            for (int j = 0; j < 8; j++)
                acc[j] = fmaf((float)xv[j], cw[(dv + j) * 4 + k], acc[j]);
        }
    }
    half8 r;
#pragma unroll
    for (int j = 0; j < 8; j++) r[j] = (f16)silu_f(acc[j]);
    *reinterpret_cast<half8*>(u + (size_t)row * MB_DINNER + dv) = r;
}

// ---------------------------------------------------------------------------
// Chunked selective scan, pass 1: per chunk of 256 steps, run the recurrence
// from h=0 and emit H = local final state and P = prod(dA) = exp(Av*sum dt).
// Grid 2048 blocks (= 8 chunks x 256 channel-blocks) -> 8 waves/SIMD: all
// load/exp/fma latencies hidden by co-resident waves (vs 1 wave/SIMD before).
// Lane (cg,n): tid = cg*16+n.
// ---------------------------------------------------------------------------
__global__ __launch_bounds__(256) void scan_pass1(
    const f16*  __restrict__ delta,   // [4096][2048]
    const f16*  __restrict__ u,       // [4096][2048]
    const float* __restrict__ xdbl,   // [4096][96]  (dt|B|C)
    const float* __restrict__ A_log,  // [2048][16]
    float* __restrict__ Hc,           // [8][4096][16]
    float* __restrict__ Pc)           // [8][4096][16]
{
    constexpr int CL = 32;
    __shared__ float2 sDU[16][CL + 2];
    __shared__ float  sB[16][CL + 2];

    const int tid   = threadIdx.x;
    const int n     = tid & 15;
    const int cg    = tid >> 4;
    const int cb    = blockIdx.x & 255;
    const int chunk = blockIdx.x >> 8;
    const int gchan = cb * 16 + cg;
    const int b     = gchan >> 11;
    const int dbase = (cb & 127) * 16;
    const int d     = gchan & (MB_DINNER - 1);
    const int lbeg  = chunk * SC_CHUNK;

    const size_t base2048 = (size_t)b * MB_L * MB_DINNER;
    const size_t base96   = (size_t)b * MB_L * 96;

    const float Av = -expf(A_log[d * MB_DSTATE + n]);
    float h = 0.f, sdt = 0.f;
    float pd[2], pu[2], pb[2];

    auto stage_load = [&](int l0) {
#pragma unroll
        for (int r = 0; r < 2; r++) {
            const int e = tid + r * 256;
            const int lloc = e >> 4, cc = e & 15;
            const size_t row = (size_t)(l0 + lloc);
            pd[r] = (float)delta[base2048 + row * MB_DINNER + dbase + cc];
            pu[r] = (float)u[base2048 + row * MB_DINNER + dbase + cc];
            pb[r] = xdbl[base96 + row * 96 + MB_DTRANK + cc];
        }
    };
    auto stage_write = [&]() {
#pragma unroll
        for (int r = 0; r < 2; r++) {
            const int e = tid + r * 256;
            const int lloc = e >> 4, cc = e & 15;
            sDU[cc][lloc] = make_float2(pd[r], pu[r]);
            sB[cc][lloc]  = pb[r];
        }
    };

    stage_load(lbeg);
    stage_write();
    __syncthreads();

    for (int l0 = lbeg; l0 < lbeg + SC_CHUNK; l0 += CL) {
        const bool has_next = (l0 + CL) < lbeg + SC_CHUNK;
        if (has_next) stage_load(l0 + CL);

#pragma unroll
        for (int ll = 0; ll < CL; ll++) {
            const float2 du = sDU[cg][ll];
            const float bv = sB[n][ll];
            const float dA = __expf(du.x * Av);
            h = fmaf(dA, h, du.x * du.y * bv);
            sdt += du.x;
        }
        __syncthreads();
        if (has_next) stage_write();
        __syncthreads();
    }

    const size_t cidx = ((size_t)chunk * MB_ROWS + gchan) * MB_DSTATE + n;
    Hc[cidx] = h;
    Pc[cidx] = __expf(Av * sdt);
}

// ---------------------------------------------------------------------------
// Chunked selective scan, pass 2: reconstruct h at chunk start via
// h = P_j*h + H_j over preceding chunks (<=7 fma, coalesced loads), then
// replay the chunk computing y with skip+gate.  Same 8-waves/SIMD grid.
// ---------------------------------------------------------------------------
__global__ __launch_bounds__(256) void scan_pass2(
    const f16*  __restrict__ delta,   // [4096][2048]
    const f16*  __restrict__ u,       // [4096][2048]
    const float* __restrict__ xdbl,   // [4096][96]  (dt|B|C)
    const float* __restrict__ A_log,  // [2048][16]
    const float* __restrict__ Dskip,  // [2048]
    const f16*  __restrict__ xz,      // z = cols [2048,4096)
    const float* __restrict__ Hc,     // [8][4096][16]
    const float* __restrict__ Pc,     // [8][4096][16]
    f16* __restrict__ yg)             // [4096][2048]
{
    constexpr int CL = 32;
    __shared__ float2 sDU[16][CL + 2];
    __shared__ float2 sBC[16][CL + 2];
    __shared__ float2 sGS[16][CL + 2];

    const int tid   = threadIdx.x;
    const int n     = tid & 15;
    const int cg    = tid >> 4;
    const int cb    = blockIdx.x & 255;
    const int chunk = blockIdx.x >> 8;
    const int gchan = cb * 16 + cg;
    const int b     = gchan >> 11;
    const int dbase = (cb & 127) * 16;
    const int d     = gchan & (MB_DINNER - 1);
    const int lbeg  = chunk * SC_CHUNK;

    const size_t base2048 = (size_t)b * MB_L * MB_DINNER;
    const size_t base4096 = (size_t)b * MB_L * MB_E2;
    const size_t base96   = (size_t)b * MB_L * 96;

    const float Av = -expf(A_log[d * MB_DSTATE + n]);
    const float Dsk_s = Dskip[dbase + (tid & 15)];

    // carry-in: h after chunks 0..chunk-1 (uniform trip count per block)
    float h = 0.f;
    for (int j = 0; j < chunk; j++) {
        const size_t cidx = ((size_t)j * MB_ROWS + gchan) * MB_DSTATE + n;
        h = fmaf(Pc[cidx], h, Hc[cidx]);
    }

    float pd[2], pu[2], pb[2], pc[2], pz[2];

    auto stage_load = [&](int l0) {
#pragma unroll
        for (int r = 0; r < 2; r++) {
            const int e = tid + r * 256;
            const int lloc = e >> 4, cc = e & 15;
            const size_t row = (size_t)(l0 + lloc);
            pd[r] = (float)delta[base2048 + row * MB_DINNER + dbase + cc];
            pu[r] = (float)u[base2048 + row * MB_DINNER + dbase + cc];
            pb[r] = xdbl[base96 + row * 96 + MB_DTRANK + cc];
            pc[r] = xdbl[base96 + row * 96 + MB_DTRANK + MB_DSTATE + cc];
            pz[r] = (float)xz[base4096 + row * MB_E2 + MB_DINNER + dbase + cc];
        }
    };
    auto stage_write = [&]() {
#pragma unroll
        for (int r = 0; r < 2; r++) {
            const int e = tid + r * 256;
            const int lloc = e >> 4, cc = e & 15;
            sDU[cc][lloc] = make_float2(pd[r], pu[r]);
            sBC[cc][lloc] = make_float2(pb[r], pc[r]);
            const float g = silu_f(pz[r]);
            sGS[cc][lloc] = make_float2(g, pu[r] * Dsk_s * g);
        }
    };

    stage_load(lbeg);
    stage_write();
    __syncthreads();

    for (int l0 = lbeg; l0 < lbeg + SC_CHUNK; l0 += CL) {
        const bool has_next = (l0 + CL) < lbeg + SC_CHUNK;
        if (has_next) stage_load(l0 + CL);

        float y0 = 0.f, y1 = 0.f;
#pragma unroll
        for (int ll = 0; ll < CL; ll++) {
            const float2 du = sDU[cg][ll];
            const float2 bc = sBC[n][ll];
            const float2 gs = sGS[cg][ll];
            const float dA = __expf(du.x * Av);
            h = fmaf(dA, h, du.x * du.y * bc.x);
            float p = h * bc.y;
            p = dpp_add<0x128>(p);   // row_ror:8
            p = dpp_add<0x124>(p);   // row_ror:4
            p = dpp_add<0x4E>(p);    // quad_perm xor2
            p = dpp_add<0xB1>(p);    // quad_perm xor1 (all 16 lanes = sum)
            const float yv = fmaf(p, gs.x, gs.y);
            if (ll < 16) y0 = (n == ll) ? yv : y0;
            else         y1 = (n == ll - 16) ? yv : y1;
        }

        // lane n owns rows l0+n, l0+n+16 of column gchan
        yg[base2048 + (size_t)(l0 + n) * MB_DINNER + dbase + cg] = (f16)y0;
        yg[base2048 + (size_t)(l0 + n + 16) * MB_DINNER + dbase + cg] = (f16)y1;

        __syncthreads();
        if (has_next) stage_write();
        __syncthreads();
    }
}

// ---------------------------------------------------------------------------
extern "C" void kernel_launch(void* const* d_in, const int* in_sizes, int n_in,
                              void* d_out, int out_size, void* d_ws,
                              size_t ws_size, hipStream_t stream)
{
    const float* x      = (const float*)d_in[0];  // (2,2048,1024)
    const float* W_in   = (const float*)d_in[1];  // (4096,1024)
    const float* conv_w = (const float*)d_in[2];  // (2048,1,4)
    const float* conv_b = (const float*)d_in[3];  // (2048)
    const float* W_xproj= (const float*)d_in[4];  // (96,2048)
    const float* W_dt   = (const float*)d_in[5];  // (2048,64)
    const float* b_dt   = (const float*)d_in[6];  // (2048)
    const float* A_log  = (const float*)d_in[7];  // (2048,16)
    const float* Dskip  = (const float*)d_in[8];  // (2048)
    const float* W_out  = (const float*)d_in[9];  // (1024,2048)
    float* out = (float*)d_out;                   // (2,2048,1024)

    // Workspace (~113 MB), all 16B-aligned chunks.  The five f16 convert
    // destinations (x_h..W_outh) are CONTIGUOUS for the fused convert.
    char* p = (char*)d_ws;
    f16* xz_h    = (f16*)p;  p += (size_t)MB_ROWS * MB_E2 * 2;      // 33.6 MB
    f16* u_h     = (f16*)p;  p += (size_t)MB_ROWS * MB_DINNER * 2;  // 16.8 MB
    f16* delta_h = (f16*)p;  p += (size_t)MB_ROWS * MB_DINNER * 2;  // 16.8 MB
    f16* yg_h    = (f16*)p;  p += (size_t)MB_ROWS * MB_DINNER * 2;  // 16.8 MB
    float* xdbl  = (float*)p; p += (size_t)MB_ROWS * 96 * 4;        // 1.6 MB
    f16* xdbl_h  = (f16*)p;  p += (size_t)MB_ROWS * 128 * 2;        // 1.0 MB
    f16* x_h     = (f16*)p;  p += (size_t)MB_ROWS * MB_DMODEL * 2;  // 8.4 MB
    f16* W_inh   = (f16*)p;  p += (size_t)MB_E2 * MB_DMODEL * 2;    // 8.4 MB
    f16* W_xprojh= (f16*)p;  p += (size_t)128 * MB_DINNER * 2;      // 0.5 MB
    f16* W_dth   = (f16*)p;  p += (size_t)MB_DINNER * MB_DTRANK * 2;// 0.26 MB
    f16* W_outh  = (f16*)p;  p += (size_t)MB_DMODEL * MB_DINNER * 2;// 4.2 MB
    float* Hc    = (float*)p; p += (size_t)SC_NC * MB_ROWS * MB_DSTATE * 4; // 2.1 MB
    float* Pc    = (float*)p;                                        // 2.1 MB

    const dim3 blk(256);

    // 0) one fused fp32 -> f16 convert over all segments (10878976 elems)
    convert_all_kernel<<<5312, blk, 0, stream>>>(
        x, W_in, W_xproj, W_dt, W_out, x_h);

    // 1) xz = x @ W_in^T     (M=4096, N=4096, K=1024) -> f16
    gemm_mfma<f16, 0, false, false><<<dim3(32, 32), blk, 0, stream>>>(
        x_h, MB_DMODEL, W_inh, MB_DMODEL, xz_h, MB_E2, MB_DMODEL, 0,
        nullptr, nullptr, 0);

    // 2) u = silu(causal_dwconv(xb) + conv_b)
    conv_silu_kernel<<<4096, blk, 0, stream>>>(xz_h, conv_w, conv_b, u_h);

    // 3) x_dbl = u @ W_xproj^T  (M=4096, N=96->128, K=2048)
    gemm_mfma<float, 0, true, true><<<dim3(1, 32), blk, 0, stream>>>(
        u_h, MB_DINNER, W_xprojh, MB_DINNER, xdbl, 96, MB_DINNER, 96,
        nullptr, xdbl_h, 128);

    // 4) delta = softplus(dt_low @ W_dt^T + b_dt)  (M=4096, N=2048, K=64)
    gemm_mfma<f16, 1, false, false><<<dim3(16, 32), blk, 0, stream>>>(
        xdbl_h, 128, W_dth, MB_DTRANK, delta_h, MB_DINNER, MB_DTRANK, 0,
        b_dt, nullptr, 0);

    // 5a) scan pass 1: per-chunk (H, P) summaries at 8 waves/SIMD
    scan_pass1<<<SC_NC * 256, blk, 0, stream>>>(
        delta_h, u_h, xdbl, A_log, Hc, Pc);

    // 5b) scan pass 2: carry-combine + replay with y/skip/gate -> yg (f16)
    scan_pass2<<<SC_NC * 256, blk, 0, stream>>>(
        delta_h, u_h, xdbl, A_log, Dskip, xz_h, Hc, Pc, yg_h);

    // 6) out = yg @ W_out^T   (M=4096, N=1024, K=2048) -> f32
    gemm_mfma<float, 0, false, false><<<dim3(8, 32), blk, 0, stream>>>(
        yg_h, MB_DINNER, W_outh, MB_DINNER, out, MB_DMODEL, MB_DINNER, 0,
        nullptr, nullptr, 0);
}

// Round 7
// 398.520 us; speedup vs baseline: 4.6751x; 1.1275x over previous
//
#include <hip/hip_runtime.h>
#include <math.h>

// Mamba block fwd: B=2, L=2048, d_model=1024, d_inner=2048, d_state=16,
// d_conv=4, dt_rank=64.  GEMMs in f16 MFMA, scan fp32 chunked 2-pass.
#define MB_B      2
#define MB_L      2048
#define MB_DMODEL 1024
#define MB_DINNER 2048
#define MB_DSTATE 16
#define MB_DTRANK 64
#define MB_ROWS   (MB_B * MB_L)      // 4096
#define MB_E2     (2 * MB_DINNER)    // 4096
#define SC_NC     8                  // scan chunks
#define SC_CHUNK  (MB_L / SC_NC)     // 256 steps per chunk

typedef _Float16 f16;
typedef __attribute__((ext_vector_type(4))) _Float16 half4;
typedef __attribute__((ext_vector_type(8))) _Float16 half8;
typedef __attribute__((ext_vector_type(4))) float floatx4;

__device__ __forceinline__ float softplus_f(float x) {
    return (x > 20.f) ? x : log1pf(expf(x));
}
__device__ __forceinline__ float silu_f(float x) {
    return x / (1.f + expf(-x));
}

// 2^x via v_exp_f32 (callers fold log2(e) into the coefficient).
#if __has_builtin(__builtin_amdgcn_exp2f)
__device__ __forceinline__ float exp2_fast(float x) {
    return __builtin_amdgcn_exp2f(x);
}
#else
__device__ __forceinline__ float exp2_fast(float x) {
    return __expf(0.69314718056f * x);
}
#endif

// async global->LDS, 16B/lane. LDS dst is WAVE-UNIFORM base; HW adds lane*16.
typedef const __attribute__((address_space(1))) unsigned char gbyte;
typedef __attribute__((address_space(3))) unsigned char lbyte;
__device__ __forceinline__ void gl_lds16(const void* g, void* l) {
    __builtin_amdgcn_global_load_lds((gbyte*)g, (lbyte*)l, 16, 0, 0);
}

// VALU cross-lane add via DPP. After ror8+ror4+xor2+xor1 every lane of a
// 16-lane row holds the row sum.
template <int CTRL>
__device__ __forceinline__ float dpp_add(float x) {
    int xi = __builtin_bit_cast(int, x);
    int yi = __builtin_amdgcn_update_dpp(0, xi, CTRL, 0xF, 0xF, true);
    return x + __builtin_bit_cast(float, yi);
}

// ---------------------------------------------------------------------------
// Single fused fp32 -> f16 convert over all weight/activation segments.
// Destinations contiguous in ws (x_h|W_inh|W_xprojh|W_dth|W_outh);
// W_xproj pads 196608->262144 with zeros.
// ---------------------------------------------------------------------------
__global__ __launch_bounds__(256) void convert_all_kernel(
    const float* __restrict__ x, const float* __restrict__ W_in,
    const float* __restrict__ W_xproj, const float* __restrict__ W_dt,
    const float* __restrict__ W_out, f16* __restrict__ dst)
{
    const int i = (blockIdx.x * 256 + threadIdx.x) * 8;  // < 10878976
    const float* src;
    int local, nsrc;
    if (i < 4194304)      { src = x;       local = i;           nsrc = 4194304; }
    else if (i < 8388608) { src = W_in;    local = i - 4194304; nsrc = 4194304; }
    else if (i < 8650752) { src = W_xproj; local = i - 8388608; nsrc = 196608; }
    else if (i < 8781824) { src = W_dt;    local = i - 8650752; nsrc = 131072; }
    else                  { src = W_out;   local = i - 8781824; nsrc = 2097152; }
    half8 o;
    if (local < nsrc) {
        const float4 a = *reinterpret_cast<const float4*>(src + local);
        const float4 b = *reinterpret_cast<const float4*>(src + local + 4);
        o[0] = (f16)a.x; o[1] = (f16)a.y; o[2] = (f16)a.z; o[3] = (f16)a.w;
        o[4] = (f16)b.x; o[5] = (f16)b.y; o[6] = (f16)b.z; o[7] = (f16)b.w;
    } else {
#pragma unroll
        for (int j = 0; j < 8; j++) o[j] = (f16)0.f;
    }
    *reinterpret_cast<half8*>(dst + i) = o;
}

// ---------------------------------------------------------------------------
// f16 MFMA GEMM:  C[m][n] = sum_k A[m][k]*B[n][k]   (C = A·B^T, f32 accum)
// 128x128 tile, BK=32, 4 waves in 2x2, global_load_lds width=16 staging.
// EPI==1: v = softplus(v + bias[n]).
// ---------------------------------------------------------------------------
template <typename OutT, int EPI>
__global__ __launch_bounds__(256) void gemm_mfma(
    const f16* __restrict__ A, int lda,
    const f16* __restrict__ B, int ldb,
    OutT* __restrict__ C, int ldc, int K,
    const float* __restrict__ bias)
{
    __shared__ f16 As[128 * 32];   // [row][k], row stride 32 halves (64 B)
    __shared__ f16 Bs[128 * 32];

    const int tid  = threadIdx.x;
    const int lane = tid & 63;
    const int wave = tid >> 6;
    const int wr   = wave >> 1, wc = wave & 1;
    const int bm   = blockIdx.y * 128, bn = blockIdx.x * 128;

    floatx4 zero4 = {0.f, 0.f, 0.f, 0.f};
    floatx4 acc[4][4];
#pragma unroll
    for (int i = 0; i < 4; i++)
#pragma unroll
        for (int j = 0; j < 4; j++) acc[i][j] = zero4;

    const int srow = lane >> 2;
    const int scol = (lane & 3) * 8;
    const f16* gA0 = A + (size_t)(bm + wave * 32 + srow) * lda + scol;
    const f16* gA1 = A + (size_t)(bm + wave * 32 + 16 + srow) * lda + scol;
    const f16* gB0 = B + (size_t)(bn + wave * 32 + srow) * ldb + scol;
    const f16* gB1 = B + (size_t)(bn + wave * 32 + 16 + srow) * ldb + scol;
    f16* lA0 = As + wave * 1024;
    f16* lA1 = As + wave * 1024 + 512;
    f16* lB0 = Bs + wave * 1024;
    f16* lB1 = Bs + wave * 1024 + 512;

    const int mr = lane & 15;
    const int kq = (lane >> 4) * 8;

    for (int k0 = 0; k0 < K; k0 += 32) {
        gl_lds16(gA0 + k0, lA0);
        gl_lds16(gA1 + k0, lA1);
        gl_lds16(gB0 + k0, lB0);
        gl_lds16(gB1 + k0, lB1);
        __syncthreads();

        half8 af[4], bf[4];
#pragma unroll
        for (int mt = 0; mt < 4; mt++)
            af[mt] = *reinterpret_cast<const half8*>(
                As + (wr * 64 + mt * 16 + mr) * 32 + kq);
#pragma unroll
        for (int nt = 0; nt < 4; nt++)
            bf[nt] = *reinterpret_cast<const half8*>(
                Bs + (wc * 64 + nt * 16 + mr) * 32 + kq);
#pragma unroll
        for (int mt = 0; mt < 4; mt++)
#pragma unroll
            for (int nt = 0; nt < 4; nt++)
                acc[mt][nt] = __builtin_amdgcn_mfma_f32_16x16x32_f16(
                    af[mt], bf[nt], acc[mt][nt], 0, 0, 0);
        __syncthreads();
    }

    // Epilogue. C/D layout (verified m89): col = lane&15, row = quad*4+reg.
    const int rbase = (lane >> 4) * 4;
#pragma unroll
    for (int mt = 0; mt < 4; mt++) {
        const int row0 = bm + wr * 64 + mt * 16 + rbase;
#pragma unroll
        for (int nt = 0; nt < 4; nt++) {
            const int col = bn + wc * 64 + nt * 16 + mr;
#pragma unroll
            for (int r = 0; r < 4; r++) {
                float v = acc[mt][nt][r];
                if constexpr (EPI == 1) v = softplus_f(v + bias[col]);
                C[(size_t)(row0 + r) * ldc + col] = (OutT)v;
            }
        }
    }
}

// ---------------------------------------------------------------------------
// gemm3 split-K: x_dbl partials.  A = u_h [4096][2048], B = W_xprojh
// [128][2048].  Grid (8, 32): blockIdx.x = k-slice (256 wide), blockIdx.y =
// row tile.  Writes f32 partial [slice][4096][128].  256 blocks -> all CUs
// (vs 32 before: was per-CU stream-bound at ~40 us).
// ---------------------------------------------------------------------------
__global__ __launch_bounds__(256) void gemm3_splitk(
    const f16* __restrict__ A, const f16* __restrict__ B,
    float* __restrict__ Cp)
{
    __shared__ f16 As[128 * 32];
    __shared__ f16 Bs[128 * 32];

    const int tid  = threadIdx.x;
    const int lane = tid & 63;
    const int wave = tid >> 6;
    const int wr   = wave >> 1, wc = wave & 1;
    const int bm   = blockIdx.y * 128;
    const int kbeg = blockIdx.x * 256;

    floatx4 zero4 = {0.f, 0.f, 0.f, 0.f};
    floatx4 acc[4][4];
#pragma unroll
    for (int i = 0; i < 4; i++)
#pragma unroll
        for (int j = 0; j < 4; j++) acc[i][j] = zero4;

    const int srow = lane >> 2;
    const int scol = (lane & 3) * 8;
    const f16* gA0 = A + (size_t)(bm + wave * 32 + srow) * MB_DINNER + scol;
    const f16* gA1 = A + (size_t)(bm + wave * 32 + 16 + srow) * MB_DINNER + scol;
    const f16* gB0 = B + (size_t)(wave * 32 + srow) * MB_DINNER + scol;
    const f16* gB1 = B + (size_t)(wave * 32 + 16 + srow) * MB_DINNER + scol;
    f16* lA0 = As + wave * 1024;
    f16* lA1 = As + wave * 1024 + 512;
    f16* lB0 = Bs + wave * 1024;
    f16* lB1 = Bs + wave * 1024 + 512;

    const int mr = lane & 15;
    const int kq = (lane >> 4) * 8;

    for (int k0 = kbeg; k0 < kbeg + 256; k0 += 32) {
        gl_lds16(gA0 + k0, lA0);
        gl_lds16(gA1 + k0, lA1);
        gl_lds16(gB0 + k0, lB0);
        gl_lds16(gB1 + k0, lB1);
        __syncthreads();

        half8 af[4], bf[4];
#pragma unroll
        for (int mt = 0; mt < 4; mt++)
            af[mt] = *reinterpret_cast<const half8*>(
                As + (wr * 64 + mt * 16 + mr) * 32 + kq);
#pragma unroll
        for (int nt = 0; nt < 4; nt++)
            bf[nt] = *reinterpret_cast<const half8*>(
                Bs + (wc * 64 + nt * 16 + mr) * 32 + kq);
#pragma unroll
        for (int mt = 0; mt < 4; mt++)
#pragma unroll
            for (int nt = 0; nt < 4; nt++)
                acc[mt][nt] = __builtin_amdgcn_mfma_f32_16x16x32_f16(
                    af[mt], bf[nt], acc[mt][nt], 0, 0, 0);
        __syncthreads();
    }

    float* Co = Cp + (size_t)blockIdx.x * MB_ROWS * 128;
    const int rbase = (lane >> 4) * 4;
#pragma unroll
    for (int mt = 0; mt < 4; mt++) {
        const int row0 = bm + wr * 64 + mt * 16 + rbase;
#pragma unroll
        for (int nt = 0; nt < 4; nt++) {
            const int col = wc * 64 + nt * 16 + mr;
#pragma unroll
            for (int r = 0; r < 4; r++)
                Co[(size_t)(row0 + r) * 128 + col] = acc[mt][nt][r];
        }
    }
}

// ---------------------------------------------------------------------------
// Reduce the 8 split-K partials -> xdbl f32 [4096][96] + xdbl_h f16 [4096][128]
// ---------------------------------------------------------------------------
__global__ __launch_bounds__(256) void reduce_xdbl_kernel(
    const float* __restrict__ Cp, float* __restrict__ xdbl,
    f16* __restrict__ xdbl_h)
{
    const int t = blockIdx.x * 256 + threadIdx.x;   // 0..131071
    const int row = t >> 5, c4 = (t & 31) * 4;
    float4 s = {0.f, 0.f, 0.f, 0.f};
#pragma unroll
    for (int j = 0; j < 8; j++) {
        const float4 v = *reinterpret_cast<const float4*>(
            Cp + (size_t)j * MB_ROWS * 128 + (size_t)row * 128 + c4);
        s.x += v.x; s.y += v.y; s.z += v.z; s.w += v.w;
    }
    if (c4 < 96)
        *reinterpret_cast<float4*>(xdbl + (size_t)row * 96 + c4) = s;
    half4 h = {(f16)s.x, (f16)s.y, (f16)s.z, (f16)s.w};
    *reinterpret_cast<half4*>(xdbl_h + (size_t)row * 128 + c4) = h;
}

// ---------------------------------------------------------------------------
// Causal depthwise conv1d (width 4) + bias + SiLU.  f16 in/out.
// ---------------------------------------------------------------------------
__global__ __launch_bounds__(256) void conv_silu_kernel(
    const f16* __restrict__ xz, const float* __restrict__ cw,
    const float* __restrict__ cb, f16* __restrict__ u)
{
    const int idx = blockIdx.x * 256 + threadIdx.x;  // 4096 rows * 256
    const int dv  = (idx & 255) * 8;
    const int row = idx >> 8;
    const int l   = row & (MB_L - 1);

    float acc[8];
#pragma unroll
    for (int j = 0; j < 8; j++) acc[j] = cb[dv + j];
#pragma unroll
    for (int k = 0; k < 4; k++) {
        if (l - 3 + k >= 0) {
            const half8 xv = *reinterpret_cast<const half8*>(
                xz + (size_t)(row - 3 + k) * MB_E2 + dv);
#pragma unroll
            for (int j = 0; j < 8; j++)
                acc[j] = fmaf((float)xv[j], cw[(dv + j) * 4 + k], acc[j]);
        }
    }
    half8 r;
#pragma unroll
    for (int j = 0; j < 8; j++) r[j] = (f16)silu_f(acc[j]);
    *reinterpret_cast<half8*>(u + (size_t)row * MB_DINNER + dv) = r;
}

// XCD-aware channel-block swizzle: blockIdx -> XCD is round-robin (%8), so
// give each XCD a CONTIGUOUS run of 32 channel-blocks (512 channels = 1 KB
// per row): every 64-B HBM line is consumed entirely within one XCD's L2
// (unswizzled, the two 32-B halves of each line land on different XCDs and
// the line is fetched twice -> measured 2x overfetch in round 5).
__device__ __forceinline__ int swizzle_cb(int idx) {
    return ((idx & 7) << 5) | (idx >> 3);
}

// ---------------------------------------------------------------------------
// Chunked selective scan, pass 1: per chunk of 256 steps, run the recurrence
// from h=0 and emit H = local final state and P = prod(dA) = exp2(Av2*sum dt).
// Grid 7x256 blocks (chunk 7's summary is never consumed).  8 waves/SIMD.
// ---------------------------------------------------------------------------
__global__ __launch_bounds__(256) void scan_pass1(
    const f16*  __restrict__ delta,   // [4096][2048]
    const f16*  __restrict__ u,       // [4096][2048]
    const float* __restrict__ xdbl,   // [4096][96]  (dt|B|C)
    const float* __restrict__ A_log,  // [2048][16]
    float* __restrict__ Hc,           // [8][4096][16]
    float* __restrict__ Pc)           // [8][4096][16]
{
    constexpr int CL = 32;
    __shared__ float2 sDU[16][CL + 2];   // (delta, delta*u)
    __shared__ float  sB[16][CL + 2];

    const int tid   = threadIdx.x;
    const int n     = tid & 15;
    const int cg    = tid >> 4;
    const int chunk = blockIdx.x >> 8;
    const int cb    = swizzle_cb(blockIdx.x & 255);
    const int gchan = cb * 16 + cg;
    const int b     = gchan >> 11;
    const int dbase = (cb & 127) * 16;
    const int d     = gchan & (MB_DINNER - 1);
    const int lbeg  = chunk * SC_CHUNK;

    const size_t base2048 = (size_t)b * MB_L * MB_DINNER;
    const size_t base96   = (size_t)b * MB_L * 96;

    const float Av2 = -expf(A_log[d * MB_DSTATE + n]) * 1.44269504f;
    float h = 0.f, sdt = 0.f;
    float pd[2], pu[2], pb[2];

    auto stage_load = [&](int l0) {
#pragma unroll
        for (int r = 0; r < 2; r++) {
            const int e = tid + r * 256;
            const int lloc = e >> 4, cc = e & 15;
            const size_t row = (size_t)(l0 + lloc);
            pd[r] = (float)delta[base2048 + row * MB_DINNER + dbase + cc];
            pu[r] = (float)u[base2048 + row * MB_DINNER + dbase + cc];
            pb[r] = xdbl[base96 + row * 96 + MB_DTRANK + cc];
        }
    };
    auto stage_write = [&]() {
#pragma unroll
        for (int r = 0; r < 2; r++) {
            const int e = tid + r * 256;
            const int lloc = e >> 4, cc = e & 15;
            sDU[cc][lloc] = make_float2(pd[r], pd[r] * pu[r]);
            sB[cc][lloc]  = pb[r];
        }
    };

    stage_load(lbeg);
    stage_write();
    __syncthreads();

    for (int l0 = lbeg; l0 < lbeg + SC_CHUNK; l0 += CL) {
        const bool has_next = (l0 + CL) < lbeg + SC_CHUNK;
        if (has_next) stage_load(l0 + CL);

#pragma unroll
        for (int ll = 0; ll < CL; ll++) {
            const float2 du = sDU[cg][ll];
            const float bv = sB[n][ll];
            h = fmaf(exp2_fast(du.x * Av2), h, du.y * bv);
            sdt += du.x;
        }
        __syncthreads();
        if (has_next) stage_write();
        __syncthreads();
    }

    const size_t cidx = ((size_t)chunk * MB_ROWS + gchan) * MB_DSTATE + n;
    Hc[cidx] = h;
    Pc[cidx] = exp2_fast(Av2 * sdt);
}

// ---------------------------------------------------------------------------
// Chunked selective scan, pass 2: reconstruct carry-in h via <=7 fma combine,
// replay the chunk.  Serial loop carries only raw p (= C.h); skip+gate moved
// to the parallel store phase (saves 1 ds_read + 1 fma per step).
// ---------------------------------------------------------------------------
__global__ __launch_bounds__(256) void scan_pass2(
    const f16*  __restrict__ delta,   // [4096][2048]
    const f16*  __restrict__ u,       // [4096][2048]
    const float* __restrict__ xdbl,   // [4096][96]  (dt|B|C)
    const float* __restrict__ A_log,  // [2048][16]
    const float* __restrict__ Dskip,  // [2048]
    const f16*  __restrict__ xz,      // z = cols [2048,4096)
    const float* __restrict__ Hc,     // [8][4096][16]
    const float* __restrict__ Pc,     // [8][4096][16]
    f16* __restrict__ yg)             // [4096][2048]
{
    constexpr int CL = 32;
    __shared__ float2 sDU[16][CL + 2];   // (delta, delta*u)
    __shared__ float2 sBC[16][CL + 2];
    __shared__ float2 sGS[16][CL + 2];   // (g, u*Dsk*g)

    const int tid   = threadIdx.x;
    const int n     = tid & 15;
    const int cg    = tid >> 4;
    const int chunk = blockIdx.x >> 8;
    const int cb    = swizzle_cb(blockIdx.x & 255);
    const int gchan = cb * 16 + cg;
    const int b     = gchan >> 11;
    const int dbase = (cb & 127) * 16;
    const int d     = gchan & (MB_DINNER - 1);
    const int lbeg  = chunk * SC_CHUNK;

    const size_t base2048 = (size_t)b * MB_L * MB_DINNER;
    const size_t base4096 = (size_t)b * MB_L * MB_E2;
    const size_t base96   = (size_t)b * MB_L * 96;

    const float Av2 = -expf(A_log[d * MB_DSTATE + n]) * 1.44269504f;
    const float Dsk_s = Dskip[dbase + (tid & 15)];

    // carry-in: h after chunks 0..chunk-1
    float h = 0.f;
    for (int j = 0; j < chunk; j++) {
        const size_t cidx = ((size_t)j * MB_ROWS + gchan) * MB_DSTATE + n;
        h = fmaf(Pc[cidx], h, Hc[cidx]);
    }

    float pd[2], pu[2], pb[2], pc[2], pz[2];

    auto stage_load = [&](int l0) {
#pragma unroll
        for (int r = 0; r < 2; r++) {
            const int e = tid + r * 256;
            const int lloc = e >> 4, cc = e & 15;
            const size_t row = (size_t)(l0 + lloc);
            pd[r] = (float)delta[base2048 + row * MB_DINNER + dbase + cc];
            pu[r] = (float)u[base2048 + row * MB_DINNER + dbase + cc];
            pb[r] = xdbl[base96 + row * 96 + MB_DTRANK + cc];
            pc[r] = xdbl[base96 + row * 96 + MB_DTRANK + MB_DSTATE + cc];
            pz[r] = (float)xz[base4096 + row * MB_E2 + MB_DINNER + dbase + cc];
        }
    };
    auto stage_write = [&]() {
#pragma unroll
        for (int r = 0; r < 2; r++) {
            const int e = tid + r * 256;
            const int lloc = e >> 4, cc = e & 15;
            sDU[cc][lloc] = make_float2(pd[r], pd[r] * pu[r]);
            sBC[cc][lloc] = make_float2(pb[r], pc[r]);
            const float g = silu_f(pz[r]);
            sGS[cc][lloc] = make_float2(g, pu[r] * Dsk_s * g);
        }
    };

    stage_load(lbeg);
    stage_write();
    __syncthreads();

    for (int l0 = lbeg; l0 < lbeg + SC_CHUNK; l0 += CL) {
        const bool has_next = (l0 + CL) < lbeg + SC_CHUNK;
        if (has_next) stage_load(l0 + CL);

        float y0 = 0.f, y1 = 0.f;   // raw p for rows l0+n, l0+n+16
#pragma unroll
        for (int ll = 0; ll < CL; ll++) {
            const float2 du = sDU[cg][ll];
            const float2 bc = sBC[n][ll];
            h = fmaf(exp2_fast(du.x * Av2), h, du.y * bc.x);
            float p = h * bc.y;
            p = dpp_add<0x128>(p);   // row_ror:8
            p = dpp_add<0x124>(p);   // row_ror:4
            p = dpp_add<0x4E>(p);    // quad_perm xor2
            p = dpp_add<0xB1>(p);    // quad_perm xor1 (all 16 lanes = sum)
            if (ll < 16) y0 = (n == ll) ? p : y0;
            else         y1 = (n == ll - 16) ? p : y1;
        }

        // skip+gate at store time: lane n owns rows l0+n, l0+n+16 of col gchan
        const float2 g0 = sGS[cg][n];
        const float2 g1 = sGS[cg][n + 16];
        yg[base2048 + (size_t)(l0 + n) * MB_DINNER + dbase + cg] =
            (f16)fmaf(y0, g0.x, g0.y);
        yg[base2048 + (size_t)(l0 + n + 16) * MB_DINNER + dbase + cg] =
            (f16)fmaf(y1, g1.x, g1.y);

        __syncthreads();
        if (has_next) stage_write();
        __syncthreads();
    }
}

// ---------------------------------------------------------------------------
extern "C" void kernel_launch(void* const* d_in, const int* in_sizes, int n_in,
                              void* d_out, int out_size, void* d_ws,
                              size_t ws_size, hipStream_t stream)
{
    const float* x      = (const float*)d_in[0];  // (2,2048,1024)
    const float* W_in   = (const float*)d_in[1];  // (4096,1024)
    const float* conv_w = (const float*)d_in[2];  // (2048,1,4)
    const float* conv_b = (const float*)d_in[3];  // (2048)
    const float* W_xproj= (const float*)d_in[4];  // (96,2048)
    const float* W_dt   = (const float*)d_in[5];  // (2048,64)
    const float* b_dt   = (const float*)d_in[6];  // (2048)
    const float* A_log  = (const float*)d_in[7];  // (2048,16)
    const float* Dskip  = (const float*)d_in[8];  // (2048)
    const float* W_out  = (const float*)d_in[9];  // (1024,2048)
    float* out = (float*)d_out;                   // (2,2048,1024)

    // Workspace (~130 MB).  The five f16 convert destinations
    // (x_h..W_outh) are CONTIGUOUS for the fused convert.
    char* p = (char*)d_ws;
    f16* xz_h    = (f16*)p;  p += (size_t)MB_ROWS * MB_E2 * 2;      // 33.6 MB
    f16* u_h     = (f16*)p;  p += (size_t)MB_ROWS * MB_DINNER * 2;  // 16.8 MB
    f16* delta_h = (f16*)p;  p += (size_t)MB_ROWS * MB_DINNER * 2;  // 16.8 MB
    f16* yg_h    = (f16*)p;  p += (size_t)MB_ROWS * MB_DINNER * 2;  // 16.8 MB
    float* xdbl  = (float*)p; p += (size_t)MB_ROWS * 96 * 4;        // 1.6 MB
    f16* xdbl_h  = (f16*)p;  p += (size_t)MB_ROWS * 128 * 2;        // 1.0 MB
    f16* x_h     = (f16*)p;  p += (size_t)MB_ROWS * MB_DMODEL * 2;  // 8.4 MB
    f16* W_inh   = (f16*)p;  p += (size_t)MB_E2 * MB_DMODEL * 2;    // 8.4 MB
    f16* W_xprojh= (f16*)p;  p += (size_t)128 * MB_DINNER * 2;      // 0.5 MB
    f16* W_dth   = (f16*)p;  p += (size_t)MB_DINNER * MB_DTRANK * 2;// 0.26 MB
    f16* W_outh  = (f16*)p;  p += (size_t)MB_DMODEL * MB_DINNER * 2;// 4.2 MB
    float* Hc    = (float*)p; p += (size_t)SC_NC * MB_ROWS * MB_DSTATE * 4; // 2.1 MB
    float* Pc    = (float*)p; p += (size_t)SC_NC * MB_ROWS * MB_DSTATE * 4; // 2.1 MB
    float* Cp    = (float*)p;                                       // 16.8 MB

    const dim3 blk(256);

    // 0) one fused fp32 -> f16 convert over all segments
    convert_all_kernel<<<5312, blk, 0, stream>>>(
        x, W_in, W_xproj, W_dt, W_out, x_h);

    // 1) xz = x @ W_in^T     (M=4096, N=4096, K=1024) -> f16
    gemm_mfma<f16, 0><<<dim3(32, 32), blk, 0, stream>>>(
        x_h, MB_DMODEL, W_inh, MB_DMODEL, xz_h, MB_E2, MB_DMODEL, nullptr);

    // 2) u = silu(causal_dwconv(xb) + conv_b)
    conv_silu_kernel<<<4096, blk, 0, stream>>>(xz_h, conv_w, conv_b, u_h);

    // 3) x_dbl = u @ W_xproj^T  (M=4096, N=128, K=2048), split-K x8 + reduce
    gemm3_splitk<<<dim3(8, 32), blk, 0, stream>>>(u_h, W_xprojh, Cp);
    reduce_xdbl_kernel<<<512, blk, 0, stream>>>(Cp, xdbl, xdbl_h);

    // 4) delta = softplus(dt_low @ W_dt^T + b_dt)  (M=4096, N=2048, K=64)
    gemm_mfma<f16, 1><<<dim3(16, 32), blk, 0, stream>>>(
        xdbl_h, 128, W_dth, MB_DTRANK, delta_h, MB_DINNER, MB_DTRANK, b_dt);

    // 5a) scan pass 1: per-chunk (H, P) summaries (chunk 7 skipped)
    scan_pass1<<<(SC_NC - 1) * 256, blk, 0, stream>>>(
        delta_h, u_h, xdbl, A_log, Hc, Pc);

    // 5b) scan pass 2: carry-combine + replay with y/skip/gate -> yg (f16)
    scan_pass2<<<SC_NC * 256, blk, 0, stream>>>(
        delta_h, u_h, xdbl, A_log, Dskip, xz_h, Hc, Pc, yg_h);

    // 6) out = yg @ W_out^T   (M=4096, N=1024, K=2048) -> f32
    gemm_mfma<float, 0><<<dim3(8, 32), blk, 0, stream>>>(
        yg_h, MB_DINNER, W_outh, MB_DINNER, out, MB_DMODEL, MB_DINNER, nullptr);
}

// Round 8
// 348.127 us; speedup vs baseline: 5.3519x; 1.1448x over previous
//
#include <hip/hip_runtime.h>
#include <math.h>

// Mamba block fwd: B=2, L=2048, d_model=1024, d_inner=2048, d_state=16,
// d_conv=4, dt_rank=64.  GEMMs in f16 MFMA, scan fp32 chunked 2-pass.
#define MB_B      2
#define MB_L      2048
#define MB_DMODEL 1024
#define MB_DINNER 2048
#define MB_DSTATE 16
#define MB_DTRANK 64
#define MB_ROWS   (MB_B * MB_L)      // 4096
#define MB_E2     (2 * MB_DINNER)    // 4096
#define SC_NC     8                  // scan chunks
#define SC_CHUNK  (MB_L / SC_NC)     // 256 steps per chunk
#define CV_R      8                  // conv rows per thread

typedef _Float16 f16;
typedef __attribute__((ext_vector_type(4))) _Float16 half4;
typedef __attribute__((ext_vector_type(8))) _Float16 half8;
typedef __attribute__((ext_vector_type(4))) float floatx4;

__device__ __forceinline__ float softplus_f(float x) {
    return (x > 20.f) ? x : log1pf(expf(x));
}
__device__ __forceinline__ float silu_f(float x) {
    return x / (1.f + expf(-x));
}

// 2^x via v_exp_f32 (callers fold log2(e) into the coefficient).
#if __has_builtin(__builtin_amdgcn_exp2f)
__device__ __forceinline__ float exp2_fast(float x) {
    return __builtin_amdgcn_exp2f(x);
}
#else
__device__ __forceinline__ float exp2_fast(float x) {
    return __expf(0.69314718056f * x);
}
#endif

// async global->LDS, 16B/lane. LDS dst is WAVE-UNIFORM base; HW adds lane*16.
typedef const __attribute__((address_space(1))) unsigned char gbyte;
typedef __attribute__((address_space(3))) unsigned char lbyte;
__device__ __forceinline__ void gl_lds16(const void* g, void* l) {
    __builtin_amdgcn_global_load_lds((gbyte*)g, (lbyte*)l, 16, 0, 0);
}

// VALU cross-lane add via DPP. After ror8+ror4+xor2+xor1 every lane of a
// 16-lane row holds the row sum.
template <int CTRL>
__device__ __forceinline__ float dpp_add(float x) {
    int xi = __builtin_bit_cast(int, x);
    int yi = __builtin_amdgcn_update_dpp(0, xi, CTRL, 0xF, 0xF, true);
    return x + __builtin_bit_cast(float, yi);
}

// ---------------------------------------------------------------------------
// Single fused fp32 -> f16 convert over all weight/activation segments.
// Destinations contiguous in ws (x_h|W_inh|W_xprojh|W_dth|W_outh);
// W_xproj pads 196608->262144 with zeros.
// ---------------------------------------------------------------------------
__global__ __launch_bounds__(256) void convert_all_kernel(
    const float* __restrict__ x, const float* __restrict__ W_in,
    const float* __restrict__ W_xproj, const float* __restrict__ W_dt,
    const float* __restrict__ W_out, f16* __restrict__ dst)
{
    const int i = (blockIdx.x * 256 + threadIdx.x) * 8;  // < 10878976
    const float* src;
    int local, nsrc;
    if (i < 4194304)      { src = x;       local = i;           nsrc = 4194304; }
    else if (i < 8388608) { src = W_in;    local = i - 4194304; nsrc = 4194304; }
    else if (i < 8650752) { src = W_xproj; local = i - 8388608; nsrc = 196608; }
    else if (i < 8781824) { src = W_dt;    local = i - 8650752; nsrc = 131072; }
    else                  { src = W_out;   local = i - 8781824; nsrc = 2097152; }
    half8 o;
    if (local < nsrc) {
        const float4 a = *reinterpret_cast<const float4*>(src + local);
        const float4 b = *reinterpret_cast<const float4*>(src + local + 4);
        o[0] = (f16)a.x; o[1] = (f16)a.y; o[2] = (f16)a.z; o[3] = (f16)a.w;
        o[4] = (f16)b.x; o[5] = (f16)b.y; o[6] = (f16)b.z; o[7] = (f16)b.w;
    } else {
#pragma unroll
        for (int j = 0; j < 8; j++) o[j] = (f16)0.f;
    }
    *reinterpret_cast<half8*>(dst + i) = o;
}

// ---------------------------------------------------------------------------
// f16 MFMA GEMM:  C[m][n] = sum_k A[m][k]*B[n][k]   (C = A·B^T, f32 accum)
// 128x128 tile, BK=32, 4 waves in 2x2, global_load_lds width=16 staging.
// EPI==1: v = softplus(v + bias[n]).
// ---------------------------------------------------------------------------
template <typename OutT, int EPI>
__global__ __launch_bounds__(256) void gemm_mfma(
    const f16* __restrict__ A, int lda,
    const f16* __restrict__ B, int ldb,
    OutT* __restrict__ C, int ldc, int K,
    const float* __restrict__ bias)
{
    __shared__ f16 As[128 * 32];   // [row][k], row stride 32 halves (64 B)
    __shared__ f16 Bs[128 * 32];

    const int tid  = threadIdx.x;
    const int lane = tid & 63;
    const int wave = tid >> 6;
    const int wr   = wave >> 1, wc = wave & 1;
    const int bm   = blockIdx.y * 128, bn = blockIdx.x * 128;

    floatx4 zero4 = {0.f, 0.f, 0.f, 0.f};
    floatx4 acc[4][4];
#pragma unroll
    for (int i = 0; i < 4; i++)
#pragma unroll
        for (int j = 0; j < 4; j++) acc[i][j] = zero4;

    const int srow = lane >> 2;
    const int scol = (lane & 3) * 8;
    const f16* gA0 = A + (size_t)(bm + wave * 32 + srow) * lda + scol;
    const f16* gA1 = A + (size_t)(bm + wave * 32 + 16 + srow) * lda + scol;
    const f16* gB0 = B + (size_t)(bn + wave * 32 + srow) * ldb + scol;
    const f16* gB1 = B + (size_t)(bn + wave * 32 + 16 + srow) * ldb + scol;
    f16* lA0 = As + wave * 1024;
    f16* lA1 = As + wave * 1024 + 512;
    f16* lB0 = Bs + wave * 1024;
    f16* lB1 = Bs + wave * 1024 + 512;

    const int mr = lane & 15;
    const int kq = (lane >> 4) * 8;

    for (int k0 = 0; k0 < K; k0 += 32) {
        gl_lds16(gA0 + k0, lA0);
        gl_lds16(gA1 + k0, lA1);
        gl_lds16(gB0 + k0, lB0);
        gl_lds16(gB1 + k0, lB1);
        __syncthreads();

        half8 af[4], bf[4];
#pragma unroll
        for (int mt = 0; mt < 4; mt++)
            af[mt] = *reinterpret_cast<const half8*>(
                As + (wr * 64 + mt * 16 + mr) * 32 + kq);
#pragma unroll
        for (int nt = 0; nt < 4; nt++)
            bf[nt] = *reinterpret_cast<const half8*>(
                Bs + (wc * 64 + nt * 16 + mr) * 32 + kq);
#pragma unroll
        for (int mt = 0; mt < 4; mt++)
#pragma unroll
            for (int nt = 0; nt < 4; nt++)
                acc[mt][nt] = __builtin_amdgcn_mfma_f32_16x16x32_f16(
                    af[mt], bf[nt], acc[mt][nt], 0, 0, 0);
        __syncthreads();
    }

    // Epilogue. C/D layout (verified m89): col = lane&15, row = quad*4+reg.
    const int rbase = (lane >> 4) * 4;
#pragma unroll
    for (int mt = 0; mt < 4; mt++) {
        const int row0 = bm + wr * 64 + mt * 16 + rbase;
#pragma unroll
        for (int nt = 0; nt < 4; nt++) {
            const int col = bn + wc * 64 + nt * 16 + mr;
#pragma unroll
            for (int r = 0; r < 4; r++) {
                float v = acc[mt][nt][r];
                if constexpr (EPI == 1) v = softplus_f(v + bias[col]);
                C[(size_t)(row0 + r) * ldc + col] = (OutT)v;
            }
        }
    }
}

// ---------------------------------------------------------------------------
// gemm3 split-K: x_dbl partials.  A = u_h [4096][2048], B = W_xprojh
// [128][2048].  Grid (8, 32): blockIdx.x = k-slice (256 wide), blockIdx.y =
// row tile.  Writes f32 partial [slice][4096][128].
// ---------------------------------------------------------------------------
__global__ __launch_bounds__(256) void gemm3_splitk(
    const f16* __restrict__ A, const f16* __restrict__ B,
    float* __restrict__ Cp)
{
    __shared__ f16 As[128 * 32];
    __shared__ f16 Bs[128 * 32];

    const int tid  = threadIdx.x;
    const int lane = tid & 63;
    const int wave = tid >> 6;
    const int wr   = wave >> 1, wc = wave & 1;
    const int bm   = blockIdx.y * 128;
    const int kbeg = blockIdx.x * 256;

    floatx4 zero4 = {0.f, 0.f, 0.f, 0.f};
    floatx4 acc[4][4];
#pragma unroll
    for (int i = 0; i < 4; i++)
#pragma unroll
        for (int j = 0; j < 4; j++) acc[i][j] = zero4;

    const int srow = lane >> 2;
    const int scol = (lane & 3) * 8;
    const f16* gA0 = A + (size_t)(bm + wave * 32 + srow) * MB_DINNER + scol;
    const f16* gA1 = A + (size_t)(bm + wave * 32 + 16 + srow) * MB_DINNER + scol;
    const f16* gB0 = B + (size_t)(wave * 32 + srow) * MB_DINNER + scol;
    const f16* gB1 = B + (size_t)(wave * 32 + 16 + srow) * MB_DINNER + scol;
    f16* lA0 = As + wave * 1024;
    f16* lA1 = As + wave * 1024 + 512;
    f16* lB0 = Bs + wave * 1024;
    f16* lB1 = Bs + wave * 1024 + 512;

    const int mr = lane & 15;
    const int kq = (lane >> 4) * 8;

    for (int k0 = kbeg; k0 < kbeg + 256; k0 += 32) {
        gl_lds16(gA0 + k0, lA0);
        gl_lds16(gA1 + k0, lA1);
        gl_lds16(gB0 + k0, lB0);
        gl_lds16(gB1 + k0, lB1);
        __syncthreads();

        half8 af[4], bf[4];
#pragma unroll
        for (int mt = 0; mt < 4; mt++)
            af[mt] = *reinterpret_cast<const half8*>(
                As + (wr * 64 + mt * 16 + mr) * 32 + kq);
#pragma unroll
        for (int nt = 0; nt < 4; nt++)
            bf[nt] = *reinterpret_cast<const half8*>(
                Bs + (wc * 64 + nt * 16 + mr) * 32 + kq);
#pragma unroll
        for (int mt = 0; mt < 4; mt++)
#pragma unroll
            for (int nt = 0; nt < 4; nt++)
                acc[mt][nt] = __builtin_amdgcn_mfma_f32_16x16x32_f16(
                    af[mt], bf[nt], acc[mt][nt], 0, 0, 0);
        __syncthreads();
    }

    float* Co = Cp + (size_t)blockIdx.x * MB_ROWS * 128;
    const int rbase = (lane >> 4) * 4;
#pragma unroll
    for (int mt = 0; mt < 4; mt++) {
        const int row0 = bm + wr * 64 + mt * 16 + rbase;
#pragma unroll
        for (int nt = 0; nt < 4; nt++) {
            const int col = wc * 64 + nt * 16 + mr;
#pragma unroll
            for (int r = 0; r < 4; r++)
                Co[(size_t)(row0 + r) * 128 + col] = acc[mt][nt][r];
        }
    }
}

// ---------------------------------------------------------------------------
// Reduce the 8 split-K partials -> xdbl f32 [4096][96] + xdbl_h f16 [4096][128]
// ---------------------------------------------------------------------------
__global__ __launch_bounds__(256) void reduce_xdbl_kernel(
    const float* __restrict__ Cp, float* __restrict__ xdbl,
    f16* __restrict__ xdbl_h)
{
    const int t = blockIdx.x * 256 + threadIdx.x;   // 0..131071
    const int row = t >> 5, c4 = (t & 31) * 4;
    float4 s = {0.f, 0.f, 0.f, 0.f};
#pragma unroll
    for (int j = 0; j < 8; j++) {
        const float4 v = *reinterpret_cast<const float4*>(
            Cp + (size_t)j * MB_ROWS * 128 + (size_t)row * 128 + c4);
        s.x += v.x; s.y += v.y; s.z += v.z; s.w += v.w;
    }
    if (c4 < 96)
        *reinterpret_cast<float4*>(xdbl + (size_t)row * 96 + c4) = s;
    half4 h = {(f16)s.x, (f16)s.y, (f16)s.z, (f16)s.w};
    *reinterpret_cast<half4*>(xdbl_h + (size_t)row * 128 + c4) = h;
}

// ---------------------------------------------------------------------------
// Causal depthwise conv1d (width 4) + bias + SiLU, sliding-window v2.
// Each thread: 8 channels x CV_R consecutive time-steps.  11 independent
// half8 loads issued up front (deep vmcnt queue), weights as contiguous
// float4s, then pure register compute + 8 coalesced stores.  v1 (1 row/
// thread) sat at 64 us with all pipes <12% busy: short-lived waves with
// 4 loads each = latency-bound.  Blocks never straddle the batch boundary
// (CV_R divides 2048).
// ---------------------------------------------------------------------------
__global__ __launch_bounds__(256) void conv_silu_kernel(
    const f16* __restrict__ xz, const float* __restrict__ cw,
    const float* __restrict__ cb, f16* __restrict__ u)
{
    const int tid  = threadIdx.x;
    const int dv   = tid * 8;                 // channel base 0..2040
    const int rbeg = blockIdx.x * CV_R;       // global row base
    const int l0   = rbeg & (MB_L - 1);       // position within batch

    // weights: 8 channels x 4 taps = 32 consecutive floats
    float wt[8][4];
#pragma unroll
    for (int j = 0; j < 8; j++) {
        const float4 wv = *reinterpret_cast<const float4*>(cw + (dv + j) * 4);
        wt[j][0] = wv.x; wt[j][1] = wv.y; wt[j][2] = wv.z; wt[j][3] = wv.w;
    }
    float bias[8];
    {
        const float4 b0 = *reinterpret_cast<const float4*>(cb + dv);
        const float4 b1 = *reinterpret_cast<const float4*>(cb + dv + 4);
        bias[0] = b0.x; bias[1] = b0.y; bias[2] = b0.z; bias[3] = b0.w;
        bias[4] = b1.x; bias[5] = b1.y; bias[6] = b1.z; bias[7] = b1.w;
    }

    // rows rbeg-3 .. rbeg+CV_R-1 (halo zeros before batch start)
    half8 xr[CV_R + 3];
#pragma unroll
    for (int i = 0; i < 3; i++) {
        if (l0 >= 3 - i) {
            xr[i] = *reinterpret_cast<const half8*>(
                xz + (size_t)(rbeg - 3 + i) * MB_E2 + dv);
        } else {
#pragma unroll
            for (int j = 0; j < 8; j++) xr[i][j] = (f16)0.f;
        }
    }
#pragma unroll
    for (int r = 0; r < CV_R; r++)
        xr[3 + r] = *reinterpret_cast<const half8*>(
            xz + (size_t)(rbeg + r) * MB_E2 + dv);

#pragma unroll
    for (int r = 0; r < CV_R; r++) {
        float acc[8];
#pragma unroll
        for (int j = 0; j < 8; j++) acc[j] = bias[j];
#pragma unroll
        for (int k = 0; k < 4; k++) {     // tap k reads row (rbeg+r-3+k)
            const half8 xv = xr[r + k];
#pragma unroll
            for (int j = 0; j < 8; j++)
                acc[j] = fmaf((float)xv[j], wt[j][k], acc[j]);
        }
        half8 o;
#pragma unroll
        for (int j = 0; j < 8; j++) o[j] = (f16)silu_f(acc[j]);
        *reinterpret_cast<half8*>(u + (size_t)(rbeg + r) * MB_DINNER + dv) = o;
    }
}

// XCD-aware channel-block swizzle: blockIdx -> XCD is round-robin (%8), so
// give each XCD a CONTIGUOUS run of 32 channel-blocks (512 channels = 1 KB
// per row): every 64-B HBM line is consumed entirely within one XCD's L2.
__device__ __forceinline__ int swizzle_cb(int idx) {
    return ((idx & 7) << 5) | (idx >> 3);
}

// ---------------------------------------------------------------------------
// Chunked selective scan, pass 1: per chunk of 256 steps, run the recurrence
// from h=0 and emit H = local final state and P = prod(dA) = exp2(Av2*sum dt).
// Grid 7x256 blocks (chunk 7's summary is never consumed).  8 waves/SIMD.
// ---------------------------------------------------------------------------
__global__ __launch_bounds__(256) void scan_pass1(
    const f16*  __restrict__ delta,   // [4096][2048]
    const f16*  __restrict__ u,       // [4096][2048]
    const float* __restrict__ xdbl,   // [4096][96]  (dt|B|C)
    const float* __restrict__ A_log,  // [2048][16]
    float* __restrict__ Hc,           // [8][4096][16]
    float* __restrict__ Pc)           // [8][4096][16]
{
    constexpr int CL = 32;
    __shared__ float2 sDU[16][CL + 2];   // (delta, delta*u)
    __shared__ float  sB[16][CL + 2];

    const int tid   = threadIdx.x;
    const int n     = tid & 15;
    const int cg    = tid >> 4;
    const int chunk = blockIdx.x >> 8;
    const int cb    = swizzle_cb(blockIdx.x & 255);
    const int gchan = cb * 16 + cg;
    const int b     = gchan >> 11;
    const int dbase = (cb & 127) * 16;
    const int d     = gchan & (MB_DINNER - 1);
    const int lbeg  = chunk * SC_CHUNK;

    const size_t base2048 = (size_t)b * MB_L * MB_DINNER;
    const size_t base96   = (size_t)b * MB_L * 96;

    const float Av2 = -expf(A_log[d * MB_DSTATE + n]) * 1.44269504f;
    float h = 0.f, sdt = 0.f;
    float pd[2], pu[2], pb[2];

    auto stage_load = [&](int l0) {
#pragma unroll
        for (int r = 0; r < 2; r++) {
            const int e = tid + r * 256;
            const int lloc = e >> 4, cc = e & 15;
            const size_t row = (size_t)(l0 + lloc);
            pd[r] = (float)delta[base2048 + row * MB_DINNER + dbase + cc];
            pu[r] = (float)u[base2048 + row * MB_DINNER + dbase + cc];
            pb[r] = xdbl[base96 + row * 96 + MB_DTRANK + cc];
        }
    };
    auto stage_write = [&]() {
#pragma unroll
        for (int r = 0; r < 2; r++) {
            const int e = tid + r * 256;
            const int lloc = e >> 4, cc = e & 15;
            sDU[cc][lloc] = make_float2(pd[r], pd[r] * pu[r]);
            sB[cc][lloc]  = pb[r];
        }
    };

    stage_load(lbeg);
    stage_write();
    __syncthreads();

    for (int l0 = lbeg; l0 < lbeg + SC_CHUNK; l0 += CL) {
        const bool has_next = (l0 + CL) < lbeg + SC_CHUNK;
        if (has_next) stage_load(l0 + CL);

#pragma unroll
        for (int ll = 0; ll < CL; ll++) {
            const float2 du = sDU[cg][ll];
            const float bv = sB[n][ll];
            h = fmaf(exp2_fast(du.x * Av2), h, du.y * bv);
            sdt += du.x;
        }
        __syncthreads();
        if (has_next) stage_write();
        __syncthreads();
    }

    const size_t cidx = ((size_t)chunk * MB_ROWS + gchan) * MB_DSTATE + n;
    Hc[cidx] = h;
    Pc[cidx] = exp2_fast(Av2 * sdt);
}

// ---------------------------------------------------------------------------
// Chunked selective scan, pass 2: reconstruct carry-in h via <=7 fma combine,
// replay the chunk.  Serial loop carries only raw p (= C.h); skip+gate at
// the parallel store phase.
// ---------------------------------------------------------------------------
__global__ __launch_bounds__(256) void scan_pass2(
    const f16*  __restrict__ delta,   // [4096][2048]
    const f16*  __restrict__ u,       // [4096][2048]
    const float* __restrict__ xdbl,   // [4096][96]  (dt|B|C)
    const float* __restrict__ A_log,  // [2048][16]
    const float* __restrict__ Dskip,  // [2048]
    const f16*  __restrict__ xz,      // z = cols [2048,4096)
    const float* __restrict__ Hc,     // [8][4096][16]
    const float* __restrict__ Pc,     // [8][4096][16]
    f16* __restrict__ yg)             // [4096][2048]
{
    constexpr int CL = 32;
    __shared__ float2 sDU[16][CL + 2];   // (delta, delta*u)
    __shared__ float2 sBC[16][CL + 2];
    __shared__ float2 sGS[16][CL + 2];   // (g, u*Dsk*g)

    const int tid   = threadIdx.x;
    const int n     = tid & 15;
    const int cg    = tid >> 4;
    const int chunk = blockIdx.x >> 8;
    const int cb    = swizzle_cb(blockIdx.x & 255);
    const int gchan = cb * 16 + cg;
    const int b     = gchan >> 11;
    const int dbase = (cb & 127) * 16;
    const int d     = gchan & (MB_DINNER - 1);
    const int lbeg  = chunk * SC_CHUNK;

    const size_t base2048 = (size_t)b * MB_L * MB_DINNER;
    const size_t base4096 = (size_t)b * MB_L * MB_E2;
    const size_t base96   = (size_t)b * MB_L * 96;

    const float Av2 = -expf(A_log[d * MB_DSTATE + n]) * 1.44269504f;
    const float Dsk_s = Dskip[dbase + (tid & 15)];

    // carry-in: h after chunks 0..chunk-1
    float h = 0.f;
    for (int j = 0; j < chunk; j++) {
        const size_t cidx = ((size_t)j * MB_ROWS + gchan) * MB_DSTATE + n;
        h = fmaf(Pc[cidx], h, Hc[cidx]);
    }

    float pd[2], pu[2], pb[2], pc[2], pz[2];

    auto stage_load = [&](int l0) {
#pragma unroll
        for (int r = 0; r < 2; r++) {
            const int e = tid + r * 256;
            const int lloc = e >> 4, cc = e & 15;
            const size_t row = (size_t)(l0 + lloc);
            pd[r] = (float)delta[base2048 + row * MB_DINNER + dbase + cc];
            pu[r] = (float)u[base2048 + row * MB_DINNER + dbase + cc];
            pb[r] = xdbl[base96 + row * 96 + MB_DTRANK + cc];
            pc[r] = xdbl[base96 + row * 96 + MB_DTRANK + MB_DSTATE + cc];
            pz[r] = (float)xz[base4096 + row * MB_E2 + MB_DINNER + dbase + cc];
        }
    };
    auto stage_write = [&]() {
#pragma unroll
        for (int r = 0; r < 2; r++) {
            const int e = tid + r * 256;
            const int lloc = e >> 4, cc = e & 15;
            sDU[cc][lloc] = make_float2(pd[r], pd[r] * pu[r]);
            sBC[cc][lloc] = make_float2(pb[r], pc[r]);
            const float g = silu_f(pz[r]);
            sGS[cc][lloc] = make_float2(g, pu[r] * Dsk_s * g);
        }
    };

    stage_load(lbeg);
    stage_write();
    __syncthreads();

    for (int l0 = lbeg; l0 < lbeg + SC_CHUNK; l0 += CL) {
        const bool has_next = (l0 + CL) < lbeg + SC_CHUNK;
        if (has_next) stage_load(l0 + CL);

        float y0 = 0.f, y1 = 0.f;   // raw p for rows l0+n, l0+n+16
#pragma unroll
        for (int ll = 0; ll < CL; ll++) {
            const float2 du = sDU[cg][ll];
            const float2 bc = sBC[n][ll];
            h = fmaf(exp2_fast(du.x * Av2), h, du.y * bc.x);
            float p = h * bc.y;
            p = dpp_add<0x128>(p);   // row_ror:8
            p = dpp_add<0x124>(p);   // row_ror:4
            p = dpp_add<0x4E>(p);    // quad_perm xor2
            p = dpp_add<0xB1>(p);    // quad_perm xor1 (all 16 lanes = sum)
            if (ll < 16) y0 = (n == ll) ? p : y0;
            else         y1 = (n == ll - 16) ? p : y1;
        }

        // skip+gate at store time: lane n owns rows l0+n, l0+n+16 of col gchan
        const float2 g0 = sGS[cg][n];
        const float2 g1 = sGS[cg][n + 16];
        yg[base2048 + (size_t)(l0 + n) * MB_DINNER + dbase + cg] =
            (f16)fmaf(y0, g0.x, g0.y);
        yg[base2048 + (size_t)(l0 + n + 16) * MB_DINNER + dbase + cg] =
            (f16)fmaf(y1, g1.x, g1.y);

        __syncthreads();
        if (has_next) stage_write();
        __syncthreads();
    }
}

// ---------------------------------------------------------------------------
extern "C" void kernel_launch(void* const* d_in, const int* in_sizes, int n_in,
                              void* d_out, int out_size, void* d_ws,
                              size_t ws_size, hipStream_t stream)
{
    const float* x      = (const float*)d_in[0];  // (2,2048,1024)
    const float* W_in   = (const float*)d_in[1];  // (4096,1024)
    const float* conv_w = (const float*)d_in[2];  // (2048,1,4)
    const float* conv_b = (const float*)d_in[3];  // (2048)
    const float* W_xproj= (const float*)d_in[4];  // (96,2048)
    const float* W_dt   = (const float*)d_in[5];  // (2048,64)
    const float* b_dt   = (const float*)d_in[6];  // (2048)
    const float* A_log  = (const float*)d_in[7];  // (2048,16)
    const float* Dskip  = (const float*)d_in[8];  // (2048)
    const float* W_out  = (const float*)d_in[9];  // (1024,2048)
    float* out = (float*)d_out;                   // (2,2048,1024)

    // Workspace (~130 MB).  The five f16 convert destinations
    // (x_h..W_outh) are CONTIGUOUS for the fused convert.
    char* p = (char*)d_ws;
    f16* xz_h    = (f16*)p;  p += (size_t)MB_ROWS * MB_E2 * 2;      // 33.6 MB
    f16* u_h     = (f16*)p;  p += (size_t)MB_ROWS * MB_DINNER * 2;  // 16.8 MB
    f16* delta_h = (f16*)p;  p += (size_t)MB_ROWS * MB_DINNER * 2;  // 16.8 MB
    f16* yg_h    = (f16*)p;  p += (size_t)MB_ROWS * MB_DINNER * 2;  // 16.8 MB
    float* xdbl  = (float*)p; p += (size_t)MB_ROWS * 96 * 4;        // 1.6 MB
    f16* xdbl_h  = (f16*)p;  p += (size_t)MB_ROWS * 128 * 2;        // 1.0 MB
    f16* x_h     = (f16*)p;  p += (size_t)MB_ROWS * MB_DMODEL * 2;  // 8.4 MB
    f16* W_inh   = (f16*)p;  p += (size_t)MB_E2 * MB_DMODEL * 2;    // 8.4 MB
    f16* W_xprojh= (f16*)p;  p += (size_t)128 * MB_DINNER * 2;      // 0.5 MB
    f16* W_dth   = (f16*)p;  p += (size_t)MB_DINNER * MB_DTRANK * 2;// 0.26 MB
    f16* W_outh  = (f16*)p;  p += (size_t)MB_DMODEL * MB_DINNER * 2;// 4.2 MB
    float* Hc    = (float*)p; p += (size_t)SC_NC * MB_ROWS * MB_DSTATE * 4; // 2.1 MB
    float* Pc    = (float*)p; p += (size_t)SC_NC * MB_ROWS * MB_DSTATE * 4; // 2.1 MB
    float* Cp    = (float*)p;                                       // 16.8 MB

    const dim3 blk(256);

    // 0) one fused fp32 -> f16 convert over all segments
    convert_all_kernel<<<5312, blk, 0, stream>>>(
        x, W_in, W_xproj, W_dt, W_out, x_h);

    // 1) xz = x @ W_in^T     (M=4096, N=4096, K=1024) -> f16
    gemm_mfma<f16, 0><<<dim3(32, 32), blk, 0, stream>>>(
        x_h, MB_DMODEL, W_inh, MB_DMODEL, xz_h, MB_E2, MB_DMODEL, nullptr);

    // 2) u = silu(causal_dwconv(xb) + conv_b), 8 rows/thread
    conv_silu_kernel<<<MB_ROWS / CV_R, blk, 0, stream>>>(
        xz_h, conv_w, conv_b, u_h);

    // 3) x_dbl = u @ W_xproj^T  (M=4096, N=128, K=2048), split-K x8 + reduce
    gemm3_splitk<<<dim3(8, 32), blk, 0, stream>>>(u_h, W_xprojh, Cp);
    reduce_xdbl_kernel<<<512, blk, 0, stream>>>(Cp, xdbl, xdbl_h);

    // 4) delta = softplus(dt_low @ W_dt^T + b_dt)  (M=4096, N=2048, K=64)
    gemm_mfma<f16, 1><<<dim3(16, 32), blk, 0, stream>>>(
        xdbl_h, 128, W_dth, MB_DTRANK, delta_h, MB_DINNER, MB_DTRANK, b_dt);

    // 5a) scan pass 1: per-chunk (H, P) summaries (chunk 7 skipped)
    scan_pass1<<<(SC_NC - 1) * 256, blk, 0, stream>>>(
        delta_h, u_h, xdbl, A_log, Hc, Pc);

    // 5b) scan pass 2: carry-combine + replay with y/skip/gate -> yg (f16)
    scan_pass2<<<SC_NC * 256, blk, 0, stream>>>(
        delta_h, u_h, xdbl, A_log, Dskip, xz_h, Hc, Pc, yg_h);

    // 6) out = yg @ W_out^T   (M=4096, N=1024, K=2048) -> f32
    gemm_mfma<float, 0><<<dim3(8, 32), blk, 0, stream>>>(
        yg_h, MB_DINNER, W_outh, MB_DINNER, out, MB_DMODEL, MB_DINNER, nullptr);
}

// Round 9
// 341.811 us; speedup vs baseline: 5.4508x; 1.0185x over previous
//
#include <hip/hip_runtime.h>
#include <math.h>

// Mamba block fwd: B=2, L=2048, d_model=1024, d_inner=2048, d_state=16,
// d_conv=4, dt_rank=64.  GEMMs in f16 MFMA, scan fp32 chunked 2-pass.
// Scan v3: wave = 16 channels x 4 lanes, each lane owns 4 states ->
// 16-state reduction = 2 quad_perm DPP adds; ~2x fewer issue slots per
// (channel,step) than the 16x16 layout (which was 84% VALU-issue-bound).
#define MB_B      2
#define MB_L      2048
#define MB_DMODEL 1024
#define MB_DINNER 2048
#define MB_DSTATE 16
#define MB_DTRANK 64
#define MB_ROWS   (MB_B * MB_L)      // 4096
#define MB_E2     (2 * MB_DINNER)    // 4096
#define SC_NC     16                 // scan chunks
#define SC_CHUNK  (MB_L / SC_NC)     // 128 steps per chunk
#define SC_CL     32                 // staging window (steps)
#define SC_CB     64                 // channels per scan block
#define CV_R      8                  // conv rows per thread

typedef _Float16 f16;
typedef __attribute__((ext_vector_type(4))) _Float16 half4;
typedef __attribute__((ext_vector_type(8))) _Float16 half8;
typedef __attribute__((ext_vector_type(4))) float floatx4;

__device__ __forceinline__ float softplus_f(float x) {
    return (x > 20.f) ? x : log1pf(expf(x));
}
__device__ __forceinline__ float silu_f(float x) {
    return x / (1.f + expf(-x));
}

// 2^x via v_exp_f32 (callers fold log2(e) into the coefficient).
#if __has_builtin(__builtin_amdgcn_exp2f)
__device__ __forceinline__ float exp2_fast(float x) {
    return __builtin_amdgcn_exp2f(x);
}
#else
__device__ __forceinline__ float exp2_fast(float x) {
    return __expf(0.69314718056f * x);
}
#endif

// async global->LDS, 16B/lane. LDS dst is WAVE-UNIFORM base; HW adds lane*16.
typedef const __attribute__((address_space(1))) unsigned char gbyte;
typedef __attribute__((address_space(3))) unsigned char lbyte;
__device__ __forceinline__ void gl_lds16(const void* g, void* l) {
    __builtin_amdgcn_global_load_lds((gbyte*)g, (lbyte*)l, 16, 0, 0);
}

// VALU cross-lane add via DPP.  0xB1 = quad_perm(1,0,3,2) = xor1,
// 0x4E = quad_perm(2,3,0,1) = xor2: two adds reduce each 4-lane quad.
template <int CTRL>
__device__ __forceinline__ float dpp_add(float x) {
    int xi = __builtin_bit_cast(int, x);
    int yi = __builtin_amdgcn_update_dpp(0, xi, CTRL, 0xF, 0xF, true);
    return x + __builtin_bit_cast(float, yi);
}

// ---------------------------------------------------------------------------
// Single fused fp32 -> f16 convert over all weight/activation segments.
// Destinations contiguous in ws (x_h|W_inh|W_xprojh|W_dth|W_outh);
// W_xproj pads 196608->262144 with zeros.
// ---------------------------------------------------------------------------
__global__ __launch_bounds__(256) void convert_all_kernel(
    const float* __restrict__ x, const float* __restrict__ W_in,
    const float* __restrict__ W_xproj, const float* __restrict__ W_dt,
    const float* __restrict__ W_out, f16* __restrict__ dst)
{
    const int i = (blockIdx.x * 256 + threadIdx.x) * 8;  // < 10878976
    const float* src;
    int local, nsrc;
    if (i < 4194304)      { src = x;       local = i;           nsrc = 4194304; }
    else if (i < 8388608) { src = W_in;    local = i - 4194304; nsrc = 4194304; }
    else if (i < 8650752) { src = W_xproj; local = i - 8388608; nsrc = 196608; }
    else if (i < 8781824) { src = W_dt;    local = i - 8650752; nsrc = 131072; }
    else                  { src = W_out;   local = i - 8781824; nsrc = 2097152; }
    half8 o;
    if (local < nsrc) {
        const float4 a = *reinterpret_cast<const float4*>(src + local);
        const float4 b = *reinterpret_cast<const float4*>(src + local + 4);
        o[0] = (f16)a.x; o[1] = (f16)a.y; o[2] = (f16)a.z; o[3] = (f16)a.w;
        o[4] = (f16)b.x; o[5] = (f16)b.y; o[6] = (f16)b.z; o[7] = (f16)b.w;
    } else {
#pragma unroll
        for (int j = 0; j < 8; j++) o[j] = (f16)0.f;
    }
    *reinterpret_cast<half8*>(dst + i) = o;
}

// ---------------------------------------------------------------------------
// f16 MFMA GEMM:  C[m][n] = sum_k A[m][k]*B[n][k]   (C = A·B^T, f32 accum)
// 128x128 tile, BK=32, 4 waves in 2x2, global_load_lds width=16 staging.
// EPI==1: v = softplus(v + bias[n]).
// ---------------------------------------------------------------------------
template <typename OutT, int EPI>
__global__ __launch_bounds__(256) void gemm_mfma(
    const f16* __restrict__ A, int lda,
    const f16* __restrict__ B, int ldb,
    OutT* __restrict__ C, int ldc, int K,
    const float* __restrict__ bias)
{
    __shared__ f16 As[128 * 32];   // [row][k], row stride 32 halves (64 B)
    __shared__ f16 Bs[128 * 32];

    const int tid  = threadIdx.x;
    const int lane = tid & 63;
    const int wave = tid >> 6;
    const int wr   = wave >> 1, wc = wave & 1;
    const int bm   = blockIdx.y * 128, bn = blockIdx.x * 128;

    floatx4 zero4 = {0.f, 0.f, 0.f, 0.f};
    floatx4 acc[4][4];
#pragma unroll
    for (int i = 0; i < 4; i++)
#pragma unroll
        for (int j = 0; j < 4; j++) acc[i][j] = zero4;

    const int srow = lane >> 2;
    const int scol = (lane & 3) * 8;
    const f16* gA0 = A + (size_t)(bm + wave * 32 + srow) * lda + scol;
    const f16* gA1 = A + (size_t)(bm + wave * 32 + 16 + srow) * lda + scol;
    const f16* gB0 = B + (size_t)(bn + wave * 32 + srow) * ldb + scol;
    const f16* gB1 = B + (size_t)(bn + wave * 32 + 16 + srow) * ldb + scol;
    f16* lA0 = As + wave * 1024;
    f16* lA1 = As + wave * 1024 + 512;
    f16* lB0 = Bs + wave * 1024;
    f16* lB1 = Bs + wave * 1024 + 512;

    const int mr = lane & 15;
    const int kq = (lane >> 4) * 8;

    for (int k0 = 0; k0 < K; k0 += 32) {
        gl_lds16(gA0 + k0, lA0);
        gl_lds16(gA1 + k0, lA1);
        gl_lds16(gB0 + k0, lB0);
        gl_lds16(gB1 + k0, lB1);
        __syncthreads();

        half8 af[4], bf[4];
#pragma unroll
        for (int mt = 0; mt < 4; mt++)
            af[mt] = *reinterpret_cast<const half8*>(
                As + (wr * 64 + mt * 16 + mr) * 32 + kq);
#pragma unroll
        for (int nt = 0; nt < 4; nt++)
            bf[nt] = *reinterpret_cast<const half8*>(
                Bs + (wc * 64 + nt * 16 + mr) * 32 + kq);
#pragma unroll
        for (int mt = 0; mt < 4; mt++)
#pragma unroll
            for (int nt = 0; nt < 4; nt++)
                acc[mt][nt] = __builtin_amdgcn_mfma_f32_16x16x32_f16(
                    af[mt], bf[nt], acc[mt][nt], 0, 0, 0);
        __syncthreads();
    }

    // Epilogue. C/D layout (verified m89): col = lane&15, row = quad*4+reg.
    const int rbase = (lane >> 4) * 4;
#pragma unroll
    for (int mt = 0; mt < 4; mt++) {
        const int row0 = bm + wr * 64 + mt * 16 + rbase;
#pragma unroll
        for (int nt = 0; nt < 4; nt++) {
            const int col = bn + wc * 64 + nt * 16 + mr;
#pragma unroll
            for (int r = 0; r < 4; r++) {
                float v = acc[mt][nt][r];
                if constexpr (EPI == 1) v = softplus_f(v + bias[col]);
                C[(size_t)(row0 + r) * ldc + col] = (OutT)v;
            }
        }
    }
}

// ---------------------------------------------------------------------------
// gemm3 split-K: x_dbl partials.  A = u_h [4096][2048], B = W_xprojh
// [128][2048].  Grid (8, 32).  Writes f32 partial [slice][4096][128].
// ---------------------------------------------------------------------------
__global__ __launch_bounds__(256) void gemm3_splitk(
    const f16* __restrict__ A, const f16* __restrict__ B,
    float* __restrict__ Cp)
{
    __shared__ f16 As[128 * 32];
    __shared__ f16 Bs[128 * 32];

    const int tid  = threadIdx.x;
    const int lane = tid & 63;
    const int wave = tid >> 6;
    const int wr   = wave >> 1, wc = wave & 1;
    const int bm   = blockIdx.y * 128;
    const int kbeg = blockIdx.x * 256;

    floatx4 zero4 = {0.f, 0.f, 0.f, 0.f};
    floatx4 acc[4][4];
#pragma unroll
    for (int i = 0; i < 4; i++)
#pragma unroll
        for (int j = 0; j < 4; j++) acc[i][j] = zero4;

    const int srow = lane >> 2;
    const int scol = (lane & 3) * 8;
    const f16* gA0 = A + (size_t)(bm + wave * 32 + srow) * MB_DINNER + scol;
    const f16* gA1 = A + (size_t)(bm + wave * 32 + 16 + srow) * MB_DINNER + scol;
    const f16* gB0 = B + (size_t)(wave * 32 + srow) * MB_DINNER + scol;
    const f16* gB1 = B + (size_t)(wave * 32 + 16 + srow) * MB_DINNER + scol;
    f16* lA0 = As + wave * 1024;
    f16* lA1 = As + wave * 1024 + 512;
    f16* lB0 = Bs + wave * 1024;
    f16* lB1 = Bs + wave * 1024 + 512;

    const int mr = lane & 15;
    const int kq = (lane >> 4) * 8;

    for (int k0 = kbeg; k0 < kbeg + 256; k0 += 32) {
        gl_lds16(gA0 + k0, lA0);
        gl_lds16(gA1 + k0, lA1);
        gl_lds16(gB0 + k0, lB0);
        gl_lds16(gB1 + k0, lB1);
        __syncthreads();

        half8 af[4], bf[4];
#pragma unroll
        for (int mt = 0; mt < 4; mt++)
            af[mt] = *reinterpret_cast<const half8*>(
                As + (wr * 64 + mt * 16 + mr) * 32 + kq);
#pragma unroll
        for (int nt = 0; nt < 4; nt++)
            bf[nt] = *reinterpret_cast<const half8*>(
                Bs + (wc * 64 + nt * 16 + mr) * 32 + kq);
#pragma unroll
        for (int mt = 0; mt < 4; mt++)
#pragma unroll
            for (int nt = 0; nt < 4; nt++)
                acc[mt][nt] = __builtin_amdgcn_mfma_f32_16x16x32_f16(
                    af[mt], bf[nt], acc[mt][nt], 0, 0, 0);
        __syncthreads();
    }

    float* Co = Cp + (size_t)blockIdx.x * MB_ROWS * 128;
    const int rbase = (lane >> 4) * 4;
#pragma unroll
    for (int mt = 0; mt < 4; mt++) {
        const int row0 = bm + wr * 64 + mt * 16 + rbase;
#pragma unroll
        for (int nt = 0; nt < 4; nt++) {
            const int col = wc * 64 + nt * 16 + mr;
#pragma unroll
            for (int r = 0; r < 4; r++)
                Co[(size_t)(row0 + r) * 128 + col] = acc[mt][nt][r];
        }
    }
}

// ---------------------------------------------------------------------------
// Reduce the 8 split-K partials -> xdbl f32 [4096][96] + xdbl_h f16 [4096][128]
// ---------------------------------------------------------------------------
__global__ __launch_bounds__(256) void reduce_xdbl_kernel(
    const float* __restrict__ Cp, float* __restrict__ xdbl,
    f16* __restrict__ xdbl_h)
{
    const int t = blockIdx.x * 256 + threadIdx.x;   // 0..131071
    const int row = t >> 5, c4 = (t & 31) * 4;
    float4 s = {0.f, 0.f, 0.f, 0.f};
#pragma unroll
    for (int j = 0; j < 8; j++) {
        const float4 v = *reinterpret_cast<const float4*>(
            Cp + (size_t)j * MB_ROWS * 128 + (size_t)row * 128 + c4);
        s.x += v.x; s.y += v.y; s.z += v.z; s.w += v.w;
    }
    if (c4 < 96)
        *reinterpret_cast<float4*>(xdbl + (size_t)row * 96 + c4) = s;
    half4 h = {(f16)s.x, (f16)s.y, (f16)s.z, (f16)s.w};
    *reinterpret_cast<half4*>(xdbl_h + (size_t)row * 128 + c4) = h;
}

// ---------------------------------------------------------------------------
// Causal depthwise conv1d (width 4) + bias + SiLU, sliding-window.
// Each thread: 8 channels x CV_R consecutive time-steps.
// ---------------------------------------------------------------------------
__global__ __launch_bounds__(256) void conv_silu_kernel(
    const f16* __restrict__ xz, const float* __restrict__ cw,
    const float* __restrict__ cb, f16* __restrict__ u)
{
    const int tid  = threadIdx.x;
    const int dv   = tid * 8;                 // channel base 0..2040
    const int rbeg = blockIdx.x * CV_R;       // global row base
    const int l0   = rbeg & (MB_L - 1);       // position within batch

    float wt[8][4];
#pragma unroll
    for (int j = 0; j < 8; j++) {
        const float4 wv = *reinterpret_cast<const float4*>(cw + (dv + j) * 4);
        wt[j][0] = wv.x; wt[j][1] = wv.y; wt[j][2] = wv.z; wt[j][3] = wv.w;
    }
    float bias[8];
    {
        const float4 b0 = *reinterpret_cast<const float4*>(cb + dv);
        const float4 b1 = *reinterpret_cast<const float4*>(cb + dv + 4);
        bias[0] = b0.x; bias[1] = b0.y; bias[2] = b0.z; bias[3] = b0.w;
        bias[4] = b1.x; bias[5] = b1.y; bias[6] = b1.z; bias[7] = b1.w;
    }

    half8 xr[CV_R + 3];
#pragma unroll
    for (int i = 0; i < 3; i++) {
        if (l0 >= 3 - i) {
            xr[i] = *reinterpret_cast<const half8*>(
                xz + (size_t)(rbeg - 3 + i) * MB_E2 + dv);
        } else {
#pragma unroll
            for (int j = 0; j < 8; j++) xr[i][j] = (f16)0.f;
        }
    }
#pragma unroll
    for (int r = 0; r < CV_R; r++)
        xr[3 + r] = *reinterpret_cast<const half8*>(
            xz + (size_t)(rbeg + r) * MB_E2 + dv);

#pragma unroll
    for (int r = 0; r < CV_R; r++) {
        float acc[8];
#pragma unroll
        for (int j = 0; j < 8; j++) acc[j] = bias[j];
#pragma unroll
        for (int k = 0; k < 4; k++) {
            const half8 xv = xr[r + k];
#pragma unroll
            for (int j = 0; j < 8; j++)
                acc[j] = fmaf((float)xv[j], wt[j][k], acc[j]);
        }
        half8 o;
#pragma unroll
        for (int j = 0; j < 8; j++) o[j] = (f16)silu_f(acc[j]);
        *reinterpret_cast<half8*>(u + (size_t)(rbeg + r) * MB_DINNER + dv) = o;
    }
}

// ---------------------------------------------------------------------------
// Scan pass 1 (v3 layout): block = 64 channels x 128-step chunk.
// Lane (ch, q): ch = wave*16 + (lane>>2)&15, q = lane&3 owns states 4q..4q+3.
// Per step: 1 ds_read_b64 (δ, δu) + 1 ds_read_b128 (B[step][n]) + 4 exp2 +
// 12 mul/fma.  Emits H (local final state) and P = exp2(Av2·Σδ) as float4.
// Grid: 15 chunks x 64 channel-blocks (chunk 15's summary never consumed).
// ---------------------------------------------------------------------------
__global__ __launch_bounds__(256) void scan_pass1(
    const f16*  __restrict__ delta,   // [4096][2048]
    const f16*  __restrict__ u,       // [4096][2048]
    const float* __restrict__ xdbl,   // [4096][96]  (dt|B|C)
    const float* __restrict__ A_log,  // [2048][16]
    float* __restrict__ Hc,           // [16][4096][16]
    float* __restrict__ Pc)           // [16][4096][16]
{
    __shared__ float2 sDU[SC_CB][SC_CL + 1];   // (δ, δ·u)  [ch][step]
    __shared__ float  sB[SC_CL][20];           // B  [step][n], +4 pad

    const int tid   = threadIdx.x;
    const int lane  = tid & 63;
    const int wave  = tid >> 6;
    const int cg    = (lane >> 2) & 15;
    const int q     = lane & 3;
    const int ch    = wave * 16 + cg;          // channel in block, 0..63
    const int cb    = blockIdx.x & 63;
    const int chunk = blockIdx.x >> 6;
    const int gchan = cb * SC_CB + ch;
    const int b     = gchan >> 11;
    const int dbase = (cb & 31) * SC_CB;
    const int d     = dbase + ch;
    const int lbeg  = chunk * SC_CHUNK;

    const size_t base2048 = (size_t)b * MB_L * MB_DINNER;
    const size_t base96   = (size_t)b * MB_L * 96;

    const float4 alog = *reinterpret_cast<const float4*>(
        A_log + d * MB_DSTATE + q * 4);
    float Av2[4] = {-expf(alog.x) * 1.44269504f, -expf(alog.y) * 1.44269504f,
                    -expf(alog.z) * 1.44269504f, -expf(alog.w) * 1.44269504f};
    float h[4] = {0.f, 0.f, 0.f, 0.f};
    float sdt = 0.f;

    // staging maps: (lloc, c8) for δ/u half8; (lloc, cpair) for B float2
    const int lloc  = tid >> 3;        // 0..31
    const int c8    = (tid & 7) * 8;   // 0..56
    const int cpair = (tid & 7) * 2;   // 0..14

    half8 pD, pU; float2 pB;
    auto stage_load = [&](int l0) {
        const size_t row = (size_t)(l0 + lloc);
        pD = *reinterpret_cast<const half8*>(
            delta + base2048 + row * MB_DINNER + dbase + c8);
        pU = *reinterpret_cast<const half8*>(
            u + base2048 + row * MB_DINNER + dbase + c8);
        pB = *reinterpret_cast<const float2*>(
            xdbl + base96 + row * 96 + MB_DTRANK + cpair);
    };
    auto stage_write = [&]() {
#pragma unroll
        for (int j = 0; j < 8; j++) {
            const float dd = (float)pD[j], uu = (float)pU[j];
            sDU[c8 + j][lloc] = make_float2(dd, dd * uu);
        }
        *reinterpret_cast<float2*>(&sB[lloc][cpair]) = pB;
    };

    stage_load(lbeg);
    stage_write();
    __syncthreads();

    for (int l0 = lbeg; l0 < lbeg + SC_CHUNK; l0 += SC_CL) {
        const bool has_next = (l0 + SC_CL) < lbeg + SC_CHUNK;
        if (has_next) stage_load(l0 + SC_CL);

#pragma unroll
        for (int ll = 0; ll < SC_CL; ll++) {
            const float2 du = sDU[ch][ll];
            const float4 Bv = *reinterpret_cast<const float4*>(&sB[ll][q * 4]);
            h[0] = fmaf(exp2_fast(du.x * Av2[0]), h[0], du.y * Bv.x);
            h[1] = fmaf(exp2_fast(du.x * Av2[1]), h[1], du.y * Bv.y);
            h[2] = fmaf(exp2_fast(du.x * Av2[2]), h[2], du.y * Bv.z);
            h[3] = fmaf(exp2_fast(du.x * Av2[3]), h[3], du.y * Bv.w);
            sdt += du.x;
        }
        __syncthreads();
        if (has_next) stage_write();
        __syncthreads();
    }

    const size_t cidx = ((size_t)chunk * MB_ROWS + gchan) * MB_DSTATE + q * 4;
    float4 H4 = {h[0], h[1], h[2], h[3]};
    float4 P4 = {exp2_fast(Av2[0] * sdt), exp2_fast(Av2[1] * sdt),
                 exp2_fast(Av2[2] * sdt), exp2_fast(Av2[3] * sdt)};
    *reinterpret_cast<float4*>(Hc + cidx) = H4;
    *reinterpret_cast<float4*>(Pc + cidx) = P4;
}

// ---------------------------------------------------------------------------
// Scan pass 2 (v3 layout): carry-combine (float4 H/P per lane), replay chunk.
// Per step: 3 LDS reads + 4 exp2 + 16 mul/fma + 2 quad DPP + 1 select.
// y captured in regs (lane q takes steps l0+4k+q); skip+gate at store time.
// ---------------------------------------------------------------------------
__global__ __launch_bounds__(256) void scan_pass2(
    const f16*  __restrict__ delta,   // [4096][2048]
    const f16*  __restrict__ u,       // [4096][2048]
    const float* __restrict__ xdbl,   // [4096][96]  (dt|B|C)
    const float* __restrict__ A_log,  // [2048][16]
    const float* __restrict__ Dskip,  // [2048]
    const f16*  __restrict__ xz,      // z = cols [2048,4096)
    const float* __restrict__ Hc,     // [16][4096][16]
    const float* __restrict__ Pc,     // [16][4096][16]
    f16* __restrict__ yg)             // [4096][2048]
{
    __shared__ float2 sDU[SC_CB][SC_CL + 1];   // (δ, δ·u)
    __shared__ float2 sGS[SC_CB][SC_CL + 1];   // (g, u·Dsk·g)
    __shared__ float  sB[SC_CL][20];
    __shared__ float  sC[SC_CL][20];

    const int tid   = threadIdx.x;
    const int lane  = tid & 63;
    const int wave  = tid >> 6;
    const int cg    = (lane >> 2) & 15;
    const int q     = lane & 3;
    const int ch    = wave * 16 + cg;
    const int cb    = blockIdx.x & 63;
    const int chunk = blockIdx.x >> 6;
    const int gchan = cb * SC_CB + ch;
    const int b     = gchan >> 11;
    const int dbase = (cb & 31) * SC_CB;
    const int d     = dbase + ch;
    const int lbeg  = chunk * SC_CHUNK;

    const size_t base2048 = (size_t)b * MB_L * MB_DINNER;
    const size_t base4096 = (size_t)b * MB_L * MB_E2;
    const size_t base96   = (size_t)b * MB_L * 96;

    const float4 alog = *reinterpret_cast<const float4*>(
        A_log + d * MB_DSTATE + q * 4);
    float Av2[4] = {-expf(alog.x) * 1.44269504f, -expf(alog.y) * 1.44269504f,
                    -expf(alog.z) * 1.44269504f, -expf(alog.w) * 1.44269504f};

    // staging maps
    const int lloc  = tid >> 3;
    const int c8    = (tid & 7) * 8;
    const int cpair = (tid & 7) * 2;

    float Dsk8[8];
    {
        const float4 d0 = *reinterpret_cast<const float4*>(Dskip + dbase + c8);
        const float4 d1 = *reinterpret_cast<const float4*>(Dskip + dbase + c8 + 4);
        Dsk8[0] = d0.x; Dsk8[1] = d0.y; Dsk8[2] = d0.z; Dsk8[3] = d0.w;
        Dsk8[4] = d1.x; Dsk8[5] = d1.y; Dsk8[6] = d1.z; Dsk8[7] = d1.w;
    }

    half8 pD, pU, pZ; float2 pB, pC;
    auto stage_load = [&](int l0) {
        const size_t row = (size_t)(l0 + lloc);
        pD = *reinterpret_cast<const half8*>(
            delta + base2048 + row * MB_DINNER + dbase + c8);
        pU = *reinterpret_cast<const half8*>(
            u + base2048 + row * MB_DINNER + dbase + c8);
        pZ = *reinterpret_cast<const half8*>(
            xz + base4096 + row * MB_E2 + MB_DINNER + dbase + c8);
        pB = *reinterpret_cast<const float2*>(
            xdbl + base96 + row * 96 + MB_DTRANK + cpair);
        pC = *reinterpret_cast<const float2*>(
            xdbl + base96 + row * 96 + MB_DTRANK + MB_DSTATE + cpair);
    };
    auto stage_write = [&]() {
#pragma unroll
        for (int j = 0; j < 8; j++) {
            const float dd = (float)pD[j], uu = (float)pU[j];
            sDU[c8 + j][lloc] = make_float2(dd, dd * uu);
            const float g = silu_f((float)pZ[j]);
            sGS[c8 + j][lloc] = make_float2(g, uu * Dsk8[j] * g);
        }
        *reinterpret_cast<float2*>(&sB[lloc][cpair]) = pB;
        *reinterpret_cast<float2*>(&sC[lloc][cpair]) = pC;
    };

    stage_load(lbeg);   // issue first window's loads before the carry chain

    // carry-in: h after chunks 0..chunk-1 (float4 per lane, L2-warm)
    float h[4] = {0.f, 0.f, 0.f, 0.f};
    for (int j = 0; j < chunk; j++) {
        const size_t cidx = ((size_t)j * MB_ROWS + gchan) * MB_DSTATE + q * 4;
        const float4 P4 = *reinterpret_cast<const float4*>(Pc + cidx);
        const float4 H4 = *reinterpret_cast<const float4*>(Hc + cidx);
        h[0] = fmaf(P4.x, h[0], H4.x);
        h[1] = fmaf(P4.y, h[1], H4.y);
        h[2] = fmaf(P4.z, h[2], H4.z);
        h[3] = fmaf(P4.w, h[3], H4.w);
    }

    stage_write();
    __syncthreads();

    for (int l0 = lbeg; l0 < lbeg + SC_CHUNK; l0 += SC_CL) {
        const bool has_next = (l0 + SC_CL) < lbeg + SC_CHUNK;
        if (has_next) stage_load(l0 + SC_CL);

        float y[SC_CL / 4] = {0.f, 0.f, 0.f, 0.f, 0.f, 0.f, 0.f, 0.f};
#pragma unroll
        for (int ll = 0; ll < SC_CL; ll++) {
            const float2 du = sDU[ch][ll];
            const float4 Bv = *reinterpret_cast<const float4*>(&sB[ll][q * 4]);
            const float4 Cv = *reinterpret_cast<const float4*>(&sC[ll][q * 4]);
            h[0] = fmaf(exp2_fast(du.x * Av2[0]), h[0], du.y * Bv.x);
            h[1] = fmaf(exp2_fast(du.x * Av2[1]), h[1], du.y * Bv.y);
            h[2] = fmaf(exp2_fast(du.x * Av2[2]), h[2], du.y * Bv.z);
            h[3] = fmaf(exp2_fast(du.x * Av2[3]), h[3], du.y * Bv.w);
            float p = h[0] * Cv.x;
            p = fmaf(h[1], Cv.y, p);
            p = fmaf(h[2], Cv.z, p);
            p = fmaf(h[3], Cv.w, p);
            p = dpp_add<0xB1>(p);   // quad xor1
            p = dpp_add<0x4E>(p);   // quad xor2: all 4 lanes hold 16-state sum
            y[ll >> 2] = (q == (ll & 3)) ? p : y[ll >> 2];
        }

        // store: lane q of channel ch owns steps l0+4k+q; skip+gate here
#pragma unroll
        for (int k = 0; k < SC_CL / 4; k++) {
            const float2 gs = sGS[ch][4 * k + q];
            yg[base2048 + (size_t)(l0 + 4 * k + q) * MB_DINNER + dbase + ch] =
                (f16)fmaf(y[k], gs.x, gs.y);
        }

        __syncthreads();
        if (has_next) stage_write();
        __syncthreads();
    }
}

// ---------------------------------------------------------------------------
extern "C" void kernel_launch(void* const* d_in, const int* in_sizes, int n_in,
                              void* d_out, int out_size, void* d_ws,
                              size_t ws_size, hipStream_t stream)
{
    const float* x      = (const float*)d_in[0];  // (2,2048,1024)
    const float* W_in   = (const float*)d_in[1];  // (4096,1024)
    const float* conv_w = (const float*)d_in[2];  // (2048,1,4)
    const float* conv_b = (const float*)d_in[3];  // (2048)
    const float* W_xproj= (const float*)d_in[4];  // (96,2048)
    const float* W_dt   = (const float*)d_in[5];  // (2048,64)
    const float* b_dt   = (const float*)d_in[6];  // (2048)
    const float* A_log  = (const float*)d_in[7];  // (2048,16)
    const float* Dskip  = (const float*)d_in[8];  // (2048)
    const float* W_out  = (const float*)d_in[9];  // (1024,2048)
    float* out = (float*)d_out;                   // (2,2048,1024)

    // Workspace (~134 MB).  The five f16 convert destinations
    // (x_h..W_outh) are CONTIGUOUS for the fused convert.
    char* p = (char*)d_ws;
    f16* xz_h    = (f16*)p;  p += (size_t)MB_ROWS * MB_E2 * 2;      // 33.6 MB
    f16* u_h     = (f16*)p;  p += (size_t)MB_ROWS * MB_DINNER * 2;  // 16.8 MB
    f16* delta_h = (f16*)p;  p += (size_t)MB_ROWS * MB_DINNER * 2;  // 16.8 MB
    f16* yg_h    = (f16*)p;  p += (size_t)MB_ROWS * MB_DINNER * 2;  // 16.8 MB
    float* xdbl  = (float*)p; p += (size_t)MB_ROWS * 96 * 4;        // 1.6 MB
    f16* xdbl_h  = (f16*)p;  p += (size_t)MB_ROWS * 128 * 2;        // 1.0 MB
    f16* x_h     = (f16*)p;  p += (size_t)MB_ROWS * MB_DMODEL * 2;  // 8.4 MB
    f16* W_inh   = (f16*)p;  p += (size_t)MB_E2 * MB_DMODEL * 2;    // 8.4 MB
    f16* W_xprojh= (f16*)p;  p += (size_t)128 * MB_DINNER * 2;      // 0.5 MB
    f16* W_dth   = (f16*)p;  p += (size_t)MB_DINNER * MB_DTRANK * 2;// 0.26 MB
    f16* W_outh  = (f16*)p;  p += (size_t)MB_DMODEL * MB_DINNER * 2;// 4.2 MB
    float* Hc    = (float*)p; p += (size_t)SC_NC * MB_ROWS * MB_DSTATE * 4; // 4.2 MB
    float* Pc    = (float*)p; p += (size_t)SC_NC * MB_ROWS * MB_DSTATE * 4; // 4.2 MB
    float* Cp    = (float*)p;                                       // 16.8 MB

    const dim3 blk(256);

    // 0) one fused fp32 -> f16 convert over all segments
    convert_all_kernel<<<5312, blk, 0, stream>>>(
        x, W_in, W_xproj, W_dt, W_out, x_h);

    // 1) xz = x @ W_in^T     (M=4096, N=4096, K=1024) -> f16
    gemm_mfma<f16, 0><<<dim3(32, 32), blk, 0, stream>>>(
        x_h, MB_DMODEL, W_inh, MB_DMODEL, xz_h, MB_E2, MB_DMODEL, nullptr);

    // 2) u = silu(causal_dwconv(xb) + conv_b), 8 rows/thread
    conv_silu_kernel<<<MB_ROWS / CV_R, blk, 0, stream>>>(
        xz_h, conv_w, conv_b, u_h);

    // 3) x_dbl = u @ W_xproj^T  (M=4096, N=128, K=2048), split-K x8 + reduce
    gemm3_splitk<<<dim3(8, 32), blk, 0, stream>>>(u_h, W_xprojh, Cp);
    reduce_xdbl_kernel<<<512, blk, 0, stream>>>(Cp, xdbl, xdbl_h);

    // 4) delta = softplus(dt_low @ W_dt^T + b_dt)  (M=4096, N=2048, K=64)
    gemm_mfma<f16, 1><<<dim3(16, 32), blk, 0, stream>>>(
        xdbl_h, 128, W_dth, MB_DTRANK, delta_h, MB_DINNER, MB_DTRANK, b_dt);

    // 5a) scan pass 1: per-chunk (H, P) summaries (last chunk skipped)
    scan_pass1<<<(SC_NC - 1) * 64, blk, 0, stream>>>(
        delta_h, u_h, xdbl, A_log, Hc, Pc);

    // 5b) scan pass 2: carry-combine + replay with y/skip/gate -> yg (f16)
    scan_pass2<<<SC_NC * 64, blk, 0, stream>>>(
        delta_h, u_h, xdbl, A_log, Dskip, xz_h, Hc, Pc, yg_h);

    // 6) out = yg @ W_out^T   (M=4096, N=1024, K=2048) -> f32
    gemm_mfma<float, 0><<<dim3(8, 32), blk, 0, stream>>>(
        yg_h, MB_DINNER, W_outh, MB_DINNER, out, MB_DMODEL, MB_DINNER, nullptr);
}

// Round 10
// 331.859 us; speedup vs baseline: 5.6142x; 1.0300x over previous
//
#include <hip/hip_runtime.h>
#include <math.h>

// Mamba block fwd: B=2, L=2048, d_model=1024, d_inner=2048, d_state=16,
// d_conv=4, dt_rank=64.  GEMMs in f16 MFMA, scan fp32 chunked 2-pass.
// Round 10: XOR bank-conflict swizzle in all MFMA staging/fragment paths
// (round 9 measured 4.2M SQ_LDS_BANK_CONFLICT = 4 extra cy per ds_read_b128:
// 64-B row stride puts 8 lanes on one 4-bank group); GEMM6 re-gridded to
// 512 blocks (was 256 = 1 block/CU, no barrier overlap).
#define MB_B      2
#define MB_L      2048
#define MB_DMODEL 1024
#define MB_DINNER 2048
#define MB_DSTATE 16
#define MB_DTRANK 64
#define MB_ROWS   (MB_B * MB_L)      // 4096
#define MB_E2     (2 * MB_DINNER)    // 4096
#define SC_NC     16                 // scan chunks
#define SC_CHUNK  (MB_L / SC_NC)     // 128 steps per chunk
#define SC_CL     32                 // staging window (steps)
#define SC_CB     64                 // channels per scan block
#define CV_R      8                  // conv rows per thread

typedef _Float16 f16;
typedef __attribute__((ext_vector_type(4))) _Float16 half4;
typedef __attribute__((ext_vector_type(8))) _Float16 half8;
typedef __attribute__((ext_vector_type(4))) float floatx4;

__device__ __forceinline__ float softplus_f(float x) {
    return (x > 20.f) ? x : log1pf(expf(x));
}
__device__ __forceinline__ float silu_f(float x) {
    return x / (1.f + expf(-x));
}

#if __has_builtin(__builtin_amdgcn_exp2f)
__device__ __forceinline__ float exp2_fast(float x) {
    return __builtin_amdgcn_exp2f(x);
}
#else
__device__ __forceinline__ float exp2_fast(float x) {
    return __expf(0.69314718056f * x);
}
#endif

// async global->LDS, 16B/lane. LDS dst is WAVE-UNIFORM base; HW adds lane*16.
typedef const __attribute__((address_space(1))) unsigned char gbyte;
typedef __attribute__((address_space(3))) unsigned char lbyte;
__device__ __forceinline__ void gl_lds16(const void* g, void* l) {
    __builtin_amdgcn_global_load_lds((gbyte*)g, (lbyte*)l, 16, 0, 0);
}

// VALU cross-lane add via DPP.  0xB1 = quad xor1, 0x4E = quad xor2.
template <int CTRL>
__device__ __forceinline__ float dpp_add(float x) {
    int xi = __builtin_bit_cast(int, x);
    int yi = __builtin_amdgcn_update_dpp(0, xi, CTRL, 0xF, 0xF, true);
    return x + __builtin_bit_cast(float, yi);
}

// ---------------------------------------------------------------------------
// Single fused fp32 -> f16 convert over all weight/activation segments.
// ---------------------------------------------------------------------------
__global__ __launch_bounds__(256) void convert_all_kernel(
    const float* __restrict__ x, const float* __restrict__ W_in,
    const float* __restrict__ W_xproj, const float* __restrict__ W_dt,
    const float* __restrict__ W_out, f16* __restrict__ dst)
{
    const int i = (blockIdx.x * 256 + threadIdx.x) * 8;  // < 10878976
    const float* src;
    int local, nsrc;
    if (i < 4194304)      { src = x;       local = i;           nsrc = 4194304; }
    else if (i < 8388608) { src = W_in;    local = i - 4194304; nsrc = 4194304; }
    else if (i < 8650752) { src = W_xproj; local = i - 8388608; nsrc = 196608; }
    else if (i < 8781824) { src = W_dt;    local = i - 8650752; nsrc = 131072; }
    else                  { src = W_out;   local = i - 8781824; nsrc = 2097152; }
    half8 o;
    if (local < nsrc) {
        const float4 a = *reinterpret_cast<const float4*>(src + local);
        const float4 b = *reinterpret_cast<const float4*>(src + local + 4);
        o[0] = (f16)a.x; o[1] = (f16)a.y; o[2] = (f16)a.z; o[3] = (f16)a.w;
        o[4] = (f16)b.x; o[5] = (f16)b.y; o[6] = (f16)b.z; o[7] = (f16)b.w;
    } else {
#pragma unroll
        for (int j = 0; j < 8; j++) o[j] = (f16)0.f;
    }
    *reinterpret_cast<half8*>(dst + i) = o;
}

// ---------------------------------------------------------------------------
// f16 MFMA GEMM:  C[m][n] = sum_k A[m][k]*B[n][k]   (C = A·B^T, f32 accum)
// Block tile BM x 128, 4 waves in (4/GN) x GN grid, BK=32,
// global_load_lds width=16 staging.
// XOR swizzle: LDS chunk c of row r holds global k-chunk c ^ ((r>>1)&3).
// Permutation is applied in the staging LOAD address (the wave-uniform LDS
// destination of global_load_lds is untouched) and undone in the fragment
// read -> fragment-read banks spread over 8 groups (2-way, free) instead of
// the unswizzled 8-way conflict (measured 4.2M conflict-cycles/dispatch).
// EPI==1: v = softplus(v + bias[n]).
// ---------------------------------------------------------------------------
template <typename OutT, int EPI, int BM, int GN>
__global__ __launch_bounds__(256) void gemm_mfma(
    const f16* __restrict__ A, int lda,
    const f16* __restrict__ B, int ldb,
    OutT* __restrict__ C, int ldc, int K,
    const float* __restrict__ bias)
{
    constexpr int BN = 128;
    constexpr int GM = 4 / GN;
    constexpr int WM = BM / GM;       // wave tile rows
    constexpr int WN = BN / GN;       // wave tile cols
    constexpr int MT = WM / 16, NT = WN / 16;
    constexpr int NCH = (BM + BN) / 16;   // 16-row staging chunks
    constexpr int CPW = NCH / 4;          // chunks per wave

    __shared__ f16 As[BM * 32];   // [row][k], row stride 32 halves (64 B)
    __shared__ f16 Bs[BN * 32];

    const int tid  = threadIdx.x;
    const int lane = tid & 63;
    const int wave = tid >> 6;
    const int wr   = wave / GN, wc = wave % GN;
    const int bm   = blockIdx.y * BM, bn = blockIdx.x * BN;

    floatx4 zero4 = {0.f, 0.f, 0.f, 0.f};
    floatx4 acc[MT][NT];
#pragma unroll
    for (int i = 0; i < MT; i++)
#pragma unroll
        for (int j = 0; j < NT; j++) acc[i][j] = zero4;

    // staging: lane covers row srow, stored-chunk schunk; global chunk is
    // schunk ^ ((srow>>1)&3)  (swizzle uniform across 16-row chunks)
    const int srow = lane >> 2;
    const int scol = ((lane & 3) ^ ((srow >> 1) & 3)) * 8;
    const f16* gp[CPW];
    f16* lp[CPW];
#pragma unroll
    for (int i = 0; i < CPW; i++) {
        const int rbase = (wave * CPW + i) * 16;
        if (rbase < BM) {
            gp[i] = A + (size_t)(bm + rbase + srow) * lda + scol;
            lp[i] = As + rbase * 32;
        } else {
            gp[i] = B + (size_t)(bn + (rbase - BM) + srow) * ldb + scol;
            lp[i] = Bs + (rbase - BM) * 32;
        }
    }

    const int mr = lane & 15;
    const int kq = ((lane >> 4) ^ ((mr >> 1) & 3)) * 8;  // swizzled k offset

    for (int k0 = 0; k0 < K; k0 += 32) {
#pragma unroll
        for (int i = 0; i < CPW; i++) gl_lds16(gp[i] + k0, lp[i]);
        __syncthreads();   // drains vmcnt; LDS tiles visible

        half8 af[MT], bf[NT];
#pragma unroll
        for (int mt = 0; mt < MT; mt++)
            af[mt] = *reinterpret_cast<const half8*>(
                As + (wr * WM + mt * 16 + mr) * 32 + kq);
#pragma unroll
        for (int nt = 0; nt < NT; nt++)
            bf[nt] = *reinterpret_cast<const half8*>(
                Bs + (wc * WN + nt * 16 + mr) * 32 + kq);
#pragma unroll
        for (int mt = 0; mt < MT; mt++)
#pragma unroll
            for (int nt = 0; nt < NT; nt++)
                acc[mt][nt] = __builtin_amdgcn_mfma_f32_16x16x32_f16(
                    af[mt], bf[nt], acc[mt][nt], 0, 0, 0);
        __syncthreads();   // all reads done before next stage overwrites
    }

    // Epilogue. C/D layout (verified m89): col = lane&15, row = quad*4+reg.
    const int rbase = (lane >> 4) * 4;
#pragma unroll
    for (int mt = 0; mt < MT; mt++) {
        const int row0 = bm + wr * WM + mt * 16 + rbase;
#pragma unroll
        for (int nt = 0; nt < NT; nt++) {
            const int col = bn + wc * WN + nt * 16 + mr;
#pragma unroll
            for (int r = 0; r < 4; r++) {
                float v = acc[mt][nt][r];
                if constexpr (EPI == 1) v = softplus_f(v + bias[col]);
                C[(size_t)(row0 + r) * ldc + col] = (OutT)v;
            }
        }
    }
}

// ---------------------------------------------------------------------------
// gemm3 split-K: x_dbl partials.  A = u_h [4096][2048], B = W_xprojh
// [128][2048].  Grid (8, 32).  Writes f32 partial [slice][4096][128].
// Same XOR swizzle as gemm_mfma.
// ---------------------------------------------------------------------------
__global__ __launch_bounds__(256) void gemm3_splitk(
    const f16* __restrict__ A, const f16* __restrict__ B,
    float* __restrict__ Cp)
{
    __shared__ f16 As[128 * 32];
    __shared__ f16 Bs[128 * 32];

    const int tid  = threadIdx.x;
    const int lane = tid & 63;
    const int wave = tid >> 6;
    const int wr   = wave >> 1, wc = wave & 1;
    const int bm   = blockIdx.y * 128;
    const int kbeg = blockIdx.x * 256;

    floatx4 zero4 = {0.f, 0.f, 0.f, 0.f};
    floatx4 acc[4][4];
#pragma unroll
    for (int i = 0; i < 4; i++)
#pragma unroll
        for (int j = 0; j < 4; j++) acc[i][j] = zero4;

    const int srow = lane >> 2;
    const int scol = ((lane & 3) ^ ((srow >> 1) & 3)) * 8;
    const f16* gA0 = A + (size_t)(bm + wave * 32 + srow) * MB_DINNER + scol;
    const f16* gA1 = A + (size_t)(bm + wave * 32 + 16 + srow) * MB_DINNER + scol;
    const f16* gB0 = B + (size_t)(wave * 32 + srow) * MB_DINNER + scol;
    const f16* gB1 = B + (size_t)(wave * 32 + 16 + srow) * MB_DINNER + scol;
    f16* lA0 = As + wave * 1024;
    f16* lA1 = As + wave * 1024 + 512;
    f16* lB0 = Bs + wave * 1024;
    f16* lB1 = Bs + wave * 1024 + 512;

    const int mr = lane & 15;
    const int kq = ((lane >> 4) ^ ((mr >> 1) & 3)) * 8;

    for (int k0 = kbeg; k0 < kbeg + 256; k0 += 32) {
        gl_lds16(gA0 + k0, lA0);
        gl_lds16(gA1 + k0, lA1);
        gl_lds16(gB0 + k0, lB0);
        gl_lds16(gB1 + k0, lB1);
        __syncthreads();

        half8 af[4], bf[4];
#pragma unroll
        for (int mt = 0; mt < 4; mt++)
            af[mt] = *reinterpret_cast<const half8*>(
                As + (wr * 64 + mt * 16 + mr) * 32 + kq);
#pragma unroll
        for (int nt = 0; nt < 4; nt++)
            bf[nt] = *reinterpret_cast<const half8*>(
                Bs + (wc * 64 + nt * 16 + mr) * 32 + kq);
#pragma unroll
        for (int mt = 0; mt < 4; mt++)
#pragma unroll
            for (int nt = 0; nt < 4; nt++)
                acc[mt][nt] = __builtin_amdgcn_mfma_f32_16x16x32_f16(
                    af[mt], bf[nt], acc[mt][nt], 0, 0, 0);
        __syncthreads();
    }

    float* Co = Cp + (size_t)blockIdx.x * MB_ROWS * 128;
    const int rbase = (lane >> 4) * 4;
#pragma unroll
    for (int mt = 0; mt < 4; mt++) {
        const int row0 = bm + wr * 64 + mt * 16 + rbase;
#pragma unroll
        for (int nt = 0; nt < 4; nt++) {
            const int col = wc * 64 + nt * 16 + mr;
#pragma unroll
            for (int r = 0; r < 4; r++)
                Co[(size_t)(row0 + r) * 128 + col] = acc[mt][nt][r];
        }
    }
}

// ---------------------------------------------------------------------------
// Reduce the 8 split-K partials -> xdbl f32 [4096][96] + xdbl_h f16 [4096][128]
// ---------------------------------------------------------------------------
__global__ __launch_bounds__(256) void reduce_xdbl_kernel(
    const float* __restrict__ Cp, float* __restrict__ xdbl,
    f16* __restrict__ xdbl_h)
{
    const int t = blockIdx.x * 256 + threadIdx.x;   // 0..131071
    const int row = t >> 5, c4 = (t & 31) * 4;
    float4 s = {0.f, 0.f, 0.f, 0.f};
#pragma unroll
    for (int j = 0; j < 8; j++) {
        const float4 v = *reinterpret_cast<const float4*>(
            Cp + (size_t)j * MB_ROWS * 128 + (size_t)row * 128 + c4);
        s.x += v.x; s.y += v.y; s.z += v.z; s.w += v.w;
    }
    if (c4 < 96)
        *reinterpret_cast<float4*>(xdbl + (size_t)row * 96 + c4) = s;
    half4 h = {(f16)s.x, (f16)s.y, (f16)s.z, (f16)s.w};
    *reinterpret_cast<half4*>(xdbl_h + (size_t)row * 128 + c4) = h;
}

// ---------------------------------------------------------------------------
// Causal depthwise conv1d (width 4) + bias + SiLU, sliding-window.
// Each thread: 8 channels x CV_R consecutive time-steps.
// ---------------------------------------------------------------------------
__global__ __launch_bounds__(256) void conv_silu_kernel(
    const f16* __restrict__ xz, const float* __restrict__ cw,
    const float* __restrict__ cb, f16* __restrict__ u)
{
    const int tid  = threadIdx.x;
    const int dv   = tid * 8;                 // channel base 0..2040
    const int rbeg = blockIdx.x * CV_R;       // global row base
    const int l0   = rbeg & (MB_L - 1);       // position within batch

    float wt[8][4];
#pragma unroll
    for (int j = 0; j < 8; j++) {
        const float4 wv = *reinterpret_cast<const float4*>(cw + (dv + j) * 4);
        wt[j][0] = wv.x; wt[j][1] = wv.y; wt[j][2] = wv.z; wt[j][3] = wv.w;
    }
    float bias[8];
    {
        const float4 b0 = *reinterpret_cast<const float4*>(cb + dv);
        const float4 b1 = *reinterpret_cast<const float4*>(cb + dv + 4);
        bias[0] = b0.x; bias[1] = b0.y; bias[2] = b0.z; bias[3] = b0.w;
        bias[4] = b1.x; bias[5] = b1.y; bias[6] = b1.z; bias[7] = b1.w;
    }

    half8 xr[CV_R + 3];
#pragma unroll
    for (int i = 0; i < 3; i++) {
        if (l0 >= 3 - i) {
            xr[i] = *reinterpret_cast<const half8*>(
                xz + (size_t)(rbeg - 3 + i) * MB_E2 + dv);
        } else {
#pragma unroll
            for (int j = 0; j < 8; j++) xr[i][j] = (f16)0.f;
        }
    }
#pragma unroll
    for (int r = 0; r < CV_R; r++)
        xr[3 + r] = *reinterpret_cast<const half8*>(
            xz + (size_t)(rbeg + r) * MB_E2 + dv);

#pragma unroll
    for (int r = 0; r < CV_R; r++) {
        float acc[8];
#pragma unroll
        for (int j = 0; j < 8; j++) acc[j] = bias[j];
#pragma unroll
        for (int k = 0; k < 4; k++) {
            const half8 xv = xr[r + k];
#pragma unroll
            for (int j = 0; j < 8; j++)
                acc[j] = fmaf((float)xv[j], wt[j][k], acc[j]);
        }
        half8 o;
#pragma unroll
        for (int j = 0; j < 8; j++) o[j] = (f16)silu_f(acc[j]);
        *reinterpret_cast<half8*>(u + (size_t)(rbeg + r) * MB_DINNER + dv) = o;
    }
}

// ---------------------------------------------------------------------------
// Scan pass 1 (v3 layout): block = 64 channels x 128-step chunk.
// Lane (ch, q): ch = wave*16 + (lane>>2)&15, q = lane&3 owns states 4q..4q+3.
// ---------------------------------------------------------------------------
__global__ __launch_bounds__(256) void scan_pass1(
    const f16*  __restrict__ delta,   // [4096][2048]
    const f16*  __restrict__ u,       // [4096][2048]
    const float* __restrict__ xdbl,   // [4096][96]  (dt|B|C)
    const float* __restrict__ A_log,  // [2048][16]
    float* __restrict__ Hc,           // [16][4096][16]
    float* __restrict__ Pc)           // [16][4096][16]
{
    __shared__ float2 sDU[SC_CB][SC_CL + 1];   // (δ, δ·u)  [ch][step]
    __shared__ float  sB[SC_CL][20];           // B  [step][n], +4 pad

    const int tid   = threadIdx.x;
    const int lane  = tid & 63;
    const int wave  = tid >> 6;
    const int cg    = (lane >> 2) & 15;
    const int q     = lane & 3;
    const int ch    = wave * 16 + cg;          // channel in block, 0..63
    const int cb    = blockIdx.x & 63;
    const int chunk = blockIdx.x >> 6;
    const int gchan = cb * SC_CB + ch;
    const int b     = gchan >> 11;
    const int dbase = (cb & 31) * SC_CB;
    const int d     = dbase + ch;
    const int lbeg  = chunk * SC_CHUNK;

    const size_t base2048 = (size_t)b * MB_L * MB_DINNER;
    const size_t base96   = (size_t)b * MB_L * 96;

    const float4 alog = *reinterpret_cast<const float4*>(
        A_log + d * MB_DSTATE + q * 4);
    float Av2[4] = {-expf(alog.x) * 1.44269504f, -expf(alog.y) * 1.44269504f,
                    -expf(alog.z) * 1.44269504f, -expf(alog.w) * 1.44269504f};
    float h[4] = {0.f, 0.f, 0.f, 0.f};
    float sdt = 0.f;

    const int lloc  = tid >> 3;        // 0..31
    const int c8    = (tid & 7) * 8;   // 0..56
    const int cpair = (tid & 7) * 2;   // 0..14

    half8 pD, pU; float2 pB;
    auto stage_load = [&](int l0) {
        const size_t row = (size_t)(l0 + lloc);
        pD = *reinterpret_cast<const half8*>(
            delta + base2048 + row * MB_DINNER + dbase + c8);
        pU = *reinterpret_cast<const half8*>(
            u + base2048 + row * MB_DINNER + dbase + c8);
        pB = *reinterpret_cast<const float2*>(
            xdbl + base96 + row * 96 + MB_DTRANK + cpair);
    };
    auto stage_write = [&]() {
#pragma unroll
        for (int j = 0; j < 8; j++) {
            const float dd = (float)pD[j], uu = (float)pU[j];
            sDU[c8 + j][lloc] = make_float2(dd, dd * uu);
        }
        *reinterpret_cast<float2*>(&sB[lloc][cpair]) = pB;
    };

    stage_load(lbeg);
    stage_write();
    __syncthreads();

    for (int l0 = lbeg; l0 < lbeg + SC_CHUNK; l0 += SC_CL) {
        const bool has_next = (l0 + SC_CL) < lbeg + SC_CHUNK;
        if (has_next) stage_load(l0 + SC_CL);

#pragma unroll
        for (int ll = 0; ll < SC_CL; ll++) {
            const float2 du = sDU[ch][ll];
            const float4 Bv = *reinterpret_cast<const float4*>(&sB[ll][q * 4]);
            h[0] = fmaf(exp2_fast(du.x * Av2[0]), h[0], du.y * Bv.x);
            h[1] = fmaf(exp2_fast(du.x * Av2[1]), h[1], du.y * Bv.y);
            h[2] = fmaf(exp2_fast(du.x * Av2[2]), h[2], du.y * Bv.z);
            h[3] = fmaf(exp2_fast(du.x * Av2[3]), h[3], du.y * Bv.w);
            sdt += du.x;
        }
        __syncthreads();
        if (has_next) stage_write();
        __syncthreads();
    }

    const size_t cidx = ((size_t)chunk * MB_ROWS + gchan) * MB_DSTATE + q * 4;
    float4 H4 = {h[0], h[1], h[2], h[3]};
    float4 P4 = {exp2_fast(Av2[0] * sdt), exp2_fast(Av2[1] * sdt),
                 exp2_fast(Av2[2] * sdt), exp2_fast(Av2[3] * sdt)};
    *reinterpret_cast<float4*>(Hc + cidx) = H4;
    *reinterpret_cast<float4*>(Pc + cidx) = P4;
}

// ---------------------------------------------------------------------------
// Scan pass 2 (v3 layout): carry-combine (float4 H/P per lane), replay chunk.
// ---------------------------------------------------------------------------
__global__ __launch_bounds__(256) void scan_pass2(
    const f16*  __restrict__ delta,   // [4096][2048]
    const f16*  __restrict__ u,       // [4096][2048]
    const float* __restrict__ xdbl,   // [4096][96]  (dt|B|C)
    const float* __restrict__ A_log,  // [2048][16]
    const float* __restrict__ Dskip,  // [2048]
    const f16*  __restrict__ xz,      // z = cols [2048,4096)
    const float* __restrict__ Hc,     // [16][4096][16]
    const float* __restrict__ Pc,     // [16][4096][16]
    f16* __restrict__ yg)             // [4096][2048]
{
    __shared__ float2 sDU[SC_CB][SC_CL + 1];   // (δ, δ·u)
    __shared__ float2 sGS[SC_CB][SC_CL + 1];   // (g, u·Dsk·g)
    __shared__ float  sB[SC_CL][20];
    __shared__ float  sC[SC_CL][20];

    const int tid   = threadIdx.x;
    const int lane  = tid & 63;
    const int wave  = tid >> 6;
    const int cg    = (lane >> 2) & 15;
    const int q     = lane & 3;
    const int ch    = wave * 16 + cg;
    const int cb    = blockIdx.x & 63;
    const int chunk = blockIdx.x >> 6;
    const int gchan = cb * SC_CB + ch;
    const int b     = gchan >> 11;
    const int dbase = (cb & 31) * SC_CB;
    const int d     = dbase + ch;
    const int lbeg  = chunk * SC_CHUNK;

    const size_t base2048 = (size_t)b * MB_L * MB_DINNER;
    const size_t base4096 = (size_t)b * MB_L * MB_E2;
    const size_t base96   = (size_t)b * MB_L * 96;

    const float4 alog = *reinterpret_cast<const float4*>(
        A_log + d * MB_DSTATE + q * 4);
    float Av2[4] = {-expf(alog.x) * 1.44269504f, -expf(alog.y) * 1.44269504f,
                    -expf(alog.z) * 1.44269504f, -expf(alog.w) * 1.44269504f};

    const int lloc  = tid >> 3;
    const int c8    = (tid & 7) * 8;
    const int cpair = (tid & 7) * 2;

    float Dsk8[8];
    {
        const float4 d0 = *reinterpret_cast<const float4*>(Dskip + dbase + c8);
        const float4 d1 = *reinterpret_cast<const float4*>(Dskip + dbase + c8 + 4);
        Dsk8[0] = d0.x; Dsk8[1] = d0.y; Dsk8[2] = d0.z; Dsk8[3] = d0.w;
        Dsk8[4] = d1.x; Dsk8[5] = d1.y; Dsk8[6] = d1.z; Dsk8[7] = d1.w;
    }

    half8 pD, pU, pZ; float2 pB, pC;
    auto stage_load = [&](int l0) {
        const size_t row = (size_t)(l0 + lloc);
        pD = *reinterpret_cast<const half8*>(
            delta + base2048 + row * MB_DINNER + dbase + c8);
        pU = *reinterpret_cast<const half8*>(
            u + base2048 + row * MB_DINNER + dbase + c8);
        pZ = *reinterpret_cast<const half8*>(
            xz + base4096 + row * MB_E2 + MB_DINNER + dbase + c8);
        pB = *reinterpret_cast<const float2*>(
            xdbl + base96 + row * 96 + MB_DTRANK + cpair);
        pC = *reinterpret_cast<const float2*>(
            xdbl + base96 + row * 96 + MB_DTRANK + MB_DSTATE + cpair);
    };
    auto stage_write = [&]() {
#pragma unroll
        for (int j = 0; j < 8; j++) {
            const float dd = (float)pD[j], uu = (float)pU[j];
            sDU[c8 + j][lloc] = make_float2(dd, dd * uu);
            const float g = silu_f((float)pZ[j]);
            sGS[c8 + j][lloc] = make_float2(g, uu * Dsk8[j] * g);
        }
        *reinterpret_cast<float2*>(&sB[lloc][cpair]) = pB;
        *reinterpret_cast<float2*>(&sC[lloc][cpair]) = pC;
    };

    stage_load(lbeg);   // issue first window's loads before the carry chain

    float h[4] = {0.f, 0.f, 0.f, 0.f};
    for (int j = 0; j < chunk; j++) {
        const size_t cidx = ((size_t)j * MB_ROWS + gchan) * MB_DSTATE + q * 4;
        const float4 P4 = *reinterpret_cast<const float4*>(Pc + cidx);
        const float4 H4 = *reinterpret_cast<const float4*>(Hc + cidx);
        h[0] = fmaf(P4.x, h[0], H4.x);
        h[1] = fmaf(P4.y, h[1], H4.y);
        h[2] = fmaf(P4.z, h[2], H4.z);
        h[3] = fmaf(P4.w, h[3], H4.w);
    }

    stage_write();
    __syncthreads();

    for (int l0 = lbeg; l0 < lbeg + SC_CHUNK; l0 += SC_CL) {
        const bool has_next = (l0 + SC_CL) < lbeg + SC_CHUNK;
        if (has_next) stage_load(l0 + SC_CL);

        float y[SC_CL / 4] = {0.f, 0.f, 0.f, 0.f, 0.f, 0.f, 0.f, 0.f};
#pragma unroll
        for (int ll = 0; ll < SC_CL; ll++) {
            const float2 du = sDU[ch][ll];
            const float4 Bv = *reinterpret_cast<const float4*>(&sB[ll][q * 4]);
            const float4 Cv = *reinterpret_cast<const float4*>(&sC[ll][q * 4]);
            h[0] = fmaf(exp2_fast(du.x * Av2[0]), h[0], du.y * Bv.x);
            h[1] = fmaf(exp2_fast(du.x * Av2[1]), h[1], du.y * Bv.y);
            h[2] = fmaf(exp2_fast(du.x * Av2[2]), h[2], du.y * Bv.z);
            h[3] = fmaf(exp2_fast(du.x * Av2[3]), h[3], du.y * Bv.w);
            float p = h[0] * Cv.x;
            p = fmaf(h[1], Cv.y, p);
            p = fmaf(h[2], Cv.z, p);
            p = fmaf(h[3], Cv.w, p);
            p = dpp_add<0xB1>(p);   // quad xor1
            p = dpp_add<0x4E>(p);   // quad xor2: all 4 lanes hold 16-state sum
            y[ll >> 2] = (q == (ll & 3)) ? p : y[ll >> 2];
        }

#pragma unroll
        for (int k = 0; k < SC_CL / 4; k++) {
            const float2 gs = sGS[ch][4 * k + q];
            yg[base2048 + (size_t)(l0 + 4 * k + q) * MB_DINNER + dbase + ch] =
                (f16)fmaf(y[k], gs.x, gs.y);
        }

        __syncthreads();
        if (has_next) stage_write();
        __syncthreads();
    }
}

// ---------------------------------------------------------------------------
extern "C" void kernel_launch(void* const* d_in, const int* in_sizes, int n_in,
                              void* d_out, int out_size, void* d_ws,
                              size_t ws_size, hipStream_t stream)
{
    const float* x      = (const float*)d_in[0];  // (2,2048,1024)
    const float* W_in   = (const float*)d_in[1];  // (4096,1024)
    const float* conv_w = (const float*)d_in[2];  // (2048,1,4)
    const float* conv_b = (const float*)d_in[3];  // (2048)
    const float* W_xproj= (const float*)d_in[4];  // (96,2048)
    const float* W_dt   = (const float*)d_in[5];  // (2048,64)
    const float* b_dt   = (const float*)d_in[6];  // (2048)
    const float* A_log  = (const float*)d_in[7];  // (2048,16)
    const float* Dskip  = (const float*)d_in[8];  // (2048)
    const float* W_out  = (const float*)d_in[9];  // (1024,2048)
    float* out = (float*)d_out;                   // (2,2048,1024)

    // Workspace (~134 MB).  The five f16 convert destinations
    // (x_h..W_outh) are CONTIGUOUS for the fused convert.
    char* p = (char*)d_ws;
    f16* xz_h    = (f16*)p;  p += (size_t)MB_ROWS * MB_E2 * 2;      // 33.6 MB
    f16* u_h     = (f16*)p;  p += (size_t)MB_ROWS * MB_DINNER * 2;  // 16.8 MB
    f16* delta_h = (f16*)p;  p += (size_t)MB_ROWS * MB_DINNER * 2;  // 16.8 MB
    f16* yg_h    = (f16*)p;  p += (size_t)MB_ROWS * MB_DINNER * 2;  // 16.8 MB
    float* xdbl  = (float*)p; p += (size_t)MB_ROWS * 96 * 4;        // 1.6 MB
    f16* xdbl_h  = (f16*)p;  p += (size_t)MB_ROWS * 128 * 2;        // 1.0 MB
    f16* x_h     = (f16*)p;  p += (size_t)MB_ROWS * MB_DMODEL * 2;  // 8.4 MB
    f16* W_inh   = (f16*)p;  p += (size_t)MB_E2 * MB_DMODEL * 2;    // 8.4 MB
    f16* W_xprojh= (f16*)p;  p += (size_t)128 * MB_DINNER * 2;      // 0.5 MB
    f16* W_dth   = (f16*)p;  p += (size_t)MB_DINNER * MB_DTRANK * 2;// 0.26 MB
    f16* W_outh  = (f16*)p;  p += (size_t)MB_DMODEL * MB_DINNER * 2;// 4.2 MB
    float* Hc    = (float*)p; p += (size_t)SC_NC * MB_ROWS * MB_DSTATE * 4; // 4.2 MB
    float* Pc    = (float*)p; p += (size_t)SC_NC * MB_ROWS * MB_DSTATE * 4; // 4.2 MB
    float* Cp    = (float*)p;                                       // 16.8 MB

    const dim3 blk(256);

    // 0) one fused fp32 -> f16 convert over all segments
    convert_all_kernel<<<5312, blk, 0, stream>>>(
        x, W_in, W_xproj, W_dt, W_out, x_h);

    // 1) xz = x @ W_in^T     (M=4096, N=4096, K=1024) -> f16
    gemm_mfma<f16, 0, 128, 2><<<dim3(32, 32), blk, 0, stream>>>(
        x_h, MB_DMODEL, W_inh, MB_DMODEL, xz_h, MB_E2, MB_DMODEL, nullptr);

    // 2) u = silu(causal_dwconv(xb) + conv_b), 8 rows/thread
    conv_silu_kernel<<<MB_ROWS / CV_R, blk, 0, stream>>>(
        xz_h, conv_w, conv_b, u_h);

    // 3) x_dbl = u @ W_xproj^T  (M=4096, N=128, K=2048), split-K x8 + reduce
    gemm3_splitk<<<dim3(8, 32), blk, 0, stream>>>(u_h, W_xprojh, Cp);
    reduce_xdbl_kernel<<<512, blk, 0, stream>>>(Cp, xdbl, xdbl_h);

    // 4) delta = softplus(dt_low @ W_dt^T + b_dt)  (M=4096, N=2048, K=64)
    gemm_mfma<f16, 1, 128, 2><<<dim3(16, 32), blk, 0, stream>>>(
        xdbl_h, 128, W_dth, MB_DTRANK, delta_h, MB_DINNER, MB_DTRANK, b_dt);

    // 5a) scan pass 1: per-chunk (H, P) summaries (last chunk skipped)
    scan_pass1<<<(SC_NC - 1) * 64, blk, 0, stream>>>(
        delta_h, u_h, xdbl, A_log, Hc, Pc);

    // 5b) scan pass 2: carry-combine + replay with y/skip/gate -> yg (f16)
    scan_pass2<<<SC_NC * 64, blk, 0, stream>>>(
        delta_h, u_h, xdbl, A_log, Dskip, xz_h, Hc, Pc, yg_h);

    // 6) out = yg @ W_out^T   (M=4096, N=1024, K=2048) -> f32
    //    BM=64 x BN=128 tiles: 512 blocks = 2/CU (was 256 = 1/CU, every
    //    barrier drain exposed with no co-resident block to overlap).
    gemm_mfma<float, 0, 64, 4><<<dim3(8, 64), blk, 0, stream>>>(
        yg_h, MB_DINNER, W_outh, MB_DINNER, out, MB_DMODEL, MB_DINNER, nullptr);
}

// Round 11
// 314.612 us; speedup vs baseline: 5.9220x; 1.0548x over previous
//
#include <hip/hip_runtime.h>
#include <math.h>

// Mamba block fwd: B=2, L=2048, d_model=1024, d_inner=2048, d_state=16,
// d_conv=4, dt_rank=64.  GEMMs in f16 MFMA, scan fp32 chunked 2-pass.
// Round 11: BK=64 K-loop in the main GEMM (half the barrier drains; round
// 10 showed conflicts=0 yet only -2us -> limiter is the per-iteration
// vmcnt(0)+barrier drain, amplified at K=1024's 32 iterations).
#define MB_B      2
#define MB_L      2048
#define MB_DMODEL 1024
#define MB_DINNER 2048
#define MB_DSTATE 16
#define MB_DTRANK 64
#define MB_ROWS   (MB_B * MB_L)      // 4096
#define MB_E2     (2 * MB_DINNER)    // 4096
#define SC_NC     16                 // scan chunks
#define SC_CHUNK  (MB_L / SC_NC)     // 128 steps per chunk
#define SC_CL     32                 // staging window (steps)
#define SC_CB     64                 // channels per scan block
#define CV_R      8                  // conv rows per thread

typedef _Float16 f16;
typedef __attribute__((ext_vector_type(4))) _Float16 half4;
typedef __attribute__((ext_vector_type(8))) _Float16 half8;
typedef __attribute__((ext_vector_type(4))) float floatx4;

__device__ __forceinline__ float softplus_f(float x) {
    return (x > 20.f) ? x : log1pf(expf(x));
}
__device__ __forceinline__ float silu_f(float x) {
    return x / (1.f + expf(-x));
}

#if __has_builtin(__builtin_amdgcn_exp2f)
__device__ __forceinline__ float exp2_fast(float x) {
    return __builtin_amdgcn_exp2f(x);
}
#else
__device__ __forceinline__ float exp2_fast(float x) {
    return __expf(0.69314718056f * x);
}
#endif

// async global->LDS, 16B/lane. LDS dst is WAVE-UNIFORM base; HW adds lane*16.
typedef const __attribute__((address_space(1))) unsigned char gbyte;
typedef __attribute__((address_space(3))) unsigned char lbyte;
__device__ __forceinline__ void gl_lds16(const void* g, void* l) {
    __builtin_amdgcn_global_load_lds((gbyte*)g, (lbyte*)l, 16, 0, 0);
}

// VALU cross-lane add via DPP.  0xB1 = quad xor1, 0x4E = quad xor2.
template <int CTRL>
__device__ __forceinline__ float dpp_add(float x) {
    int xi = __builtin_bit_cast(int, x);
    int yi = __builtin_amdgcn_update_dpp(0, xi, CTRL, 0xF, 0xF, true);
    return x + __builtin_bit_cast(float, yi);
}

// ---------------------------------------------------------------------------
// Single fused fp32 -> f16 convert over all weight/activation segments.
// ---------------------------------------------------------------------------
__global__ __launch_bounds__(256) void convert_all_kernel(
    const float* __restrict__ x, const float* __restrict__ W_in,
    const float* __restrict__ W_xproj, const float* __restrict__ W_dt,
    const float* __restrict__ W_out, f16* __restrict__ dst)
{
    const int i = (blockIdx.x * 256 + threadIdx.x) * 8;  // < 10878976
    const float* src;
    int local, nsrc;
    if (i < 4194304)      { src = x;       local = i;           nsrc = 4194304; }
    else if (i < 8388608) { src = W_in;    local = i - 4194304; nsrc = 4194304; }
    else if (i < 8650752) { src = W_xproj; local = i - 8388608; nsrc = 196608; }
    else if (i < 8781824) { src = W_dt;    local = i - 8650752; nsrc = 131072; }
    else                  { src = W_out;   local = i - 8781824; nsrc = 2097152; }
    half8 o;
    if (local < nsrc) {
        const float4 a = *reinterpret_cast<const float4*>(src + local);
        const float4 b = *reinterpret_cast<const float4*>(src + local + 4);
        o[0] = (f16)a.x; o[1] = (f16)a.y; o[2] = (f16)a.z; o[3] = (f16)a.w;
        o[4] = (f16)b.x; o[5] = (f16)b.y; o[6] = (f16)b.z; o[7] = (f16)b.w;
    } else {
#pragma unroll
        for (int j = 0; j < 8; j++) o[j] = (f16)0.f;
    }
    *reinterpret_cast<half8*>(dst + i) = o;
}

// ---------------------------------------------------------------------------
// f16 MFMA GEMM, BK=64:  C[m][n] = sum_k A[m][k]*B[n][k]  (C = A·B^T)
// Block tile BM x 128, 4 waves in (4/GN) x GN grid.  Per K-iteration each
// wave stages (BM+BN)/32 x 1024B chunks (8 rows x 128 B) via global_load_lds
// and issues 2x MT x NT MFMAs — same LDS:MFMA ratio as BK=32 but HALF the
// vmcnt(0)+barrier drains.
// XOR swizzle (128-B rows): global k-chunk g at stored position p obeys
// g = p ^ (row&7); fragment reads spread the 16 mr-rows across all 8
// bank-groups (2-way, free).  EPI==1: v = softplus(v + bias[n]).
// ---------------------------------------------------------------------------
template <typename OutT, int EPI, int BM, int GN>
__global__ __launch_bounds__(256) void gemm_mfma(
    const f16* __restrict__ A, int lda,
    const f16* __restrict__ B, int ldb,
    OutT* __restrict__ C, int ldc, int K,
    const float* __restrict__ bias)
{
    constexpr int BN = 128;
    constexpr int GM = 4 / GN;
    constexpr int WM = BM / GM;       // wave tile rows
    constexpr int WN = BN / GN;       // wave tile cols
    constexpr int MT = WM / 16, NT = WN / 16;
    constexpr int CPW = (BM + BN) / 32;   // 8-row staging chunks per wave

    __shared__ f16 As[BM * 64];   // [row][k], row stride 64 halves (128 B)
    __shared__ f16 Bs[BN * 64];

    const int tid  = threadIdx.x;
    const int lane = tid & 63;
    const int wave = tid >> 6;
    const int wr   = wave / GN, wc = wave % GN;
    const int bm   = blockIdx.y * BM, bn = blockIdx.x * BN;

    floatx4 zero4 = {0.f, 0.f, 0.f, 0.f};
    floatx4 acc[MT][NT];
#pragma unroll
    for (int i = 0; i < MT; i++)
#pragma unroll
        for (int j = 0; j < NT; j++) acc[i][j] = zero4;

    // staging: lane covers row srow (=row&7 within chunk), stored 16B-chunk
    // p = lane&7; global chunk g = p ^ (srow&7) -> scol elements
    const int srow = lane >> 3;
    const int scol = ((lane & 7) ^ (srow & 7)) * 8;
    const f16* gp[CPW];
    f16* lp[CPW];
#pragma unroll
    for (int i = 0; i < CPW; i++) {
        const int rbase = (wave * CPW + i) * 8;
        if (rbase < BM) {
            gp[i] = A + (size_t)(bm + rbase + srow) * lda + scol;
            lp[i] = As + rbase * 64;
        } else {
            gp[i] = B + (size_t)(bn + (rbase - BM) + srow) * ldb + scol;
            lp[i] = Bs + (rbase - BM) * 64;
        }
    }

    const int mr = lane & 15;
    const int ko = lane >> 4;         // 0..3: k-chunk within a 32-wide MFMA

    for (int k0 = 0; k0 < K; k0 += 64) {
#pragma unroll
        for (int i = 0; i < CPW; i++) gl_lds16(gp[i] + k0, lp[i]);
        __syncthreads();   // drains vmcnt; LDS tiles visible

        half8 af[MT][2], bf[NT][2];
#pragma unroll
        for (int kk = 0; kk < 2; kk++) {
            const int koff = ((ko + kk * 4) ^ (mr & 7)) * 8;  // swizzled
#pragma unroll
            for (int mt = 0; mt < MT; mt++)
                af[mt][kk] = *reinterpret_cast<const half8*>(
                    As + (wr * WM + mt * 16 + mr) * 64 + koff);
#pragma unroll
            for (int nt = 0; nt < NT; nt++)
                bf[nt][kk] = *reinterpret_cast<const half8*>(
                    Bs + (wc * WN + nt * 16 + mr) * 64 + koff);
        }
#pragma unroll
        for (int kk = 0; kk < 2; kk++)
#pragma unroll
            for (int mt = 0; mt < MT; mt++)
#pragma unroll
                for (int nt = 0; nt < NT; nt++)
                    acc[mt][nt] = __builtin_amdgcn_mfma_f32_16x16x32_f16(
                        af[mt][kk], bf[nt][kk], acc[mt][nt], 0, 0, 0);
        __syncthreads();   // all reads done before next stage overwrites
    }

    // Epilogue. C/D layout (verified m89): col = lane&15, row = quad*4+reg.
    const int rbase = (lane >> 4) * 4;
#pragma unroll
    for (int mt = 0; mt < MT; mt++) {
        const int row0 = bm + wr * WM + mt * 16 + rbase;
#pragma unroll
        for (int nt = 0; nt < NT; nt++) {
            const int col = bn + wc * WN + nt * 16 + mr;
#pragma unroll
            for (int r = 0; r < 4; r++) {
                float v = acc[mt][nt][r];
                if constexpr (EPI == 1) v = softplus_f(v + bias[col]);
                C[(size_t)(row0 + r) * ldc + col] = (OutT)v;
            }
        }
    }
}

// ---------------------------------------------------------------------------
// gemm3 split-K (BK=32, 64-B-row swizzle): x_dbl partials.
// A = u_h [4096][2048], B = W_xprojh [128][2048].  Grid (8, 32).
// ---------------------------------------------------------------------------
__global__ __launch_bounds__(256) void gemm3_splitk(
    const f16* __restrict__ A, const f16* __restrict__ B,
    float* __restrict__ Cp)
{
    __shared__ f16 As[128 * 32];
    __shared__ f16 Bs[128 * 32];

    const int tid  = threadIdx.x;
    const int lane = tid & 63;
    const int wave = tid >> 6;
    const int wr   = wave >> 1, wc = wave & 1;
    const int bm   = blockIdx.y * 128;
    const int kbeg = blockIdx.x * 256;

    floatx4 zero4 = {0.f, 0.f, 0.f, 0.f};
    floatx4 acc[4][4];
#pragma unroll
    for (int i = 0; i < 4; i++)
#pragma unroll
        for (int j = 0; j < 4; j++) acc[i][j] = zero4;

    const int srow = lane >> 2;
    const int scol = ((lane & 3) ^ ((srow >> 1) & 3)) * 8;
    const f16* gA0 = A + (size_t)(bm + wave * 32 + srow) * MB_DINNER + scol;
    const f16* gA1 = A + (size_t)(bm + wave * 32 + 16 + srow) * MB_DINNER + scol;
    const f16* gB0 = B + (size_t)(wave * 32 + srow) * MB_DINNER + scol;
    const f16* gB1 = B + (size_t)(wave * 32 + 16 + srow) * MB_DINNER + scol;
    f16* lA0 = As + wave * 1024;
    f16* lA1 = As + wave * 1024 + 512;
    f16* lB0 = Bs + wave * 1024;
    f16* lB1 = Bs + wave * 1024 + 512;

    const int mr = lane & 15;
    const int kq = ((lane >> 4) ^ ((mr >> 1) & 3)) * 8;

    for (int k0 = kbeg; k0 < kbeg + 256; k0 += 32) {
        gl_lds16(gA0 + k0, lA0);
        gl_lds16(gA1 + k0, lA1);
        gl_lds16(gB0 + k0, lB0);
        gl_lds16(gB1 + k0, lB1);
        __syncthreads();

        half8 af[4], bf[4];
#pragma unroll
        for (int mt = 0; mt < 4; mt++)
            af[mt] = *reinterpret_cast<const half8*>(
                As + (wr * 64 + mt * 16 + mr) * 32 + kq);
#pragma unroll
        for (int nt = 0; nt < 4; nt++)
            bf[nt] = *reinterpret_cast<const half8*>(
                Bs + (wc * 64 + nt * 16 + mr) * 32 + kq);
#pragma unroll
        for (int mt = 0; mt < 4; mt++)
#pragma unroll
            for (int nt = 0; nt < 4; nt++)
                acc[mt][nt] = __builtin_amdgcn_mfma_f32_16x16x32_f16(
                    af[mt], bf[nt], acc[mt][nt], 0, 0, 0);
        __syncthreads();
    }

    float* Co = Cp + (size_t)blockIdx.x * MB_ROWS * 128;
    const int rbase = (lane >> 4) * 4;
#pragma unroll
    for (int mt = 0; mt < 4; mt++) {
        const int row0 = bm + wr * 64 + mt * 16 + rbase;
#pragma unroll
        for (int nt = 0; nt < 4; nt++) {
            const int col = wc * 64 + nt * 16 + mr;
#pragma unroll
            for (int r = 0; r < 4; r++)
                Co[(size_t)(row0 + r) * 128 + col] = acc[mt][nt][r];
        }
    }
}

// ---------------------------------------------------------------------------
// Reduce the 8 split-K partials -> xdbl f32 [4096][96] + xdbl_h f16 [4096][128]
// ---------------------------------------------------------------------------
__global__ __launch_bounds__(256) void reduce_xdbl_kernel(
    const float* __restrict__ Cp, float* __restrict__ xdbl,
    f16* __restrict__ xdbl_h)
{
    const int t = blockIdx.x * 256 + threadIdx.x;   // 0..131071
    const int row = t >> 5, c4 = (t & 31) * 4;
    float4 s = {0.f, 0.f, 0.f, 0.f};
#pragma unroll
    for (int j = 0; j < 8; j++) {
        const float4 v = *reinterpret_cast<const float4*>(
            Cp + (size_t)j * MB_ROWS * 128 + (size_t)row * 128 + c4);
        s.x += v.x; s.y += v.y; s.z += v.z; s.w += v.w;
    }
    if (c4 < 96)
        *reinterpret_cast<float4*>(xdbl + (size_t)row * 96 + c4) = s;
    half4 h = {(f16)s.x, (f16)s.y, (f16)s.z, (f16)s.w};
    *reinterpret_cast<half4*>(xdbl_h + (size_t)row * 128 + c4) = h;
}

// ---------------------------------------------------------------------------
// Causal depthwise conv1d (width 4) + bias + SiLU, sliding-window.
// ---------------------------------------------------------------------------
__global__ __launch_bounds__(256) void conv_silu_kernel(
    const f16* __restrict__ xz, const float* __restrict__ cw,
    const float* __restrict__ cb, f16* __restrict__ u)
{
    const int tid  = threadIdx.x;
    const int dv   = tid * 8;                 // channel base 0..2040
    const int rbeg = blockIdx.x * CV_R;       // global row base
    const int l0   = rbeg & (MB_L - 1);       // position within batch

    float wt[8][4];
#pragma unroll
    for (int j = 0; j < 8; j++) {
        const float4 wv = *reinterpret_cast<const float4*>(cw + (dv + j) * 4);
        wt[j][0] = wv.x; wt[j][1] = wv.y; wt[j][2] = wv.z; wt[j][3] = wv.w;
    }
    float bias[8];
    {
        const float4 b0 = *reinterpret_cast<const float4*>(cb + dv);
        const float4 b1 = *reinterpret_cast<const float4*>(cb + dv + 4);
        bias[0] = b0.x; bias[1] = b0.y; bias[2] = b0.z; bias[3] = b0.w;
        bias[4] = b1.x; bias[5] = b1.y; bias[6] = b1.z; bias[7] = b1.w;
    }

    half8 xr[CV_R + 3];
#pragma unroll
    for (int i = 0; i < 3; i++) {
        if (l0 >= 3 - i) {
            xr[i] = *reinterpret_cast<const half8*>(
                xz + (size_t)(rbeg - 3 + i) * MB_E2 + dv);
        } else {
#pragma unroll
            for (int j = 0; j < 8; j++) xr[i][j] = (f16)0.f;
        }
    }
#pragma unroll
    for (int r = 0; r < CV_R; r++)
        xr[3 + r] = *reinterpret_cast<const half8*>(
            xz + (size_t)(rbeg + r) * MB_E2 + dv);

#pragma unroll
    for (int r = 0; r < CV_R; r++) {
        float acc[8];
#pragma unroll
        for (int j = 0; j < 8; j++) acc[j] = bias[j];
#pragma unroll
        for (int k = 0; k < 4; k++) {
            const half8 xv = xr[r + k];
#pragma unroll
            for (int j = 0; j < 8; j++)
                acc[j] = fmaf((float)xv[j], wt[j][k], acc[j]);
        }
        half8 o;
#pragma unroll
        for (int j = 0; j < 8; j++) o[j] = (f16)silu_f(acc[j]);
        *reinterpret_cast<half8*>(u + (size_t)(rbeg + r) * MB_DINNER + dv) = o;
    }
}

// ---------------------------------------------------------------------------
// Scan pass 1 (v3 layout): block = 64 channels x 128-step chunk.
// Lane (ch, q): ch = wave*16 + (lane>>2)&15, q = lane&3 owns states 4q..4q+3.
// ---------------------------------------------------------------------------
__global__ __launch_bounds__(256) void scan_pass1(
    const f16*  __restrict__ delta,   // [4096][2048]
    const f16*  __restrict__ u,       // [4096][2048]
    const float* __restrict__ xdbl,   // [4096][96]  (dt|B|C)
    const float* __restrict__ A_log,  // [2048][16]
    float* __restrict__ Hc,           // [16][4096][16]
    float* __restrict__ Pc)           // [16][4096][16]
{
    __shared__ float2 sDU[SC_CB][SC_CL + 1];   // (δ, δ·u)  [ch][step]
    __shared__ float  sB[SC_CL][20];           // B  [step][n], +4 pad

    const int tid   = threadIdx.x;
    const int lane  = tid & 63;
    const int wave  = tid >> 6;
    const int cg    = (lane >> 2) & 15;
    const int q     = lane & 3;
    const int ch    = wave * 16 + cg;          // channel in block, 0..63
    const int cb    = blockIdx.x & 63;
    const int chunk = blockIdx.x >> 6;
    const int gchan = cb * SC_CB + ch;
    const int b     = gchan >> 11;
    const int dbase = (cb & 31) * SC_CB;
    const int d     = dbase + ch;
    const int lbeg  = chunk * SC_CHUNK;

    const size_t base2048 = (size_t)b * MB_L * MB_DINNER;
    const size_t base96   = (size_t)b * MB_L * 96;

    const float4 alog = *reinterpret_cast<const float4*>(
        A_log + d * MB_DSTATE + q * 4);
    float Av2[4] = {-expf(alog.x) * 1.44269504f, -expf(alog.y) * 1.44269504f,
                    -expf(alog.z) * 1.44269504f, -expf(alog.w) * 1.44269504f};
    float h[4] = {0.f, 0.f, 0.f, 0.f};
    float sdt = 0.f;

    const int lloc  = tid >> 3;        // 0..31
    const int c8    = (tid & 7) * 8;   // 0..56
    const int cpair = (tid & 7) * 2;   // 0..14

    half8 pD, pU; float2 pB;
    auto stage_load = [&](int l0) {
        const size_t row = (size_t)(l0 + lloc);
        pD = *reinterpret_cast<const half8*>(
            delta + base2048 + row * MB_DINNER + dbase + c8);
        pU = *reinterpret_cast<const half8*>(
            u + base2048 + row * MB_DINNER + dbase + c8);
        pB = *reinterpret_cast<const float2*>(
            xdbl + base96 + row * 96 + MB_DTRANK + cpair);
    };
    auto stage_write = [&]() {
#pragma unroll
        for (int j = 0; j < 8; j++) {
            const float dd = (float)pD[j], uu = (float)pU[j];
            sDU[c8 + j][lloc] = make_float2(dd, dd * uu);
        }
        *reinterpret_cast<float2*>(&sB[lloc][cpair]) = pB;
    };

    stage_load(lbeg);
    stage_write();
    __syncthreads();

    for (int l0 = lbeg; l0 < lbeg + SC_CHUNK; l0 += SC_CL) {
        const bool has_next = (l0 + SC_CL) < lbeg + SC_CHUNK;
        if (has_next) stage_load(l0 + SC_CL);

#pragma unroll
        for (int ll = 0; ll < SC_CL; ll++) {
            const float2 du = sDU[ch][ll];
            const float4 Bv = *reinterpret_cast<const float4*>(&sB[ll][q * 4]);
            h[0] = fmaf(exp2_fast(du.x * Av2[0]), h[0], du.y * Bv.x);
            h[1] = fmaf(exp2_fast(du.x * Av2[1]), h[1], du.y * Bv.y);
            h[2] = fmaf(exp2_fast(du.x * Av2[2]), h[2], du.y * Bv.z);
            h[3] = fmaf(exp2_fast(du.x * Av2[3]), h[3], du.y * Bv.w);
            sdt += du.x;
        }
        __syncthreads();
        if (has_next) stage_write();
        __syncthreads();
    }

    const size_t cidx = ((size_t)chunk * MB_ROWS + gchan) * MB_DSTATE + q * 4;
    float4 H4 = {h[0], h[1], h[2], h[3]};
    float4 P4 = {exp2_fast(Av2[0] * sdt), exp2_fast(Av2[1] * sdt),
                 exp2_fast(Av2[2] * sdt), exp2_fast(Av2[3] * sdt)};
    *reinterpret_cast<float4*>(Hc + cidx) = H4;
    *reinterpret_cast<float4*>(Pc + cidx) = P4;
}

// ---------------------------------------------------------------------------
// Scan pass 2 (v3 layout): carry-combine (float4 H/P per lane), replay chunk.
// ---------------------------------------------------------------------------
__global__ __launch_bounds__(256) void scan_pass2(
    const f16*  __restrict__ delta,   // [4096][2048]
    const f16*  __restrict__ u,       // [4096][2048]
    const float* __restrict__ xdbl,   // [4096][96]  (dt|B|C)
    const float* __restrict__ A_log,  // [2048][16]
    const float* __restrict__ Dskip,  // [2048]
    const f16*  __restrict__ xz,      // z = cols [2048,4096)
    const float* __restrict__ Hc,     // [16][4096][16]
    const float* __restrict__ Pc,     // [16][4096][16]
    f16* __restrict__ yg)             // [4096][2048]
{
    __shared__ float2 sDU[SC_CB][SC_CL + 1];   // (δ, δ·u)
    __shared__ float2 sGS[SC_CB][SC_CL + 1];   // (g, u·Dsk·g)
    __shared__ float  sB[SC_CL][20];
    __shared__ float  sC[SC_CL][20];

    const int tid   = threadIdx.x;
    const int lane  = tid & 63;
    const int wave  = tid >> 6;
    const int cg    = (lane >> 2) & 15;
    const int q     = lane & 3;
    const int ch    = wave * 16 + cg;
    const int cb    = blockIdx.x & 63;
    const int chunk = blockIdx.x >> 6;
    const int gchan = cb * SC_CB + ch;
    const int b     = gchan >> 11;
    const int dbase = (cb & 31) * SC_CB;
    const int d     = dbase + ch;
    const int lbeg  = chunk * SC_CHUNK;

    const size_t base2048 = (size_t)b * MB_L * MB_DINNER;
    const size_t base4096 = (size_t)b * MB_L * MB_E2;
    const size_t base96   = (size_t)b * MB_L * 96;

    const float4 alog = *reinterpret_cast<const float4*>(
        A_log + d * MB_DSTATE + q * 4);
    float Av2[4] = {-expf(alog.x) * 1.44269504f, -expf(alog.y) * 1.44269504f,
                    -expf(alog.z) * 1.44269504f, -expf(alog.w) * 1.44269504f};

    const int lloc  = tid >> 3;
    const int c8    = (tid & 7) * 8;
    const int cpair = (tid & 7) * 2;

    float Dsk8[8];
    {
        const float4 d0 = *reinterpret_cast<const float4*>(Dskip + dbase + c8);
        const float4 d1 = *reinterpret_cast<const float4*>(Dskip + dbase + c8 + 4);
        Dsk8[0] = d0.x; Dsk8[1] = d0.y; Dsk8[2] = d0.z; Dsk8[3] = d0.w;
        Dsk8[4] = d1.x; Dsk8[5] = d1.y; Dsk8[6] = d1.z; Dsk8[7] = d1.w;
    }

    half8 pD, pU, pZ; float2 pB, pC;
    auto stage_load = [&](int l0) {
        const size_t row = (size_t)(l0 + lloc);
        pD = *reinterpret_cast<const half8*>(
            delta + base2048 + row * MB_DINNER + dbase + c8);
        pU = *reinterpret_cast<const half8*>(
            u + base2048 + row * MB_DINNER + dbase + c8);
        pZ = *reinterpret_cast<const half8*>(
            xz + base4096 + row * MB_E2 + MB_DINNER + dbase + c8);
        pB = *reinterpret_cast<const float2*>(
            xdbl + base96 + row * 96 + MB_DTRANK + cpair);
        pC = *reinterpret_cast<const float2*>(
            xdbl + base96 + row * 96 + MB_DTRANK + MB_DSTATE + cpair);
    };
    auto stage_write = [&]() {
#pragma unroll
        for (int j = 0; j < 8; j++) {
            const float dd = (float)pD[j], uu = (float)pU[j];
            sDU[c8 + j][lloc] = make_float2(dd, dd * uu);
            const float g = silu_f((float)pZ[j]);
            sGS[c8 + j][lloc] = make_float2(g, uu * Dsk8[j] * g);
        }
        *reinterpret_cast<float2*>(&sB[lloc][cpair]) = pB;
        *reinterpret_cast<float2*>(&sC[lloc][cpair]) = pC;
    };

    stage_load(lbeg);   // issue first window's loads before the carry chain

    float h[4] = {0.f, 0.f, 0.f, 0.f};
    for (int j = 0; j < chunk; j++) {
        const size_t cidx = ((size_t)j * MB_ROWS + gchan) * MB_DSTATE + q * 4;
        const float4 P4 = *reinterpret_cast<const float4*>(Pc + cidx);
        const float4 H4 = *reinterpret_cast<const float4*>(Hc + cidx);
        h[0] = fmaf(P4.x, h[0], H4.x);
        h[1] = fmaf(P4.y, h[1], H4.y);
        h[2] = fmaf(P4.z, h[2], H4.z);
        h[3] = fmaf(P4.w, h[3], H4.w);
    }

    stage_write();
    __syncthreads();

    for (int l0 = lbeg; l0 < lbeg + SC_CHUNK; l0 += SC_CL) {
        const bool has_next = (l0 + SC_CL) < lbeg + SC_CHUNK;
        if (has_next) stage_load(l0 + SC_CL);

        float y[SC_CL / 4] = {0.f, 0.f, 0.f, 0.f, 0.f, 0.f, 0.f, 0.f};
#pragma unroll
        for (int ll = 0; ll < SC_CL; ll++) {
            const float2 du = sDU[ch][ll];
            const float4 Bv = *reinterpret_cast<const float4*>(&sB[ll][q * 4]);
            const float4 Cv = *reinterpret_cast<const float4*>(&sC[ll][q * 4]);
            h[0] = fmaf(exp2_fast(du.x * Av2[0]), h[0], du.y * Bv.x);
            h[1] = fmaf(exp2_fast(du.x * Av2[1]), h[1], du.y * Bv.y);
            h[2] = fmaf(exp2_fast(du.x * Av2[2]), h[2], du.y * Bv.z);
            h[3] = fmaf(exp2_fast(du.x * Av2[3]), h[3], du.y * Bv.w);
            float p = h[0] * Cv.x;
            p = fmaf(h[1], Cv.y, p);
            p = fmaf(h[2], Cv.z, p);
            p = fmaf(h[3], Cv.w, p);
            p = dpp_add<0xB1>(p);   // quad xor1
            p = dpp_add<0x4E>(p);   // quad xor2: all 4 lanes hold 16-state sum
            y[ll >> 2] = (q == (ll & 3)) ? p : y[ll >> 2];
        }

#pragma unroll
        for (int k = 0; k < SC_CL / 4; k++) {
            const float2 gs = sGS[ch][4 * k + q];
            yg[base2048 + (size_t)(l0 + 4 * k + q) * MB_DINNER + dbase + ch] =
                (f16)fmaf(y[k], gs.x, gs.y);
        }

        __syncthreads();
        if (has_next) stage_write();
        __syncthreads();
    }
}

// ---------------------------------------------------------------------------
extern "C" void kernel_launch(void* const* d_in, const int* in_sizes, int n_in,
                              void* d_out, int out_size, void* d_ws,
                              size_t ws_size, hipStream_t stream)
{
    const float* x      = (const float*)d_in[0];  // (2,2048,1024)
    const float* W_in   = (const float*)d_in[1];  // (4096,1024)
    const float* conv_w = (const float*)d_in[2];  // (2048,1,4)
    const float* conv_b = (const float*)d_in[3];  // (2048)
    const float* W_xproj= (const float*)d_in[4];  // (96,2048)
    const float* W_dt   = (const float*)d_in[5];  // (2048,64)
    const float* b_dt   = (const float*)d_in[6];  // (2048)
    const float* A_log  = (const float*)d_in[7];  // (2048,16)
    const float* Dskip  = (const float*)d_in[8];  // (2048)
    const float* W_out  = (const float*)d_in[9];  // (1024,2048)
    float* out = (float*)d_out;                   // (2,2048,1024)

    // Workspace (~134 MB).  The five f16 convert destinations
    // (x_h..W_outh) are CONTIGUOUS for the fused convert.
    char* p = (char*)d_ws;
    f16* xz_h    = (f16*)p;  p += (size_t)MB_ROWS * MB_E2 * 2;      // 33.6 MB
    f16* u_h     = (f16*)p;  p += (size_t)MB_ROWS * MB_DINNER * 2;  // 16.8 MB
    f16* delta_h = (f16*)p;  p += (size_t)MB_ROWS * MB_DINNER * 2;  // 16.8 MB
    f16* yg_h    = (f16*)p;  p += (size_t)MB_ROWS * MB_DINNER * 2;  // 16.8 MB
    float* xdbl  = (float*)p; p += (size_t)MB_ROWS * 96 * 4;        // 1.6 MB
    f16* xdbl_h  = (f16*)p;  p += (size_t)MB_ROWS * 128 * 2;        // 1.0 MB
    f16* x_h     = (f16*)p;  p += (size_t)MB_ROWS * MB_DMODEL * 2;  // 8.4 MB
    f16* W_inh   = (f16*)p;  p += (size_t)MB_E2 * MB_DMODEL * 2;    // 8.4 MB
    f16* W_xprojh= (f16*)p;  p += (size_t)128 * MB_DINNER * 2;      // 0.5 MB
    f16* W_dth   = (f16*)p;  p += (size_t)MB_DINNER * MB_DTRANK * 2;// 0.26 MB
    f16* W_outh  = (f16*)p;  p += (size_t)MB_DMODEL * MB_DINNER * 2;// 4.2 MB
    float* Hc    = (float*)p; p += (size_t)SC_NC * MB_ROWS * MB_DSTATE * 4; // 4.2 MB
    float* Pc    = (float*)p; p += (size_t)SC_NC * MB_ROWS * MB_DSTATE * 4; // 4.2 MB
    float* Cp    = (float*)p;                                       // 16.8 MB

    const dim3 blk(256);

    // 0) one fused fp32 -> f16 convert over all segments
    convert_all_kernel<<<5312, blk, 0, stream>>>(
        x, W_in, W_xproj, W_dt, W_out, x_h);

    // 1) xz = x @ W_in^T     (M=4096, N=4096, K=1024) -> f16, 16 K-iters
    gemm_mfma<f16, 0, 128, 2><<<dim3(32, 32), blk, 0, stream>>>(
        x_h, MB_DMODEL, W_inh, MB_DMODEL, xz_h, MB_E2, MB_DMODEL, nullptr);

    // 2) u = silu(causal_dwconv(xb) + conv_b), 8 rows/thread
    conv_silu_kernel<<<MB_ROWS / CV_R, blk, 0, stream>>>(
        xz_h, conv_w, conv_b, u_h);

    // 3) x_dbl = u @ W_xproj^T  (M=4096, N=128, K=2048), split-K x8 + reduce
    gemm3_splitk<<<dim3(8, 32), blk, 0, stream>>>(u_h, W_xprojh, Cp);
    reduce_xdbl_kernel<<<512, blk, 0, stream>>>(Cp, xdbl, xdbl_h);

    // 4) delta = softplus(dt_low @ W_dt^T + b_dt)  (M=4096, N=2048, K=64)
    //    single K-iteration at BK=64
    gemm_mfma<f16, 1, 128, 2><<<dim3(16, 32), blk, 0, stream>>>(
        xdbl_h, 128, W_dth, MB_DTRANK, delta_h, MB_DINNER, MB_DTRANK, b_dt);

    // 5a) scan pass 1: per-chunk (H, P) summaries (last chunk skipped)
    scan_pass1<<<(SC_NC - 1) * 64, blk, 0, stream>>>(
        delta_h, u_h, xdbl, A_log, Hc, Pc);

    // 5b) scan pass 2: carry-combine + replay with y/skip/gate -> yg (f16)
    scan_pass2<<<SC_NC * 64, blk, 0, stream>>>(
        delta_h, u_h, xdbl, A_log, Dskip, xz_h, Hc, Pc, yg_h);

    // 6) out = yg @ W_out^T   (M=4096, N=1024, K=2048) -> f32, 32 K-iters
    gemm_mfma<float, 0, 64, 4><<<dim3(8, 64), blk, 0, stream>>>(
        yg_h, MB_DINNER, W_outh, MB_DINNER, out, MB_DMODEL, MB_DINNER, nullptr);
}

// Round 12
// 308.711 us; speedup vs baseline: 6.0352x; 1.0191x over previous
//
#include <hip/hip_runtime.h>
#include <math.h>

// Mamba block fwd: B=2, L=2048, d_model=1024, d_inner=2048, d_state=16,
// d_conv=4, dt_rank=64.  GEMMs in f16 MFMA, scan fp32 chunked 2-pass.
// Round 12: scan occupancy recovery — f16 LDS staging (22KB -> 7 blocks/CU)
// + SC_NC=32 (2048 blocks): ~7 waves/SIMD vs 4.  delta/u are already f16 in
// global, so f16 LDS adds only one product-rounding (y is f16-quantized at
// store anyway).  Hc/Pc alias the dead Cp buffer to keep ws <= 134 MB.
#define MB_B      2
#define MB_L      2048
#define MB_DMODEL 1024
#define MB_DINNER 2048
#define MB_DSTATE 16
#define MB_DTRANK 64
#define MB_ROWS   (MB_B * MB_L)      // 4096
#define MB_E2     (2 * MB_DINNER)    // 4096
#define SC_NC     32                 // scan chunks
#define SC_CHUNK  (MB_L / SC_NC)     // 64 steps per chunk
#define SC_CL     32                 // staging window (steps)
#define SC_CB     64                 // channels per scan block
#define CV_R      4                  // conv rows per thread

typedef _Float16 f16;
typedef __attribute__((ext_vector_type(2))) _Float16 half2v;
typedef __attribute__((ext_vector_type(4))) _Float16 half4;
typedef __attribute__((ext_vector_type(8))) _Float16 half8;
typedef __attribute__((ext_vector_type(4))) float floatx4;

__device__ __forceinline__ float softplus_f(float x) {
    return (x > 20.f) ? x : log1pf(expf(x));
}
__device__ __forceinline__ float silu_f(float x) {
    return x / (1.f + expf(-x));
}

#if __has_builtin(__builtin_amdgcn_exp2f)
__device__ __forceinline__ float exp2_fast(float x) {
    return __builtin_amdgcn_exp2f(x);
}
#else
__device__ __forceinline__ float exp2_fast(float x) {
    return __expf(0.69314718056f * x);
}
#endif

// async global->LDS, 16B/lane. LDS dst is WAVE-UNIFORM base; HW adds lane*16.
typedef const __attribute__((address_space(1))) unsigned char gbyte;
typedef __attribute__((address_space(3))) unsigned char lbyte;
__device__ __forceinline__ void gl_lds16(const void* g, void* l) {
    __builtin_amdgcn_global_load_lds((gbyte*)g, (lbyte*)l, 16, 0, 0);
}

// VALU cross-lane add via DPP.  0xB1 = quad xor1, 0x4E = quad xor2.
template <int CTRL>
__device__ __forceinline__ float dpp_add(float x) {
    int xi = __builtin_bit_cast(int, x);
    int yi = __builtin_amdgcn_update_dpp(0, xi, CTRL, 0xF, 0xF, true);
    return x + __builtin_bit_cast(float, yi);
}

// ---------------------------------------------------------------------------
// Single fused fp32 -> f16 convert over all weight/activation segments.
// ---------------------------------------------------------------------------
__global__ __launch_bounds__(256) void convert_all_kernel(
    const float* __restrict__ x, const float* __restrict__ W_in,
    const float* __restrict__ W_xproj, const float* __restrict__ W_dt,
    const float* __restrict__ W_out, f16* __restrict__ dst)
{
    const int i = (blockIdx.x * 256 + threadIdx.x) * 8;  // < 10878976
    const float* src;
    int local, nsrc;
    if (i < 4194304)      { src = x;       local = i;           nsrc = 4194304; }
    else if (i < 8388608) { src = W_in;    local = i - 4194304; nsrc = 4194304; }
    else if (i < 8650752) { src = W_xproj; local = i - 8388608; nsrc = 196608; }
    else if (i < 8781824) { src = W_dt;    local = i - 8650752; nsrc = 131072; }
    else                  { src = W_out;   local = i - 8781824; nsrc = 2097152; }
    half8 o;
    if (local < nsrc) {
        const float4 a = *reinterpret_cast<const float4*>(src + local);
        const float4 b = *reinterpret_cast<const float4*>(src + local + 4);
        o[0] = (f16)a.x; o[1] = (f16)a.y; o[2] = (f16)a.z; o[3] = (f16)a.w;
        o[4] = (f16)b.x; o[5] = (f16)b.y; o[6] = (f16)b.z; o[7] = (f16)b.w;
    } else {
#pragma unroll
        for (int j = 0; j < 8; j++) o[j] = (f16)0.f;
    }
    *reinterpret_cast<half8*>(dst + i) = o;
}

// ---------------------------------------------------------------------------
// f16 MFMA GEMM, BK=64:  C[m][n] = sum_k A[m][k]*B[n][k]  (C = A·B^T)
// Block tile BM x 128, 4 waves in (4/GN) x GN grid.  XOR swizzle (128-B
// rows): global k-chunk g at stored position p obeys g = p ^ (row&7).
// EPI==1: v = softplus(v + bias[n]).
// ---------------------------------------------------------------------------
template <typename OutT, int EPI, int BM, int GN>
__global__ __launch_bounds__(256) void gemm_mfma(
    const f16* __restrict__ A, int lda,
    const f16* __restrict__ B, int ldb,
    OutT* __restrict__ C, int ldc, int K,
    const float* __restrict__ bias)
{
    constexpr int BN = 128;
    constexpr int GM = 4 / GN;
    constexpr int WM = BM / GM;       // wave tile rows
    constexpr int WN = BN / GN;       // wave tile cols
    constexpr int MT = WM / 16, NT = WN / 16;
    constexpr int CPW = (BM + BN) / 32;   // 8-row staging chunks per wave

    __shared__ f16 As[BM * 64];   // [row][k], row stride 64 halves (128 B)
    __shared__ f16 Bs[BN * 64];

    const int tid  = threadIdx.x;
    const int lane = tid & 63;
    const int wave = tid >> 6;
    const int wr   = wave / GN, wc = wave % GN;
    const int bm   = blockIdx.y * BM, bn = blockIdx.x * BN;

    floatx4 zero4 = {0.f, 0.f, 0.f, 0.f};
    floatx4 acc[MT][NT];
#pragma unroll
    for (int i = 0; i < MT; i++)
#pragma unroll
        for (int j = 0; j < NT; j++) acc[i][j] = zero4;

    const int srow = lane >> 3;
    const int scol = ((lane & 7) ^ (srow & 7)) * 8;
    const f16* gp[CPW];
    f16* lp[CPW];
#pragma unroll
    for (int i = 0; i < CPW; i++) {
        const int rbase = (wave * CPW + i) * 8;
        if (rbase < BM) {
            gp[i] = A + (size_t)(bm + rbase + srow) * lda + scol;
            lp[i] = As + rbase * 64;
        } else {
            gp[i] = B + (size_t)(bn + (rbase - BM) + srow) * ldb + scol;
            lp[i] = Bs + (rbase - BM) * 64;
        }
    }

    const int mr = lane & 15;
    const int ko = lane >> 4;         // 0..3: k-chunk within a 32-wide MFMA

    for (int k0 = 0; k0 < K; k0 += 64) {
#pragma unroll
        for (int i = 0; i < CPW; i++) gl_lds16(gp[i] + k0, lp[i]);
        __syncthreads();   // drains vmcnt; LDS tiles visible

        half8 af[MT][2], bf[NT][2];
#pragma unroll
        for (int kk = 0; kk < 2; kk++) {
            const int koff = ((ko + kk * 4) ^ (mr & 7)) * 8;  // swizzled
#pragma unroll
            for (int mt = 0; mt < MT; mt++)
                af[mt][kk] = *reinterpret_cast<const half8*>(
                    As + (wr * WM + mt * 16 + mr) * 64 + koff);
#pragma unroll
            for (int nt = 0; nt < NT; nt++)
                bf[nt][kk] = *reinterpret_cast<const half8*>(
                    Bs + (wc * WN + nt * 16 + mr) * 64 + koff);
        }
#pragma unroll
        for (int kk = 0; kk < 2; kk++)
#pragma unroll
            for (int mt = 0; mt < MT; mt++)
#pragma unroll
                for (int nt = 0; nt < NT; nt++)
                    acc[mt][nt] = __builtin_amdgcn_mfma_f32_16x16x32_f16(
                        af[mt][kk], bf[nt][kk], acc[mt][nt], 0, 0, 0);
        __syncthreads();   // all reads done before next stage overwrites
    }

    // Epilogue. C/D layout (verified m89): col = lane&15, row = quad*4+reg.
    const int rbase = (lane >> 4) * 4;
#pragma unroll
    for (int mt = 0; mt < MT; mt++) {
        const int row0 = bm + wr * WM + mt * 16 + rbase;
#pragma unroll
        for (int nt = 0; nt < NT; nt++) {
            const int col = bn + wc * WN + nt * 16 + mr;
#pragma unroll
            for (int r = 0; r < 4; r++) {
                float v = acc[mt][nt][r];
                if constexpr (EPI == 1) v = softplus_f(v + bias[col]);
                C[(size_t)(row0 + r) * ldc + col] = (OutT)v;
            }
        }
    }
}

// ---------------------------------------------------------------------------
// gemm3 split-K (BK=32, 64-B-row swizzle): x_dbl partials.
// A = u_h [4096][2048], B = W_xprojh [128][2048].  Grid (8, 32).
// ---------------------------------------------------------------------------
__global__ __launch_bounds__(256) void gemm3_splitk(
    const f16* __restrict__ A, const f16* __restrict__ B,
    float* __restrict__ Cp)
{
    __shared__ f16 As[128 * 32];
    __shared__ f16 Bs[128 * 32];

    const int tid  = threadIdx.x;
    const int lane = tid & 63;
    const int wave = tid >> 6;
    const int wr   = wave >> 1, wc = wave & 1;
    const int bm   = blockIdx.y * 128;
    const int kbeg = blockIdx.x * 256;

    floatx4 zero4 = {0.f, 0.f, 0.f, 0.f};
    floatx4 acc[4][4];
#pragma unroll
    for (int i = 0; i < 4; i++)
#pragma unroll
        for (int j = 0; j < 4; j++) acc[i][j] = zero4;

    const int srow = lane >> 2;
    const int scol = ((lane & 3) ^ ((srow >> 1) & 3)) * 8;
    const f16* gA0 = A + (size_t)(bm + wave * 32 + srow) * MB_DINNER + scol;
    const f16* gA1 = A + (size_t)(bm + wave * 32 + 16 + srow) * MB_DINNER + scol;
    const f16* gB0 = B + (size_t)(wave * 32 + srow) * MB_DINNER + scol;
    const f16* gB1 = B + (size_t)(wave * 32 + 16 + srow) * MB_DINNER + scol;
    f16* lA0 = As + wave * 1024;
    f16* lA1 = As + wave * 1024 + 512;
    f16* lB0 = Bs + wave * 1024;
    f16* lB1 = Bs + wave * 1024 + 512;

    const int mr = lane & 15;
    const int kq = ((lane >> 4) ^ ((mr >> 1) & 3)) * 8;

    for (int k0 = kbeg; k0 < kbeg + 256; k0 += 32) {
        gl_lds16(gA0 + k0, lA0);
        gl_lds16(gA1 + k0, lA1);
        gl_lds16(gB0 + k0, lB0);
        gl_lds16(gB1 + k0, lB1);
        __syncthreads();

        half8 af[4], bf[4];
#pragma unroll
        for (int mt = 0; mt < 4; mt++)
            af[mt] = *reinterpret_cast<const half8*>(
                As + (wr * 64 + mt * 16 + mr) * 32 + kq);
#pragma unroll
        for (int nt = 0; nt < 4; nt++)
            bf[nt] = *reinterpret_cast<const half8*>(
                Bs + (wc * 64 + nt * 16 + mr) * 32 + kq);
#pragma unroll
        for (int mt = 0; mt < 4; mt++)
#pragma unroll
            for (int nt = 0; nt < 4; nt++)
                acc[mt][nt] = __builtin_amdgcn_mfma_f32_16x16x32_f16(
                    af[mt], bf[nt], acc[mt][nt], 0, 0, 0);
        __syncthreads();
    }

    float* Co = Cp + (size_t)blockIdx.x * MB_ROWS * 128;
    const int rbase = (lane >> 4) * 4;
#pragma unroll
    for (int mt = 0; mt < 4; mt++) {
        const int row0 = bm + wr * 64 + mt * 16 + rbase;
#pragma unroll
        for (int nt = 0; nt < 4; nt++) {
            const int col = wc * 64 + nt * 16 + mr;
#pragma unroll
            for (int r = 0; r < 4; r++)
                Co[(size_t)(row0 + r) * 128 + col] = acc[mt][nt][r];
        }
    }
}

// ---------------------------------------------------------------------------
// Reduce the 8 split-K partials -> xdbl f32 [4096][96] + xdbl_h f16 [4096][128]
// ---------------------------------------------------------------------------
__global__ __launch_bounds__(256) void reduce_xdbl_kernel(
    const float* __restrict__ Cp, float* __restrict__ xdbl,
    f16* __restrict__ xdbl_h)
{
    const int t = blockIdx.x * 256 + threadIdx.x;   // 0..131071
    const int row = t >> 5, c4 = (t & 31) * 4;
    float4 s = {0.f, 0.f, 0.f, 0.f};
#pragma unroll
    for (int j = 0; j < 8; j++) {
        const float4 v = *reinterpret_cast<const float4*>(
            Cp + (size_t)j * MB_ROWS * 128 + (size_t)row * 128 + c4);
        s.x += v.x; s.y += v.y; s.z += v.z; s.w += v.w;
    }
    if (c4 < 96)
        *reinterpret_cast<float4*>(xdbl + (size_t)row * 96 + c4) = s;
    half4 h = {(f16)s.x, (f16)s.y, (f16)s.z, (f16)s.w};
    *reinterpret_cast<half4*>(xdbl_h + (size_t)row * 128 + c4) = h;
}

// ---------------------------------------------------------------------------
// Causal depthwise conv1d (width 4) + bias + SiLU, sliding-window.
// Each thread: 8 channels x CV_R consecutive time-steps.
// ---------------------------------------------------------------------------
__global__ __launch_bounds__(256) void conv_silu_kernel(
    const f16* __restrict__ xz, const float* __restrict__ cw,
    const float* __restrict__ cb, f16* __restrict__ u)
{
    const int tid  = threadIdx.x;
    const int dv   = tid * 8;                 // channel base 0..2040
    const int rbeg = blockIdx.x * CV_R;       // global row base
    const int l0   = rbeg & (MB_L - 1);       // position within batch

    float wt[8][4];
#pragma unroll
    for (int j = 0; j < 8; j++) {
        const float4 wv = *reinterpret_cast<const float4*>(cw + (dv + j) * 4);
        wt[j][0] = wv.x; wt[j][1] = wv.y; wt[j][2] = wv.z; wt[j][3] = wv.w;
    }
    float bias[8];
    {
        const float4 b0 = *reinterpret_cast<const float4*>(cb + dv);
        const float4 b1 = *reinterpret_cast<const float4*>(cb + dv + 4);
        bias[0] = b0.x; bias[1] = b0.y; bias[2] = b0.z; bias[3] = b0.w;
        bias[4] = b1.x; bias[5] = b1.y; bias[6] = b1.z; bias[7] = b1.w;
    }

    half8 xr[CV_R + 3];
#pragma unroll
    for (int i = 0; i < 3; i++) {
        if (l0 >= 3 - i) {
            xr[i] = *reinterpret_cast<const half8*>(
                xz + (size_t)(rbeg - 3 + i) * MB_E2 + dv);
        } else {
#pragma unroll
            for (int j = 0; j < 8; j++) xr[i][j] = (f16)0.f;
        }
    }
#pragma unroll
    for (int r = 0; r < CV_R; r++)
        xr[3 + r] = *reinterpret_cast<const half8*>(
            xz + (size_t)(rbeg + r) * MB_E2 + dv);

#pragma unroll
    for (int r = 0; r < CV_R; r++) {
        float acc[8];
#pragma unroll
        for (int j = 0; j < 8; j++) acc[j] = bias[j];
#pragma unroll
        for (int k = 0; k < 4; k++) {
            const half8 xv = xr[r + k];
#pragma unroll
            for (int j = 0; j < 8; j++)
                acc[j] = fmaf((float)xv[j], wt[j][k], acc[j]);
        }
        half8 o;
#pragma unroll
        for (int j = 0; j < 8; j++) o[j] = (f16)silu_f(acc[j]);
        *reinterpret_cast<half8*>(u + (size_t)(rbeg + r) * MB_DINNER + dv) = o;
    }
}

// ---------------------------------------------------------------------------
// Scan pass 1 (v4): block = 64 channels x 64-step chunk, f16 LDS staging
// (11 KB -> 14 blocks/CU).  Lane (ch, q): ch = wave*16 + (lane>>2)&15,
// q = lane&3 owns states 4q..4q+3.  Grid 31x64 blocks, ~7 waves/SIMD.
// delta/u are f16 in global already -> f16 LDS adds only the delta*u
// product rounding (5e-4 rel, under the final f16 y-quantization).
// ---------------------------------------------------------------------------
__global__ __launch_bounds__(256) void scan_pass1(
    const f16*  __restrict__ delta,   // [4096][2048]
    const f16*  __restrict__ u,       // [4096][2048]
    const float* __restrict__ xdbl,   // [4096][96]  (dt|B|C)
    const float* __restrict__ A_log,  // [2048][16]
    float* __restrict__ Hc,           // [32][4096][16]
    float* __restrict__ Pc)           // [32][4096][16]
{
    __shared__ half2v sDU[SC_CB][SC_CL + 2];   // (δ, δ·u)  [ch][step], f16
    __shared__ float  sB[SC_CL][20];           // B  [step][n], +4 pad

    const int tid   = threadIdx.x;
    const int lane  = tid & 63;
    const int wave  = tid >> 6;
    const int cg    = (lane >> 2) & 15;
    const int q     = lane & 3;
    const int ch    = wave * 16 + cg;          // channel in block, 0..63
    const int cb    = blockIdx.x & 63;
    const int chunk = blockIdx.x >> 6;
    const int gchan = cb * SC_CB + ch;
    const int b     = gchan >> 11;
    const int dbase = (cb & 31) * SC_CB;
    const int d     = dbase + ch;
    const int lbeg  = chunk * SC_CHUNK;

    const size_t base2048 = (size_t)b * MB_L * MB_DINNER;
    const size_t base96   = (size_t)b * MB_L * 96;

    const float4 alog = *reinterpret_cast<const float4*>(
        A_log + d * MB_DSTATE + q * 4);
    float Av2[4] = {-expf(alog.x) * 1.44269504f, -expf(alog.y) * 1.44269504f,
                    -expf(alog.z) * 1.44269504f, -expf(alog.w) * 1.44269504f};
    float h[4] = {0.f, 0.f, 0.f, 0.f};
    float sdt = 0.f;

    const int lloc  = tid >> 3;        // 0..31
    const int c8    = (tid & 7) * 8;   // 0..56
    const int cpair = (tid & 7) * 2;   // 0..14

    half8 pD, pU; float2 pB;
    auto stage_load = [&](int l0) {
        const size_t row = (size_t)(l0 + lloc);
        pD = *reinterpret_cast<const half8*>(
            delta + base2048 + row * MB_DINNER + dbase + c8);
        pU = *reinterpret_cast<const half8*>(
            u + base2048 + row * MB_DINNER + dbase + c8);
        pB = *reinterpret_cast<const float2*>(
            xdbl + base96 + row * 96 + MB_DTRANK + cpair);
    };
    auto stage_write = [&]() {
#pragma unroll
        for (int j = 0; j < 8; j++) {
            half2v t; t[0] = pD[j]; t[1] = pD[j] * pU[j];
            sDU[c8 + j][lloc] = t;
        }
        *reinterpret_cast<float2*>(&sB[lloc][cpair]) = pB;
    };

    stage_load(lbeg);
    stage_write();
    __syncthreads();

    for (int l0 = lbeg; l0 < lbeg + SC_CHUNK; l0 += SC_CL) {
        const bool has_next = (l0 + SC_CL) < lbeg + SC_CHUNK;
        if (has_next) stage_load(l0 + SC_CL);

#pragma unroll
        for (int ll = 0; ll < SC_CL; ll++) {
            const half2v duh = sDU[ch][ll];
            const float dx = (float)duh[0], dy = (float)duh[1];
            const float4 Bv = *reinterpret_cast<const float4*>(&sB[ll][q * 4]);
            h[0] = fmaf(exp2_fast(dx * Av2[0]), h[0], dy * Bv.x);
            h[1] = fmaf(exp2_fast(dx * Av2[1]), h[1], dy * Bv.y);
            h[2] = fmaf(exp2_fast(dx * Av2[2]), h[2], dy * Bv.z);
            h[3] = fmaf(exp2_fast(dx * Av2[3]), h[3], dy * Bv.w);
            sdt += dx;
        }
        __syncthreads();
        if (has_next) stage_write();
        __syncthreads();
    }

    const size_t cidx = ((size_t)chunk * MB_ROWS + gchan) * MB_DSTATE + q * 4;
    float4 H4 = {h[0], h[1], h[2], h[3]};
    float4 P4 = {exp2_fast(Av2[0] * sdt), exp2_fast(Av2[1] * sdt),
                 exp2_fast(Av2[2] * sdt), exp2_fast(Av2[3] * sdt)};
    *reinterpret_cast<float4*>(Hc + cidx) = H4;
    *reinterpret_cast<float4*>(Pc + cidx) = P4;
}

// ---------------------------------------------------------------------------
// Scan pass 2 (v4): carry-combine (float4 H/P per lane, <=31 fma), replay
// chunk.  f16 LDS staging: 22 KB -> 7 blocks/CU, grid 32x64 = 2048 blocks.
// ---------------------------------------------------------------------------
__global__ __launch_bounds__(256) void scan_pass2(
    const f16*  __restrict__ delta,   // [4096][2048]
    const f16*  __restrict__ u,       // [4096][2048]
    const float* __restrict__ xdbl,   // [4096][96]  (dt|B|C)
    const float* __restrict__ A_log,  // [2048][16]
    const float* __restrict__ Dskip,  // [2048]
    const f16*  __restrict__ xz,      // z = cols [2048,4096)
    const float* __restrict__ Hc,     // [32][4096][16]
    const float* __restrict__ Pc,     // [32][4096][16]
    f16* __restrict__ yg)             // [4096][2048]
{
    __shared__ half2v sDU[SC_CB][SC_CL + 2];   // (δ, δ·u)  f16
    __shared__ half2v sGS[SC_CB][SC_CL + 2];   // (g, u·Dsk·g)  f16
    __shared__ float  sB[SC_CL][20];
    __shared__ float  sC[SC_CL][20];

    const int tid   = threadIdx.x;
    const int lane  = tid & 63;
    const int wave  = tid >> 6;
    const int cg    = (lane >> 2) & 15;
    const int q     = lane & 3;
    const int ch    = wave * 16 + cg;
    const int cb    = blockIdx.x & 63;
    const int chunk = blockIdx.x >> 6;
    const int gchan = cb * SC_CB + ch;
    const int b     = gchan >> 11;
    const int dbase = (cb & 31) * SC_CB;
    const int d     = dbase + ch;
    const int lbeg  = chunk * SC_CHUNK;

    const size_t base2048 = (size_t)b * MB_L * MB_DINNER;
    const size_t base4096 = (size_t)b * MB_L * MB_E2;
    const size_t base96   = (size_t)b * MB_L * 96;

    const float4 alog = *reinterpret_cast<const float4*>(
        A_log + d * MB_DSTATE + q * 4);
    float Av2[4] = {-expf(alog.x) * 1.44269504f, -expf(alog.y) * 1.44269504f,
                    -expf(alog.z) * 1.44269504f, -expf(alog.w) * 1.44269504f};

    const int lloc  = tid >> 3;
    const int c8    = (tid & 7) * 8;
    const int cpair = (tid & 7) * 2;

    float Dsk8[8];
    {
        const float4 d0 = *reinterpret_cast<const float4*>(Dskip + dbase + c8);
        const float4 d1 = *reinterpret_cast<const float4*>(Dskip + dbase + c8 + 4);
        Dsk8[0] = d0.x; Dsk8[1] = d0.y; Dsk8[2] = d0.z; Dsk8[3] = d0.w;
        Dsk8[4] = d1.x; Dsk8[5] = d1.y; Dsk8[6] = d1.z; Dsk8[7] = d1.w;
    }

    half8 pD, pU, pZ; float2 pB, pC;
    auto stage_load = [&](int l0) {
        const size_t row = (size_t)(l0 + lloc);
        pD = *reinterpret_cast<const half8*>(
            delta + base2048 + row * MB_DINNER + dbase + c8);
        pU = *reinterpret_cast<const half8*>(
            u + base2048 + row * MB_DINNER + dbase + c8);
        pZ = *reinterpret_cast<const half8*>(
            xz + base4096 + row * MB_E2 + MB_DINNER + dbase + c8);
        pB = *reinterpret_cast<const float2*>(
            xdbl + base96 + row * 96 + MB_DTRANK + cpair);
        pC = *reinterpret_cast<const float2*>(
            xdbl + base96 + row * 96 + MB_DTRANK + MB_DSTATE + cpair);
    };
    auto stage_write = [&]() {
#pragma unroll
        for (int j = 0; j < 8; j++) {
            half2v t; t[0] = pD[j]; t[1] = pD[j] * pU[j];
            sDU[c8 + j][lloc] = t;
            const float uu = (float)pU[j];
            const float g = silu_f((float)pZ[j]);
            half2v gs; gs[0] = (f16)g; gs[1] = (f16)(uu * Dsk8[j] * g);
            sGS[c8 + j][lloc] = gs;
        }
        *reinterpret_cast<float2*>(&sB[lloc][cpair]) = pB;
        *reinterpret_cast<float2*>(&sC[lloc][cpair]) = pC;
    };

    stage_load(lbeg);   // issue first window's loads before the carry chain

    float h[4] = {0.f, 0.f, 0.f, 0.f};
    for (int j = 0; j < chunk; j++) {
        const size_t cidx = ((size_t)j * MB_ROWS + gchan) * MB_DSTATE + q * 4;
        const float4 P4 = *reinterpret_cast<const float4*>(Pc + cidx);
        const float4 H4 = *reinterpret_cast<const float4*>(Hc + cidx);
        h[0] = fmaf(P4.x, h[0], H4.x);
        h[1] = fmaf(P4.y, h[1], H4.y);
        h[2] = fmaf(P4.z, h[2], H4.z);
        h[3] = fmaf(P4.w, h[3], H4.w);
    }

    stage_write();
    __syncthreads();

    for (int l0 = lbeg; l0 < lbeg + SC_CHUNK; l0 += SC_CL) {
        const bool has_next = (l0 + SC_CL) < lbeg + SC_CHUNK;
        if (has_next) stage_load(l0 + SC_CL);

        float y[SC_CL / 4] = {0.f, 0.f, 0.f, 0.f, 0.f, 0.f, 0.f, 0.f};
#pragma unroll
        for (int ll = 0; ll < SC_CL; ll++) {
            const half2v duh = sDU[ch][ll];
            const float dx = (float)duh[0], dy = (float)duh[1];
            const float4 Bv = *reinterpret_cast<const float4*>(&sB[ll][q * 4]);
            const float4 Cv = *reinterpret_cast<const float4*>(&sC[ll][q * 4]);
            h[0] = fmaf(exp2_fast(dx * Av2[0]), h[0], dy * Bv.x);
            h[1] = fmaf(exp2_fast(dx * Av2[1]), h[1], dy * Bv.y);
            h[2] = fmaf(exp2_fast(dx * Av2[2]), h[2], dy * Bv.z);
            h[3] = fmaf(exp2_fast(dx * Av2[3]), h[3], dy * Bv.w);
            float p = h[0] * Cv.x;
            p = fmaf(h[1], Cv.y, p);
            p = fmaf(h[2], Cv.z, p);
            p = fmaf(h[3], Cv.w, p);
            p = dpp_add<0xB1>(p);   // quad xor1
            p = dpp_add<0x4E>(p);   // quad xor2: all 4 lanes hold 16-state sum
            y[ll >> 2] = (q == (ll & 3)) ? p : y[ll >> 2];
        }

#pragma unroll
        for (int k = 0; k < SC_CL / 4; k++) {
            const half2v gs = sGS[ch][4 * k + q];
            yg[base2048 + (size_t)(l0 + 4 * k + q) * MB_DINNER + dbase + ch] =
                (f16)fmaf(y[k], (float)gs[0], (float)gs[1]);
        }

        __syncthreads();
        if (has_next) stage_write();
        __syncthreads();
    }
}

// ---------------------------------------------------------------------------
extern "C" void kernel_launch(void* const* d_in, const int* in_sizes, int n_in,
                              void* d_out, int out_size, void* d_ws,
                              size_t ws_size, hipStream_t stream)
{
    const float* x      = (const float*)d_in[0];  // (2,2048,1024)
    const float* W_in   = (const float*)d_in[1];  // (4096,1024)
    const float* conv_w = (const float*)d_in[2];  // (2048,1,4)
    const float* conv_b = (const float*)d_in[3];  // (2048)
    const float* W_xproj= (const float*)d_in[4];  // (96,2048)
    const float* W_dt   = (const float*)d_in[5];  // (2048,64)
    const float* b_dt   = (const float*)d_in[6];  // (2048)
    const float* A_log  = (const float*)d_in[7];  // (2048,16)
    const float* Dskip  = (const float*)d_in[8];  // (2048)
    const float* W_out  = (const float*)d_in[9];  // (1024,2048)
    float* out = (float*)d_out;                   // (2,2048,1024)

    // Workspace (~126 MB).  The five f16 convert destinations
    // (x_h..W_outh) are CONTIGUOUS for the fused convert.  Hc/Pc ALIAS the
    // Cp split-K scratch (16.8 MB each way, exact fit): Cp is dead after
    // reduce_xdbl, which runs before scan_pass1 writes Hc/Pc.
    char* p = (char*)d_ws;
    f16* xz_h    = (f16*)p;  p += (size_t)MB_ROWS * MB_E2 * 2;      // 33.6 MB
    f16* u_h     = (f16*)p;  p += (size_t)MB_ROWS * MB_DINNER * 2;  // 16.8 MB
    f16* delta_h = (f16*)p;  p += (size_t)MB_ROWS * MB_DINNER * 2;  // 16.8 MB
    f16* yg_h    = (f16*)p;  p += (size_t)MB_ROWS * MB_DINNER * 2;  // 16.8 MB
    float* xdbl  = (float*)p; p += (size_t)MB_ROWS * 96 * 4;        // 1.6 MB
    f16* xdbl_h  = (f16*)p;  p += (size_t)MB_ROWS * 128 * 2;        // 1.0 MB
    f16* x_h     = (f16*)p;  p += (size_t)MB_ROWS * MB_DMODEL * 2;  // 8.4 MB
    f16* W_inh   = (f16*)p;  p += (size_t)MB_E2 * MB_DMODEL * 2;    // 8.4 MB
    f16* W_xprojh= (f16*)p;  p += (size_t)128 * MB_DINNER * 2;      // 0.5 MB
    f16* W_dth   = (f16*)p;  p += (size_t)MB_DINNER * MB_DTRANK * 2;// 0.26 MB
    f16* W_outh  = (f16*)p;  p += (size_t)MB_DMODEL * MB_DINNER * 2;// 4.2 MB
    float* Cp    = (float*)p;                                       // 16.8 MB
    float* Hc    = Cp;                                              // alias
    float* Pc    = Cp + (size_t)SC_NC * MB_ROWS * MB_DSTATE;        // alias

    const dim3 blk(256);

    // 0) one fused fp32 -> f16 convert over all segments
    convert_all_kernel<<<5312, blk, 0, stream>>>(
        x, W_in, W_xproj, W_dt, W_out, x_h);

    // 1) xz = x @ W_in^T     (M=4096, N=4096, K=1024) -> f16, 16 K-iters
    gemm_mfma<f16, 0, 128, 2><<<dim3(32, 32), blk, 0, stream>>>(
        x_h, MB_DMODEL, W_inh, MB_DMODEL, xz_h, MB_E2, MB_DMODEL, nullptr);

    // 2) u = silu(causal_dwconv(xb) + conv_b), 8 ch x 4 rows/thread
    conv_silu_kernel<<<MB_ROWS / CV_R, blk, 0, stream>>>(
        xz_h, conv_w, conv_b, u_h);

    // 3) x_dbl = u @ W_xproj^T  (M=4096, N=128, K=2048), split-K x8 + reduce
    gemm3_splitk<<<dim3(8, 32), blk, 0, stream>>>(u_h, W_xprojh, Cp);
    reduce_xdbl_kernel<<<512, blk, 0, stream>>>(Cp, xdbl, xdbl_h);

    // 4) delta = softplus(dt_low @ W_dt^T + b_dt)  (M=4096, N=2048, K=64)
    gemm_mfma<f16, 1, 128, 2><<<dim3(16, 32), blk, 0, stream>>>(
        xdbl_h, 128, W_dth, MB_DTRANK, delta_h, MB_DINNER, MB_DTRANK, b_dt);

    // 5a) scan pass 1: per-chunk (H, P) summaries (last chunk skipped)
    //     NOTE: writes Hc/Pc over the dead Cp scratch.
    scan_pass1<<<(SC_NC - 1) * 64, blk, 0, stream>>>(
        delta_h, u_h, xdbl, A_log, Hc, Pc);

    // 5b) scan pass 2: carry-combine + replay with y/skip/gate -> yg (f16)
    scan_pass2<<<SC_NC * 64, blk, 0, stream>>>(
        delta_h, u_h, xdbl, A_log, Dskip, xz_h, Hc, Pc, yg_h);

    // 6) out = yg @ W_out^T   (M=4096, N=1024, K=2048) -> f32, 32 K-iters
    gemm_mfma<float, 0, 64, 4><<<dim3(8, 64), blk, 0, stream>>>(
        yg_h, MB_DINNER, W_outh, MB_DINNER, out, MB_DMODEL, MB_DINNER, nullptr);
}